// Round 9
// baseline (1397.876 us; speedup 1.0000x reference)
//
#include <hip/hip_runtime.h>
#include <math.h>

namespace {

constexpr int BSZ  = 1024;
constexpr int P    = 128;
constexpr int HG   = 128;
constexpr int NH   = 4;
constexpr int N    = 168;     // P + IND
constexpr int NPAD = 176;     // padded token count (11 tiles of 16)

typedef short bf16x8 __attribute__((ext_vector_type(8)));
typedef float f32x4  __attribute__((ext_vector_type(4)));

__device__ __forceinline__ unsigned short f2bf(float x){
  union { float f; unsigned u; } v; v.f = x;
  unsigned r = (v.u + 0x7FFF + ((v.u >> 16) & 1)) >> 16;
  return (unsigned short)r;
}
__device__ __forceinline__ float bf2f(unsigned short b){
  union { unsigned u; float f; } v; v.u = ((unsigned)b) << 16;
  return v.f;
}

// ---------- wave (64-lane) butterfly reductions: result in ALL lanes ----------
__device__ __forceinline__ float wsum(float v){
  #pragma unroll
  for (int o = 1; o < 64; o <<= 1) v += __shfl_xor(v, o, 64);
  return v;
}
__device__ __forceinline__ float wmax(float v){
  #pragma unroll
  for (int o = 1; o < 64; o <<= 1) v = fmaxf(v, __shfl_xor(v, o, 64));
  return v;
}
__device__ __forceinline__ float wmin(float v){
  #pragma unroll
  for (int o = 1; o < 64; o <<= 1) v = fminf(v, __shfl_xor(v, o, 64));
  return v;
}
__device__ __forceinline__ float rsum256(float v, volatile float* red4){
  #pragma unroll
  for (int o = 32; o > 0; o >>= 1) v += __shfl_down(v, o, 64);
  __syncthreads();
  if ((threadIdx.x & 63) == 0) red4[threadIdx.x >> 6] = v;
  __syncthreads();
  return red4[0] + red4[1] + red4[2] + red4[3];
}

// ---------- twiddle table: tw[tt*64+l] = cos(2pi*(l*tt mod 128)/128),
//            tw[4096+...] = -sin(...)  (matches old recurrence convention) ----------
__global__ void twiddle_kernel(float* __restrict__ tw){
  int i = blockIdx.x * 256 + threadIdx.x;
  if (i < 4096){
    int tt = i >> 6, l = i & 63;
    int k = (l * tt) & 127;
    float ang = (float)k * (-0.049087385212340517f);   // -2*pi/128
    tw[i]        = cosf(ang);
    tw[4096 + i] = sinf(ang);                          // = -sin(+ang')
  }
}

// ---------- K1: per-patch features, one WAVE per patch ----------
// DFT via LDS twiddle table (no rotation recurrence); median via 31-step
// radix-select on float bits (psd>=0 -> uint order == float order).
__global__ __launch_bounds__(256) void feat_kernel(const float* __restrict__ X,
                                                   const float* __restrict__ twg,
                                                   float* __restrict__ Xf){
  const int wave = threadIdx.x >> 6, l = threadIdx.x & 63;
  const int pp = blockIdx.x * 4 + wave;          // patch id
  const float* xp = X + (size_t)pp * 128;
  const float x0 = xp[l];
  const float x1 = xp[l + 64];

  __shared__ float tws[8192];                    // 32KB: cos[4096], -sin[4096]
  for (int idx = threadIdx.x; idx < 2048; idx += 256)
    *((float4*)tws + idx) = *((const float4*)twg + idx);
  __syncthreads();

  // ---- temporal ----
  float sum   = wsum(x0 + x1);
  float mean  = sum * (1.0f / 128.0f);
  float mx    = wmax(fmaxf(x0, x1));
  float mn    = wmin(fminf(x0, x1));
  float sumsq = wsum(fmaf(x0, x0, x1 * x1));
  float c0 = x0 - mean, c1_ = x1 - mean;
  float c0q = c0 * c0, c1q = c1_ * c1_;
  float m2 = wsum(c0q + c1q);
  float m3 = wsum(c0q * c0 + c1q * c1_);
  float m4 = wsum(c0q * c0q + c1q * c1q);
  float var = m2 * (1.0f / 127.0f);
  float sd  = sqrtf(var);
  float rms = sqrtf(sumsq * (1.0f / 128.0f));
  float ex0 = expf(x0 - mx), ex1 = expf(x1 - mx);
  float Z   = wsum(ex0 + ex1);
  float SxE = wsum(fmaf(ex0, x0, ex1 * x1));
  float ent = (mx + logf(Z)) - SxE / Z;
  const float lo = (float)(-1.0 + 1e-7), hi = (float)(1.0 - 1e-7);
  float a0 = asinf(fminf(fmaxf(x0, lo), hi));
  float a1 = asinf(fminf(fmaxf(x1, lo), hi));
  float amean = wsum(a0 + a1) * (1.0f / 128.0f);
  float ad0 = a0 - amean, ad1 = a1 - amean;
  float std_asin = sqrtf(wsum(fmaf(ad0, ad0, ad1 * ad1)) * (1.0f / 127.0f));
  float b0 = atanf(x0), b1v = atanf(x1);
  float bmean = wsum(b0 + b1v) * (1.0f / 128.0f);
  float bd0 = b0 - bmean, bd1 = b1v - bmean;
  float std_atan = sqrtf(wsum(fmaf(bd0, bd0, bd1 * bd1)) * (1.0f / 127.0f));
  float kurt = (m4 * (1.0f / 128.0f)) / (sd * sd * sd * sd) - 3.0f;
  float skew = (m3 * (1.0f / 128.0f)) / (sd * sd * sd);

  // ---- DFT: lane l computes bin l; twiddles from LDS table ----
  const float sign = (l & 1) ? -1.0f : 1.0f;
  const int x0i = __float_as_int(x0), x1i = __float_as_int(x1);
  float re = 0.f, im = 0.f;
  #pragma unroll
  for (int tt = 0; tt < 64; ++tt){
    float s0v = __int_as_float(__builtin_amdgcn_readlane(x0i, tt));
    float s1v = __int_as_float(__builtin_amdgcn_readlane(x1i, tt));
    float se = fmaf(sign, s1v, s0v);
    float wc  = tws[tt * 64 + l];
    float wsv = tws[4096 + tt * 64 + l];
    re = fmaf(se, wc, re);
    im = fmaf(se, wsv, im);
  }
  float psd = fmaf(re, re, im * im) * 0.0078125f;          // bins 0..63 (lane l)
  float re64 = wsum(sign * (x0 + x1));                     // bin 64
  float psd64 = re64 * re64 * 0.0078125f;

  const float mult = (l == 0) ? 1.f : 2.f;
  float psum = wsum(psd * mult) + psd64;
  float p2   = wsum(psd * psd * mult) + psd64 * psd64;
  float vm   = wmax(psd);
  float maxp = fmaxf(vm, psd64);
  float meanfreq = (-0.5f * psd64) / psum;
  float pbw = sqrtf(p2 / psum);
  unsigned long long am = __ballot(psd == vm);             // first-index argmax
  int lmin = __builtin_ctzll(am);
  float fmaxv = (psd64 > vm) ? -0.5f : (float)lmin * (1.0f / 128.0f);
  float maxamp = sqrtf(maxp * 128.0f);

  // ---- median via radix-select on float bits (rank 64 of 128 weighted) ----
  // weights: bin0 x1, bins1..63 x2, bin64 x1 (total 128); same rank formula
  // as the old ballot loop: less = 2*popc - (mask&1) + (psd64 < T).
  const unsigned pu   = __float_as_uint(psd);
  const unsigned pu64 = __float_as_uint(psd64);
  unsigned Pv = 0u;
  #pragma unroll
  for (int bit = 30; bit >= 0; --bit){
    unsigned T = Pv | (1u << bit);
    unsigned long long m = __ballot(pu < T);
    int c = 2 * __popcll(m) - (int)(m & 1ull) + ((pu64 < T) ? 1 : 0);
    if (c <= 64) Pv = T;                 // rank-64 value >= T
  }
  float med;
  {
    unsigned long long em = __ballot(pu == Pv);
    unsigned long long m2b = __ballot(pu < Pv);
    int less = 2 * __popcll(m2b) - (int)(m2b & 1ull) + ((pu64 < Pv) ? 1 : 0);
    if (em){
      int kt = (int)__builtin_ctzll(em);
      med = (less == 64) ? (float)kt * (1.0f / 128.0f)
                         : -(float)kt * (1.0f / 128.0f);   // less==63: 2nd copy, neg freq
    } else {
      med = -0.5f;                        // rank-64 element is bin 64
    }
  }

  if (l == 0){
    float* o = Xf + (size_t)pp * 40;
    o[0]  = mx;  o[1]  = mn;  o[2]  = sd;   o[3]  = rms; o[4]  = mean;
    o[5]  = mx - mn;  o[6] = var;  o[7] = ent; o[8] = std_asin; o[9] = std_atan;
    o[10] = kurt; o[11] = skew;
    o[12] = meanfreq;
    o[13] = med;
    o[14] = psum;
    o[15] = 1.0f;
    o[16] = pbw;
    o[17] = maxp;
    o[18] = maxamp;
    o[19] = fmaxv;
  }
}

// ---------- K2: cumsum feature + per-sample normalization ----------
__global__ __launch_bounds__(256) void cumnorm_kernel(float* __restrict__ Xf){
  const int b = blockIdx.x, t = threadIdx.x;
  __shared__ float arr[128 * 40];
  __shared__ float red4[4];
  float* base = Xf + b * 5120;
  for (int idx = t; idx < 128 * 20; idx += 256){
    int p = idx / 20, c = idx - p * 20;
    arr[p * 40 + c] = base[p * 40 + c];
  }
  __syncthreads();
  if (t < 20){
    float acc = 0.f;
    for (int p = 0; p < 128; ++p){
      acc += arr[p * 40 + t];
      arr[p * 40 + 20 + t] = acc / sqrtf(fmaxf(fabsf(acc), 1e-12f));
    }
  }
  __syncthreads();
  float pa = 0.f;
  for (int idx = t; idx < 5120; idx += 256){ float v = arr[idx]; pa = fmaf(v, v, pa); }
  float nrm = sqrtf(rsum256(pa, red4));
  for (int idx = t; idx < 5120; idx += 256) base[idx] = arr[idx] / nrm;
}

// ---------- K3: A_t (register-tiled fp32; K-order per output unchanged) ----------
__global__ __launch_bounds__(256) void adjt_kernel(const float* __restrict__ Xf,
    const float* __restrict__ w1, const float* __restrict__ b1,
    const float* __restrict__ w2, const float* __restrict__ b2,
    float* __restrict__ At){
  const int b = blockIdx.x, t = threadIdx.x;
  __shared__ float xf[5120];          // stride 40
  __shared__ float T[128 * 64];
  const float* src = Xf + b * 5120;
  for (int idx = t; idx < 1280; idx += 256)
    *((float4*)xf + idx) = *((const float4*)src + idx);
  __syncthreads();

  // T1[i][k] = tanh(b1[k] + sum_c xf[i][c]*w1[c][k]); tile 8i x 4k per thread
  {
    const int k0 = (t & 15) * 4, i0 = (t >> 4) * 8;
    float4 bv = *(const float4*)&b1[k0];
    float acc[8][4];
    #pragma unroll
    for (int di = 0; di < 8; ++di){ acc[di][0]=bv.x; acc[di][1]=bv.y; acc[di][2]=bv.z; acc[di][3]=bv.w; }
    for (int c = 0; c < 40; ++c){
      float4 wv = *(const float4*)&w1[c * 64 + k0];
      #pragma unroll
      for (int di = 0; di < 8; ++di){
        float xv = xf[(i0 + di) * 40 + c];
        acc[di][0] = fmaf(xv, wv.x, acc[di][0]);
        acc[di][1] = fmaf(xv, wv.y, acc[di][1]);
        acc[di][2] = fmaf(xv, wv.z, acc[di][2]);
        acc[di][3] = fmaf(xv, wv.w, acc[di][3]);
      }
    }
    #pragma unroll
    for (int di = 0; di < 8; ++di){
      float4 o;
      o.x = tanhf(acc[di][0]); o.y = tanhf(acc[di][1]);
      o.z = tanhf(acc[di][2]); o.w = tanhf(acc[di][3]);
      *(float4*)&T[(i0 + di) * 64 + k0] = o;
    }
  }
  __syncthreads();

  // A_t[i][j] = b2[j] + sum_k T[i][k]*w2[k][j]; tile 16i x 4j per thread
  {
    const int j0 = (t & 31) * 4, i0 = (t >> 5) * 16;
    float4 bv = *(const float4*)&b2[j0];
    float acc[16][4];
    #pragma unroll
    for (int di = 0; di < 16; ++di){ acc[di][0]=bv.x; acc[di][1]=bv.y; acc[di][2]=bv.z; acc[di][3]=bv.w; }
    for (int k = 0; k < 64; ++k){
      float4 wv = *(const float4*)&w2[k * 128 + j0];
      #pragma unroll
      for (int di = 0; di < 16; ++di){
        float tv = T[(i0 + di) * 64 + k];
        acc[di][0] = fmaf(tv, wv.x, acc[di][0]);
        acc[di][1] = fmaf(tv, wv.y, acc[di][1]);
        acc[di][2] = fmaf(tv, wv.z, acc[di][2]);
        acc[di][3] = fmaf(tv, wv.w, acc[di][3]);
      }
    }
    float* dst = At + (size_t)b * 16384;
    #pragma unroll
    for (int di = 0; di < 16; ++di)
      *(float4*)&dst[(i0 + di) * 128 + j0] = *(float4*)acc[di];
  }
}

// ---------- K4: A_s ----------
__global__ __launch_bounds__(256) void adjs_kernel(const float* __restrict__ Xf,
    const float* __restrict__ w1, const float* __restrict__ b1,
    const float* __restrict__ w2, const float* __restrict__ b2,
    float* __restrict__ As){
  const int b = blockIdx.x, t = threadIdx.x;
  __shared__ float xf[5120];
  __shared__ float T2[40 * 64];
  const float* src = Xf + b * 5120;
  for (int idx = t; idx < 1280; idx += 256)
    *((float4*)xf + idx) = *((const float4*)src + idx);
  __syncthreads();
  for (int idx = t; idx < 40 * 64; idx += 256){
    int i = idx >> 6, k = idx & 63;
    float acc = b1[k];
    for (int p = 0; p < 128; ++p) acc = fmaf(xf[p * 40 + i], w1[p * 64 + k], acc);
    T2[idx] = tanhf(acc);
  }
  __syncthreads();
  float* dst = As + b * 1600;
  for (int idx = t; idx < 1600; idx += 256){
    int i = idx / 40, j = idx - i * 40;
    float acc = b2[j];
    #pragma unroll 8
    for (int k = 0; k < 64; ++k) acc = fmaf(T2[i * 64 + k], w2[k * 40 + j], acc);
    dst[idx] = acc;
  }
}

// ---------- K5: H_s (register-tiled) ----------
__global__ __launch_bounds__(256) void hs_kernel(const float* __restrict__ Xf,
    const float* __restrict__ As_g, const float* __restrict__ w, const float* __restrict__ bias,
    float* __restrict__ H){
  const int b = blockIdx.x, t = threadIdx.x;
  __shared__ float xf[5120];          // stride 40
  __shared__ float As[1600];
  __shared__ float M[40 * 128];
  const float* src = Xf + b * 5120;
  for (int idx = t; idx < 1280; idx += 256)
    *((float4*)xf + idx) = *((const float4*)src + idx);
  for (int idx = t; idx < 400; idx += 256)
    *((float4*)As + idx) = *((const float4*)(As_g + b * 1600) + idx);
  __syncthreads();

  // M[i][p] = sum_m As[i][m] * xf[p][m]; tile 5i x 4p, m in float4 steps
  {
    const int p0 = (t & 31) * 4, i0 = (t >> 5) * 5;
    float acc[5][4];
    #pragma unroll
    for (int di = 0; di < 5; ++di)
      #pragma unroll
      for (int dp = 0; dp < 4; ++dp) acc[di][dp] = 0.f;
    for (int m = 0; m < 40; m += 4){
      float4 a4[5], x4[4];
      #pragma unroll
      for (int di = 0; di < 5; ++di) a4[di] = *(const float4*)&As[(i0 + di) * 40 + m];
      #pragma unroll
      for (int dp = 0; dp < 4; ++dp) x4[dp] = *(const float4*)&xf[(p0 + dp) * 40 + m];
      #pragma unroll
      for (int dm = 0; dm < 4; ++dm)
        #pragma unroll
        for (int di = 0; di < 5; ++di){
          float av = (&a4[di].x)[dm];
          #pragma unroll
          for (int dp = 0; dp < 4; ++dp)
            acc[di][dp] = fmaf(av, (&x4[dp].x)[dm], acc[di][dp]);
        }
    }
    #pragma unroll
    for (int di = 0; di < 5; ++di)
      *(float4*)&M[(i0 + di) * 128 + p0] = *(float4*)acc[di];
  }
  __syncthreads();

  // H_s[i][j] = leaky(bias[j] + sum_p M[i][p]*w[p][j]); tile 5i x 4j
  {
    const int j0 = (t & 31) * 4, i0 = (t >> 5) * 5;
    float4 bv = *(const float4*)&bias[j0];
    float acc[5][4];
    #pragma unroll
    for (int di = 0; di < 5; ++di){ acc[di][0]=bv.x; acc[di][1]=bv.y; acc[di][2]=bv.z; acc[di][3]=bv.w; }
    for (int p = 0; p < 128; ++p){
      float4 wv = *(const float4*)&w[p * 128 + j0];
      #pragma unroll
      for (int di = 0; di < 5; ++di){
        float mv = M[(i0 + di) * 128 + p];
        acc[di][0] = fmaf(mv, wv.x, acc[di][0]);
        acc[di][1] = fmaf(mv, wv.y, acc[di][1]);
        acc[di][2] = fmaf(mv, wv.z, acc[di][2]);
        acc[di][3] = fmaf(mv, wv.w, acc[di][3]);
      }
    }
    float* dst = H + (size_t)b * (N * HG);
    #pragma unroll
    for (int di = 0; di < 5; ++di){
      float4 o;
      o.x = (acc[di][0] >= 0.f) ? acc[di][0] : 0.01f * acc[di][0];
      o.y = (acc[di][1] >= 0.f) ? acc[di][1] : 0.01f * acc[di][1];
      o.z = (acc[di][2] >= 0.f) ? acc[di][2] : 0.01f * acc[di][2];
      o.w = (acc[di][3] >= 0.f) ? acc[di][3] : 0.01f * acc[di][3];
      *(float4*)&dst[(i0 + di) * 128 + j0] = o;
    }
  }
}

// ---------- K6: H_t (register-tiled) ----------
__global__ __launch_bounds__(256) void ht_kernel(const float* __restrict__ Xf,
    const float* __restrict__ At_g, const float* __restrict__ w, const float* __restrict__ bias,
    float* __restrict__ H){
  const int b = blockIdx.x, t = threadIdx.x;
  __shared__ float xf[5120];          // stride 40
  __shared__ float M2[128 * 40];
  const float* src = Xf + b * 5120;
  for (int idx = t; idx < 1280; idx += 256)
    *((float4*)xf + idx) = *((const float4*)src + idx);
  __syncthreads();

  // M2[i][c] = sum_m At[i][m] * xf[m][c]; tile 4i x 5c, m in float4 steps
  {
    const int c0 = (t & 7) * 5, i0 = (t >> 3) * 4;
    const float* At = At_g + (size_t)b * 16384;
    float acc[4][5];
    #pragma unroll
    for (int di = 0; di < 4; ++di)
      #pragma unroll
      for (int dc = 0; dc < 5; ++dc) acc[di][dc] = 0.f;
    for (int m = 0; m < 128; m += 4){
      float4 a4[4];
      #pragma unroll
      for (int di = 0; di < 4; ++di) a4[di] = *(const float4*)&At[(i0 + di) * 128 + m];
      #pragma unroll
      for (int dm = 0; dm < 4; ++dm){
        float xv[5];
        #pragma unroll
        for (int dc = 0; dc < 5; ++dc) xv[dc] = xf[(m + dm) * 40 + c0 + dc];
        #pragma unroll
        for (int di = 0; di < 4; ++di){
          float av = (&a4[di].x)[dm];
          #pragma unroll
          for (int dc = 0; dc < 5; ++dc)
            acc[di][dc] = fmaf(av, xv[dc], acc[di][dc]);
        }
      }
    }
    #pragma unroll
    for (int di = 0; di < 4; ++di)
      #pragma unroll
      for (int dc = 0; dc < 5; ++dc)
        M2[(i0 + di) * 40 + c0 + dc] = acc[di][dc];
  }
  __syncthreads();

  // H_t[i][j] = leaky(bias[j] + sum_c M2[i][c]*w[c][j]); tile 16i x 4j
  {
    const int j0 = (t & 31) * 4, i0 = (t >> 5) * 16;
    float4 bv = *(const float4*)&bias[j0];
    float acc[16][4];
    #pragma unroll
    for (int di = 0; di < 16; ++di){ acc[di][0]=bv.x; acc[di][1]=bv.y; acc[di][2]=bv.z; acc[di][3]=bv.w; }
    for (int c = 0; c < 40; ++c){
      float4 wv = *(const float4*)&w[c * 128 + j0];
      #pragma unroll
      for (int di = 0; di < 16; ++di){
        float mv = M2[(i0 + di) * 40 + c];
        acc[di][0] = fmaf(mv, wv.x, acc[di][0]);
        acc[di][1] = fmaf(mv, wv.y, acc[di][1]);
        acc[di][2] = fmaf(mv, wv.z, acc[di][2]);
        acc[di][3] = fmaf(mv, wv.w, acc[di][3]);
      }
    }
    float* dst = H + (size_t)b * (N * HG) + 40 * 128;
    #pragma unroll
    for (int di = 0; di < 16; ++di){
      float4 o;
      o.x = (acc[di][0] >= 0.f) ? acc[di][0] : 0.01f * acc[di][0];
      o.y = (acc[di][1] >= 0.f) ? acc[di][1] : 0.01f * acc[di][1];
      o.z = (acc[di][2] >= 0.f) ? acc[di][2] : 0.01f * acc[di][2];
      o.w = (acc[di][3] >= 0.f) ? acc[di][3] : 0.01f * acc[di][3];
      *(float4*)&dst[(i0 + di) * 128 + j0] = o;
    }
  }
}

// out[b] = fc_b + sum_h c4[h]  (c4 = vb-term collapsed: rows of P sum to 1)
__global__ void initout_kernel(float* __restrict__ out, const float* __restrict__ fcb,
                               const float* __restrict__ c4){
  int i = blockIdx.x * 256 + threadIdx.x;
  float base = fcb[0] + c4[0] + c4[1] + c4[2] + c4[3];
  if (i < BSZ) out[i] = base;
}

// ---------- prep: per-head M^T, R = fcw·Wv^T, c1/c2/c3/c4; grid (NH, 11) ----------
__global__ __launch_bounds__(256) void prep_kernel(
    const float* __restrict__ qw, const float* __restrict__ qb,
    const float* __restrict__ kw, const float* __restrict__ kb,
    const float* __restrict__ vw, const float* __restrict__ vb,
    const float* __restrict__ fcw,
    short* __restrict__ MT, short* __restrict__ Rbf,
    float* __restrict__ c1, float* __restrict__ c2,
    float* __restrict__ c3, float* __restrict__ c4){
  const int h = blockIdx.x, sl = blockIdx.y, t = threadIdx.x;
  const float* Q = qw + h * 16384;
  const float* K = kw + h * 16384;
  const float* V = vw + h * 16384;
  if (sl < 8){
    for (int idx = t; idx < 2048; idx += 256){
      int j = sl * 16 + (idx >> 7), d = idx & 127;
      float acc = 0.f;
      for (int e = 0; e < 128; ++e) acc = fmaf(Q[d * 128 + e], K[j * 128 + e], acc);
      MT[h * 16384 + j * 128 + d] = (short)f2bf(acc);     // MT[j][d] = M[d][j]
    }
    if (t < 16){
      int r = sl * 16 + t;
      float a = 0.f, bsum = 0.f;
      for (int e = 0; e < 128; ++e){
        a    = fmaf(Q[r * 128 + e], kb[h * 128 + e], a);
        bsum = fmaf(K[r * 128 + e], qb[h * 128 + e], bsum);
      }
      c1[h * 128 + r] = a;
      c2[h * 128 + r] = bsum;
    }
  }
  // R rows n in [sl*16, sl*16+16); zero-pad n >= 168
  for (int idx = t; idx < 2048; idx += 256){
    int n = sl * 16 + (idx >> 7), d = idx & 127;
    float acc = 0.f;
    if (n < N){
      const float* fr = fcw + n * 512 + h * 128;
      const float* vr = V + d * 128;
      for (int e = 0; e < 128; ++e) acc = fmaf(fr[e], vr[e], acc);
    }
    Rbf[h * 22528 + n * 128 + d] = (short)f2bf(acc);
  }
  if (sl == 0){
    if (t == 0){
      float a = 0.f;
      for (int e = 0; e < 128; ++e) a = fmaf(qb[h * 128 + e], kb[h * 128 + e], a);
      c3[h] = a;
    }
    if (t >= 64 && t < 128){                  // wave 1: c4 reduction
      int l = t - 64;
      float part = 0.f;
      for (int i = l; i < N * 128; i += 64){
        int n = i >> 7, e = i & 127;
        part = fmaf(fcw[n * 512 + h * 128 + e], vb[h * 128 + e], part);
      }
      part = wsum(part);
      if (l == 0) c4[h] = part;
    }
  }
}

// ---------- cast H -> bf16 with zero-padded rows 168..175 ----------
__global__ __launch_bounds__(256) void cast_kernel(const float* __restrict__ H,
                                                   short* __restrict__ Hbf){
  const int b = blockIdx.x;
  for (int idx = threadIdx.x; idx < NPAD * 128; idx += 256){
    int n = idx >> 7, d = idx & 127;
    float v = (n < N) ? H[((size_t)b * N + n) * 128 + d] : 0.f;
    Hbf[(size_t)b * NPAD * 128 + idx] = (short)f2bf(v);
  }
}

// ---------- u1/u2 precompute: u1[n]=H[n]·c1, u2[n]=H[n]·c2 per (b,h) ----------
__global__ __launch_bounds__(256) void uprep_kernel(const short* __restrict__ Hbf,
    const float* __restrict__ c1, const float* __restrict__ c2,
    float* __restrict__ u1g, float* __restrict__ u2g){
  const int b = blockIdx.x, t = threadIdx.x;
  for (int idx = t; idx < 176 * 4; idx += 256){
    int n = idx >> 2, h = idx & 3;
    const bf16x8* rp = (const bf16x8*)(Hbf + (size_t)b * NPAD * 128 + (size_t)n * 128);
    const float* C1 = c1 + h * 128;
    const float* C2 = c2 + h * 128;
    float a1 = 0.f, a2 = 0.f;
    for (int kk = 0; kk < 16; ++kk){
      bf16x8 v = rp[kk];
      #pragma unroll
      for (int j = 0; j < 8; ++j){
        float hv = bf2f((unsigned short)v[j]);
        a1 = fmaf(hv, C1[kk * 8 + j], a1);
        a2 = fmaf(hv, C2[kk * 8 + j], a2);
      }
    }
    u1g[(size_t)(b * 4 + h) * 176 + n] = a1;
    u2g[(size_t)(b * 4 + h) * 176 + n] = a2;
  }
}

// ---------- attention, flash-style, 8-wave block: grid (b) ----------
// Hsh 45KB + Tsh 32KB = 78KB -> 2 blocks/CU: one block computes while the other
// stages/barriers (r7's 16-wave/110KB had 1 block/CU, no inter-block overlap).
// 8 waves x 5-6 (zt,h) tasks each; per-task code identical to r7.
__global__ __launch_bounds__(512, 4) void attn_flash(
    const short* __restrict__ Hbf, const short* __restrict__ MT,
    const short* __restrict__ Rbf,
    const float* __restrict__ u1g, const float* __restrict__ u2g,
    const float* __restrict__ c3g, float* __restrict__ out){
  const int b = blockIdx.x;
  const int t = threadIdx.x;
  const int wv = t >> 6, l = t & 63, quad = l >> 4, l15 = l & 15;
  const int h = wv & 3;

  __shared__ __align__(16) short Hsh[NPAD * 128];     // 45KB, swizzled
  __shared__ __align__(16) short Tsh[8 * 2048];       // 32KB, 4KB/wave private
  __shared__ float red8[8];

  const short* Hb = Hbf + (size_t)b * NPAD * 128;

  // ---- cooperative stage: 2816 x 16B units, coalesced global, swizzled LDS ----
  #pragma unroll
  for (int i = 0; i < 6; ++i){
    int idx = t + i * 512;
    if (idx < 2816){
      int row = idx >> 4, g = idx & 15;
      bf16x8 v = *(const bf16x8*)(Hb + row * 128 + g * 8);
      *(bf16x8*)(Hsh + row * 128 + ((g ^ (row & 15)) * 8)) = v;
    }
  }
  __syncthreads();

  const short* MTh = MT + h * 16384;
  const short* Rh  = Rbf + h * 22528;
  const float c3v = c3g[h];
  const float inv = 0.08838834764831845f;   // 1/sqrt(128)
  const float* u1p = u1g + (size_t)(b * 4 + h) * 176;
  const float* u2p = u2g + (size_t)(b * 4 + h) * 176;
  short* Tw = Tsh + wv * 2048;

  float tp = 0.f;
  #pragma unroll
  for (int ti = 0; ti < 6; ++ti){
    const int zt = (wv >> 2) + ti * 2;
    if (zt < 11){                                  // wave-uniform guard
      const int rowbase = zt * 16;

      // A-frags (H rows, from LDS) and R-frags (global, L2-hot)
      bf16x8 HA[4], RA[4];
      #pragma unroll
      for (int kk = 0; kk < 4; ++kk){
        HA[kk] = *(const bf16x8*)(Hsh + (rowbase + l15) * 128 + (((kk * 4 + quad) ^ l15) * 8));
        RA[kk] = *(const bf16x8*)(Rh + (rowbase + l15) * 128 + kk * 32 + quad * 8);
      }
      float u1v[4];
      #pragma unroll
      for (int r = 0; r < 4; ++r) u1v[r] = u1p[rowbase + quad * 4 + r];

      // ---- Phase A: T = H_chunk @ M -> private LDS slice (XOR-swizzled) ----
      #pragma unroll
      for (int jt = 0; jt < 8; ++jt){
        const int j0 = jt * 16;
        f32x4 acc = {0.f, 0.f, 0.f, 0.f};
        #pragma unroll
        for (int kk = 0; kk < 4; ++kk){
          bf16x8 Bv = *(const bf16x8*)(MTh + (j0 + l15) * 128 + kk * 32 + quad * 8);
          acc = __builtin_amdgcn_mfma_f32_16x16x32_bf16(HA[kk], Bv, acc, 0, 0, 0);
        }
        const int jcol = j0 + l15, ch = jcol >> 3;
        #pragma unroll
        for (int r = 0; r < 4; ++r){
          int row = quad * 4 + r;
          Tw[row * 128 + ((ch ^ row) << 3) + (jcol & 7)] = (short)f2bf(acc[r]);
        }
      }
      // no barrier: same-wave DS ops are ordered

      // ---- Phase BG + per-lane online softmax over 11 m-tiles ----
      float Mx[4], Av[4], Dv[4];
      #pragma unroll
      for (int r = 0; r < 4; ++r){ Mx[r] = -1e30f; Av[r] = 0.f; Dv[r] = 0.f; }

      #pragma unroll
      for (int mt = 0; mt < 11; ++mt){
        const int m0 = mt * 16;
        bf16x8 Bv[4];
        #pragma unroll
        for (int kk = 0; kk < 4; ++kk)
          Bv[kk] = *(const bf16x8*)(Hsh + (m0 + l15) * 128 + (((kk * 4 + quad) ^ l15) * 8));
        const float u2v = u2p[m0 + l15];
        f32x4 acc = {0.f, 0.f, 0.f, 0.f};
        f32x4 g   = {0.f, 0.f, 0.f, 0.f};
        #pragma unroll
        for (int kk = 0; kk < 4; ++kk){
          bf16x8 A = *(const bf16x8*)(Tw + l15 * 128 + (((kk * 4 + quad) ^ l15) << 3));
          acc = __builtin_amdgcn_mfma_f32_16x16x32_bf16(A, Bv[kk], acc, 0, 0, 0);
          g   = __builtin_amdgcn_mfma_f32_16x16x32_bf16(RA[kk], Bv[kk], g, 0, 0, 0);
        }
        const bool padcol = (mt == 10) && (l15 >= 8);     // cols 168..175 masked
        #pragma unroll
        for (int r = 0; r < 4; ++r){
          float s = padcol ? -1e30f : (acc[r] + u1v[r] + u2v + c3v) * inv;
          float Mn = fmaxf(Mx[r], s);
          float ea = __expf(Mx[r] - Mn);
          float eb = __expf(s - Mn);
          Av[r] = fmaf(Av[r], ea, eb * g[r]);
          Dv[r] = fmaf(Dv[r], ea, eb);
          Mx[r] = Mn;
        }
      }

      // ---- merge (M,A,D) across the 16 l15 lanes (stays within quad) ----
      #pragma unroll
      for (int r = 0; r < 4; ++r){
        #pragma unroll
        for (int o = 1; o < 16; o <<= 1){
          float M2 = __shfl_xor(Mx[r], o, 64);
          float A2 = __shfl_xor(Av[r], o, 64);
          float D2 = __shfl_xor(Dv[r], o, 64);
          float Mn = fmaxf(Mx[r], M2);
          float ea = __expf(Mx[r] - Mn);
          float eb = __expf(M2 - Mn);
          Av[r] = fmaf(Av[r], ea, A2 * eb);
          Dv[r] = fmaf(Dv[r], ea, D2 * eb);
          Mx[r] = Mn;
        }
      }

      // ---- per-row A/D, replicated over 16 lanes -> scale by 1/16 ----
      #pragma unroll
      for (int r = 0; r < 4; ++r){
        int n = rowbase + quad * 4 + r;
        if (n < N) tp += Av[r] / Dv[r];
      }
    }
  }
  tp *= (1.0f / 16.0f);

  // ---- block reduction over 8 waves ----
  #pragma unroll
  for (int o = 32; o > 0; o >>= 1) tp += __shfl_down(tp, o, 64);
  if (l == 0) red8[wv] = tp;
  __syncthreads();
  if (t == 0){
    float s = 0.f;
    #pragma unroll
    for (int i = 0; i < 8; ++i) s += red8[i];
    atomicAdd(out + b, s);
  }
}

} // anonymous namespace

extern "C" void kernel_launch(void* const* d_in, const int* in_sizes, int n_in,
                              void* d_out, int out_size, void* d_ws, size_t ws_size,
                              hipStream_t stream) {
  (void)in_sizes; (void)n_in; (void)out_size;
  const float* X      = (const float*)d_in[0];
  const float* spa_w1 = (const float*)d_in[1];
  const float* spa_b1 = (const float*)d_in[2];
  const float* spa_w2 = (const float*)d_in[3];
  const float* spa_b2 = (const float*)d_in[4];
  const float* tem_w1 = (const float*)d_in[5];
  const float* tem_b1 = (const float*)d_in[6];
  const float* tem_w2 = (const float*)d_in[7];
  const float* tem_b2 = (const float*)d_in[8];
  const float* sgnn_w = (const float*)d_in[9];
  const float* sgnn_b = (const float*)d_in[10];
  const float* tgnn_w = (const float*)d_in[11];
  const float* tgnn_b = (const float*)d_in[12];
  const float* q_w    = (const float*)d_in[13];
  const float* q_b    = (const float*)d_in[14];
  const float* k_w    = (const float*)d_in[15];
  const float* k_b    = (const float*)d_in[16];
  const float* v_w    = (const float*)d_in[17];
  const float* v_b    = (const float*)d_in[18];
  const float* fc_w   = (const float*)d_in[19];
  const float* fc_b   = (const float*)d_in[20];
  float* out = (float*)d_out;

  if (ws_size < (size_t)182714368) return;

  char* wsb = (char*)d_ws;
  float* H   = (float*)wsb;                      // fp32 H [0, 88MB)
  float* u1g = (float*)(wsb + 50331648);         // overlays dead-H region (H dead after cast)
  float* u2g = (float*)(wsb + 53215232);
  char*  Rb  = wsb + 88080384;
  float* Xf  = (float*)Rb;
  float* As  = (float*)(Rb + 20971520);
  float* At  = (float*)(Rb + 27525120);
  short* Hbf = (short*)Rb;                       // overlays dead Xf/As/At after ht
  char*  Pb  = Rb + 46137344;
  short* MT  = (short*)Pb;                       // 131072 B
  short* Rbf = (short*)(Pb + 131072);            // 180224 B (4 heads x 176 x 128 bf16)
  float* c1  = (float*)(Pb + 311296);
  float* c2  = (float*)(Pb + 313344);
  float* c3  = (float*)(Pb + 315392);
  float* c4  = (float*)(Pb + 315408);
  float* twg = (float*)(Pb + 327680);            // 32KB twiddle table

  twiddle_kernel<<<16, 256, 0, stream>>>(twg);
  feat_kernel<<<BSZ * P / 4, 256, 0, stream>>>(X, twg, Xf);
  cumnorm_kernel<<<BSZ, 256, 0, stream>>>(Xf);
  adjt_kernel<<<BSZ, 256, 0, stream>>>(Xf, tem_w1, tem_b1, tem_w2, tem_b2, At);
  adjs_kernel<<<BSZ, 256, 0, stream>>>(Xf, spa_w1, spa_b1, spa_w2, spa_b2, As);
  hs_kernel<<<BSZ, 256, 0, stream>>>(Xf, As, sgnn_w, sgnn_b, H);
  ht_kernel<<<BSZ, 256, 0, stream>>>(Xf, At, tgnn_w, tgnn_b, H);
  prep_kernel<<<dim3(NH, 11), 256, 0, stream>>>(q_w, q_b, k_w, k_b, v_w, v_b, fc_w,
                                                MT, Rbf, c1, c2, c3, c4);
  cast_kernel<<<BSZ, 256, 0, stream>>>(H, Hbf);          // H fp32 dead after this
  uprep_kernel<<<BSZ, 256, 0, stream>>>(Hbf, c1, c2, u1g, u2g);
  initout_kernel<<<4, 256, 0, stream>>>(out, fc_b, c4);
  attn_flash<<<dim3(BSZ), 512, 0, stream>>>(Hbf, MT, Rbf, u1g, u2g, c3, out);
}

// Round 10
// 1201.272 us; speedup vs baseline: 1.1637x; 1.1637x over previous
//
#include <hip/hip_runtime.h>
#include <math.h>

namespace {

constexpr int BSZ  = 1024;
constexpr int P    = 128;
constexpr int HG   = 128;
constexpr int NH   = 4;
constexpr int N    = 168;     // P + IND
constexpr int NPAD = 176;     // padded token count (11 tiles of 16)

typedef short bf16x8 __attribute__((ext_vector_type(8)));
typedef float f32x4  __attribute__((ext_vector_type(4)));

__device__ __forceinline__ unsigned short f2bf(float x){
  union { float f; unsigned u; } v; v.f = x;
  unsigned r = (v.u + 0x7FFF + ((v.u >> 16) & 1)) >> 16;
  return (unsigned short)r;
}
__device__ __forceinline__ float bf2f(unsigned short b){
  union { unsigned u; float f; } v; v.u = ((unsigned)b) << 16;
  return v.f;
}

// ---------- wave (64-lane) butterfly reductions: result in ALL lanes ----------
__device__ __forceinline__ float wsum(float v){
  #pragma unroll
  for (int o = 1; o < 64; o <<= 1) v += __shfl_xor(v, o, 64);
  return v;
}
__device__ __forceinline__ float wmax(float v){
  #pragma unroll
  for (int o = 1; o < 64; o <<= 1) v = fmaxf(v, __shfl_xor(v, o, 64));
  return v;
}
__device__ __forceinline__ float wmin(float v){
  #pragma unroll
  for (int o = 1; o < 64; o <<= 1) v = fminf(v, __shfl_xor(v, o, 64));
  return v;
}
__device__ __forceinline__ float rsum256(float v, volatile float* red4){
  #pragma unroll
  for (int o = 32; o > 0; o >>= 1) v += __shfl_down(v, o, 64);
  __syncthreads();
  if ((threadIdx.x & 63) == 0) red4[threadIdx.x >> 6] = v;
  __syncthreads();
  return red4[0] + red4[1] + red4[2] + red4[3];
}

// ---------- twiddle table: tw[tt*64+l] = cos(2pi*(l*tt mod 128)/128),
//            tw[4096+...] = -sin(...)  (matches old recurrence convention) ----------
__global__ void twiddle_kernel(float* __restrict__ tw){
  int i = blockIdx.x * 256 + threadIdx.x;
  if (i < 4096){
    int tt = i >> 6, l = i & 63;
    int k = (l * tt) & 127;
    float ang = (float)k * (-0.049087385212340517f);   // -2*pi/128
    tw[i]        = cosf(ang);
    tw[4096 + i] = sinf(ang);                          // = -sin(+ang')
  }
}

// ---------- K1: per-patch features, one WAVE per patch ----------
// DFT via LDS twiddle table (no rotation recurrence); median via 31-step
// radix-select on float bits (psd>=0 -> uint order == float order).
__global__ __launch_bounds__(256) void feat_kernel(const float* __restrict__ X,
                                                   const float* __restrict__ twg,
                                                   float* __restrict__ Xf){
  const int wave = threadIdx.x >> 6, l = threadIdx.x & 63;
  const int pp = blockIdx.x * 4 + wave;          // patch id
  const float* xp = X + (size_t)pp * 128;
  const float x0 = xp[l];
  const float x1 = xp[l + 64];

  __shared__ float tws[8192];                    // 32KB: cos[4096], -sin[4096]
  for (int idx = threadIdx.x; idx < 2048; idx += 256)
    *((float4*)tws + idx) = *((const float4*)twg + idx);
  __syncthreads();

  // ---- temporal ----
  float sum   = wsum(x0 + x1);
  float mean  = sum * (1.0f / 128.0f);
  float mx    = wmax(fmaxf(x0, x1));
  float mn    = wmin(fminf(x0, x1));
  float sumsq = wsum(fmaf(x0, x0, x1 * x1));
  float c0 = x0 - mean, c1_ = x1 - mean;
  float c0q = c0 * c0, c1q = c1_ * c1_;
  float m2 = wsum(c0q + c1q);
  float m3 = wsum(c0q * c0 + c1q * c1_);
  float m4 = wsum(c0q * c0q + c1q * c1q);
  float var = m2 * (1.0f / 127.0f);
  float sd  = sqrtf(var);
  float rms = sqrtf(sumsq * (1.0f / 128.0f));
  float ex0 = expf(x0 - mx), ex1 = expf(x1 - mx);
  float Z   = wsum(ex0 + ex1);
  float SxE = wsum(fmaf(ex0, x0, ex1 * x1));
  float ent = (mx + logf(Z)) - SxE / Z;
  const float lo = (float)(-1.0 + 1e-7), hi = (float)(1.0 - 1e-7);
  float a0 = asinf(fminf(fmaxf(x0, lo), hi));
  float a1 = asinf(fminf(fmaxf(x1, lo), hi));
  float amean = wsum(a0 + a1) * (1.0f / 128.0f);
  float ad0 = a0 - amean, ad1 = a1 - amean;
  float std_asin = sqrtf(wsum(fmaf(ad0, ad0, ad1 * ad1)) * (1.0f / 127.0f));
  float b0 = atanf(x0), b1v = atanf(x1);
  float bmean = wsum(b0 + b1v) * (1.0f / 128.0f);
  float bd0 = b0 - bmean, bd1 = b1v - bmean;
  float std_atan = sqrtf(wsum(fmaf(bd0, bd0, bd1 * bd1)) * (1.0f / 127.0f));
  float kurt = (m4 * (1.0f / 128.0f)) / (sd * sd * sd * sd) - 3.0f;
  float skew = (m3 * (1.0f / 128.0f)) / (sd * sd * sd);

  // ---- DFT: lane l computes bin l; twiddles from LDS table ----
  const float sign = (l & 1) ? -1.0f : 1.0f;
  const int x0i = __float_as_int(x0), x1i = __float_as_int(x1);
  float re = 0.f, im = 0.f;
  #pragma unroll
  for (int tt = 0; tt < 64; ++tt){
    float s0v = __int_as_float(__builtin_amdgcn_readlane(x0i, tt));
    float s1v = __int_as_float(__builtin_amdgcn_readlane(x1i, tt));
    float se = fmaf(sign, s1v, s0v);
    float wc  = tws[tt * 64 + l];
    float wsv = tws[4096 + tt * 64 + l];
    re = fmaf(se, wc, re);
    im = fmaf(se, wsv, im);
  }
  float psd = fmaf(re, re, im * im) * 0.0078125f;          // bins 0..63 (lane l)
  float re64 = wsum(sign * (x0 + x1));                     // bin 64
  float psd64 = re64 * re64 * 0.0078125f;

  const float mult = (l == 0) ? 1.f : 2.f;
  float psum = wsum(psd * mult) + psd64;
  float p2   = wsum(psd * psd * mult) + psd64 * psd64;
  float vm   = wmax(psd);
  float maxp = fmaxf(vm, psd64);
  float meanfreq = (-0.5f * psd64) / psum;
  float pbw = sqrtf(p2 / psum);
  unsigned long long am = __ballot(psd == vm);             // first-index argmax
  int lmin = __builtin_ctzll(am);
  float fmaxv = (psd64 > vm) ? -0.5f : (float)lmin * (1.0f / 128.0f);
  float maxamp = sqrtf(maxp * 128.0f);

  // ---- median via radix-select on float bits (rank 64 of 128 weighted) ----
  const unsigned pu   = __float_as_uint(psd);
  const unsigned pu64 = __float_as_uint(psd64);
  unsigned Pv = 0u;
  #pragma unroll
  for (int bit = 30; bit >= 0; --bit){
    unsigned T = Pv | (1u << bit);
    unsigned long long m = __ballot(pu < T);
    int c = 2 * __popcll(m) - (int)(m & 1ull) + ((pu64 < T) ? 1 : 0);
    if (c <= 64) Pv = T;                 // rank-64 value >= T
  }
  float med;
  {
    unsigned long long em = __ballot(pu == Pv);
    unsigned long long m2b = __ballot(pu < Pv);
    int less = 2 * __popcll(m2b) - (int)(m2b & 1ull) + ((pu64 < Pv) ? 1 : 0);
    if (em){
      int kt = (int)__builtin_ctzll(em);
      med = (less == 64) ? (float)kt * (1.0f / 128.0f)
                         : -(float)kt * (1.0f / 128.0f);   // less==63: 2nd copy, neg freq
    } else {
      med = -0.5f;                        // rank-64 element is bin 64
    }
  }

  if (l == 0){
    float* o = Xf + (size_t)pp * 40;
    o[0]  = mx;  o[1]  = mn;  o[2]  = sd;   o[3]  = rms; o[4]  = mean;
    o[5]  = mx - mn;  o[6] = var;  o[7] = ent; o[8] = std_asin; o[9] = std_atan;
    o[10] = kurt; o[11] = skew;
    o[12] = meanfreq;
    o[13] = med;
    o[14] = psum;
    o[15] = 1.0f;
    o[16] = pbw;
    o[17] = maxp;
    o[18] = maxamp;
    o[19] = fmaxv;
  }
}

// ---------- K2: cumsum feature + per-sample normalization ----------
__global__ __launch_bounds__(256) void cumnorm_kernel(float* __restrict__ Xf){
  const int b = blockIdx.x, t = threadIdx.x;
  __shared__ float arr[128 * 40];
  __shared__ float red4[4];
  float* base = Xf + b * 5120;
  for (int idx = t; idx < 128 * 20; idx += 256){
    int p = idx / 20, c = idx - p * 20;
    arr[p * 40 + c] = base[p * 40 + c];
  }
  __syncthreads();
  if (t < 20){
    float acc = 0.f;
    for (int p = 0; p < 128; ++p){
      acc += arr[p * 40 + t];
      arr[p * 40 + 20 + t] = acc / sqrtf(fmaxf(fabsf(acc), 1e-12f));
    }
  }
  __syncthreads();
  float pa = 0.f;
  for (int idx = t; idx < 5120; idx += 256){ float v = arr[idx]; pa = fmaf(v, v, pa); }
  float nrm = sqrtf(rsum256(pa, red4));
  for (int idx = t; idx < 5120; idx += 256) base[idx] = arr[idx] / nrm;
}

// ---------- K3: A_t (register-tiled fp32; K-order per output unchanged) ----------
__global__ __launch_bounds__(256) void adjt_kernel(const float* __restrict__ Xf,
    const float* __restrict__ w1, const float* __restrict__ b1,
    const float* __restrict__ w2, const float* __restrict__ b2,
    float* __restrict__ At){
  const int b = blockIdx.x, t = threadIdx.x;
  __shared__ float xf[5120];          // stride 40
  __shared__ float T[128 * 64];
  const float* src = Xf + b * 5120;
  for (int idx = t; idx < 1280; idx += 256)
    *((float4*)xf + idx) = *((const float4*)src + idx);
  __syncthreads();

  // T1[i][k] = tanh(b1[k] + sum_c xf[i][c]*w1[c][k]); tile 8i x 4k per thread
  {
    const int k0 = (t & 15) * 4, i0 = (t >> 4) * 8;
    float4 bv = *(const float4*)&b1[k0];
    float acc[8][4];
    #pragma unroll
    for (int di = 0; di < 8; ++di){ acc[di][0]=bv.x; acc[di][1]=bv.y; acc[di][2]=bv.z; acc[di][3]=bv.w; }
    for (int c = 0; c < 40; ++c){
      float4 wv = *(const float4*)&w1[c * 64 + k0];
      #pragma unroll
      for (int di = 0; di < 8; ++di){
        float xv = xf[(i0 + di) * 40 + c];
        acc[di][0] = fmaf(xv, wv.x, acc[di][0]);
        acc[di][1] = fmaf(xv, wv.y, acc[di][1]);
        acc[di][2] = fmaf(xv, wv.z, acc[di][2]);
        acc[di][3] = fmaf(xv, wv.w, acc[di][3]);
      }
    }
    #pragma unroll
    for (int di = 0; di < 8; ++di){
      float4 o;
      o.x = tanhf(acc[di][0]); o.y = tanhf(acc[di][1]);
      o.z = tanhf(acc[di][2]); o.w = tanhf(acc[di][3]);
      *(float4*)&T[(i0 + di) * 64 + k0] = o;
    }
  }
  __syncthreads();

  // A_t[i][j] = b2[j] + sum_k T[i][k]*w2[k][j]; tile 16i x 4j per thread
  {
    const int j0 = (t & 31) * 4, i0 = (t >> 5) * 16;
    float4 bv = *(const float4*)&b2[j0];
    float acc[16][4];
    #pragma unroll
    for (int di = 0; di < 16; ++di){ acc[di][0]=bv.x; acc[di][1]=bv.y; acc[di][2]=bv.z; acc[di][3]=bv.w; }
    for (int k = 0; k < 64; ++k){
      float4 wv = *(const float4*)&w2[k * 128 + j0];
      #pragma unroll
      for (int di = 0; di < 16; ++di){
        float tv = T[(i0 + di) * 64 + k];
        acc[di][0] = fmaf(tv, wv.x, acc[di][0]);
        acc[di][1] = fmaf(tv, wv.y, acc[di][1]);
        acc[di][2] = fmaf(tv, wv.z, acc[di][2]);
        acc[di][3] = fmaf(tv, wv.w, acc[di][3]);
      }
    }
    float* dst = At + (size_t)b * 16384;
    #pragma unroll
    for (int di = 0; di < 16; ++di)
      *(float4*)&dst[(i0 + di) * 128 + j0] = *(float4*)acc[di];
  }
}

// ---------- K4: A_s ----------
__global__ __launch_bounds__(256) void adjs_kernel(const float* __restrict__ Xf,
    const float* __restrict__ w1, const float* __restrict__ b1,
    const float* __restrict__ w2, const float* __restrict__ b2,
    float* __restrict__ As){
  const int b = blockIdx.x, t = threadIdx.x;
  __shared__ float xf[5120];
  __shared__ float T2[40 * 64];
  const float* src = Xf + b * 5120;
  for (int idx = t; idx < 1280; idx += 256)
    *((float4*)xf + idx) = *((const float4*)src + idx);
  __syncthreads();
  for (int idx = t; idx < 40 * 64; idx += 256){
    int i = idx >> 6, k = idx & 63;
    float acc = b1[k];
    for (int p = 0; p < 128; ++p) acc = fmaf(xf[p * 40 + i], w1[p * 64 + k], acc);
    T2[idx] = tanhf(acc);
  }
  __syncthreads();
  float* dst = As + b * 1600;
  for (int idx = t; idx < 1600; idx += 256){
    int i = idx / 40, j = idx - i * 40;
    float acc = b2[j];
    #pragma unroll 8
    for (int k = 0; k < 64; ++k) acc = fmaf(T2[i * 64 + k], w2[k * 40 + j], acc);
    dst[idx] = acc;
  }
}

// ---------- K5: H_s (register-tiled) ----------
__global__ __launch_bounds__(256) void hs_kernel(const float* __restrict__ Xf,
    const float* __restrict__ As_g, const float* __restrict__ w, const float* __restrict__ bias,
    float* __restrict__ H){
  const int b = blockIdx.x, t = threadIdx.x;
  __shared__ float xf[5120];          // stride 40
  __shared__ float As[1600];
  __shared__ float M[40 * 128];
  const float* src = Xf + b * 5120;
  for (int idx = t; idx < 1280; idx += 256)
    *((float4*)xf + idx) = *((const float4*)src + idx);
  for (int idx = t; idx < 400; idx += 256)
    *((float4*)As + idx) = *((const float4*)(As_g + b * 1600) + idx);
  __syncthreads();

  // M[i][p] = sum_m As[i][m] * xf[p][m]; tile 5i x 4p, m in float4 steps
  {
    const int p0 = (t & 31) * 4, i0 = (t >> 5) * 5;
    float acc[5][4];
    #pragma unroll
    for (int di = 0; di < 5; ++di)
      #pragma unroll
      for (int dp = 0; dp < 4; ++dp) acc[di][dp] = 0.f;
    for (int m = 0; m < 40; m += 4){
      float4 a4[5], x4[4];
      #pragma unroll
      for (int di = 0; di < 5; ++di) a4[di] = *(const float4*)&As[(i0 + di) * 40 + m];
      #pragma unroll
      for (int dp = 0; dp < 4; ++dp) x4[dp] = *(const float4*)&xf[(p0 + dp) * 40 + m];
      #pragma unroll
      for (int dm = 0; dm < 4; ++dm)
        #pragma unroll
        for (int di = 0; di < 5; ++di){
          float av = (&a4[di].x)[dm];
          #pragma unroll
          for (int dp = 0; dp < 4; ++dp)
            acc[di][dp] = fmaf(av, (&x4[dp].x)[dm], acc[di][dp]);
        }
    }
    #pragma unroll
    for (int di = 0; di < 5; ++di)
      *(float4*)&M[(i0 + di) * 128 + p0] = *(float4*)acc[di];
  }
  __syncthreads();

  // H_s[i][j] = leaky(bias[j] + sum_p M[i][p]*w[p][j]); tile 5i x 4j
  {
    const int j0 = (t & 31) * 4, i0 = (t >> 5) * 5;
    float4 bv = *(const float4*)&bias[j0];
    float acc[5][4];
    #pragma unroll
    for (int di = 0; di < 5; ++di){ acc[di][0]=bv.x; acc[di][1]=bv.y; acc[di][2]=bv.z; acc[di][3]=bv.w; }
    for (int p = 0; p < 128; ++p){
      float4 wv = *(const float4*)&w[p * 128 + j0];
      #pragma unroll
      for (int di = 0; di < 5; ++di){
        float mv = M[(i0 + di) * 128 + p];
        acc[di][0] = fmaf(mv, wv.x, acc[di][0]);
        acc[di][1] = fmaf(mv, wv.y, acc[di][1]);
        acc[di][2] = fmaf(mv, wv.z, acc[di][2]);
        acc[di][3] = fmaf(mv, wv.w, acc[di][3]);
      }
    }
    float* dst = H + (size_t)b * (N * HG);
    #pragma unroll
    for (int di = 0; di < 5; ++di){
      float4 o;
      o.x = (acc[di][0] >= 0.f) ? acc[di][0] : 0.01f * acc[di][0];
      o.y = (acc[di][1] >= 0.f) ? acc[di][1] : 0.01f * acc[di][1];
      o.z = (acc[di][2] >= 0.f) ? acc[di][2] : 0.01f * acc[di][2];
      o.w = (acc[di][3] >= 0.f) ? acc[di][3] : 0.01f * acc[di][3];
      *(float4*)&dst[(i0 + di) * 128 + j0] = o;
    }
  }
}

// ---------- K6: H_t (register-tiled) ----------
__global__ __launch_bounds__(256) void ht_kernel(const float* __restrict__ Xf,
    const float* __restrict__ At_g, const float* __restrict__ w, const float* __restrict__ bias,
    float* __restrict__ H){
  const int b = blockIdx.x, t = threadIdx.x;
  __shared__ float xf[5120];          // stride 40
  __shared__ float M2[128 * 40];
  const float* src = Xf + b * 5120;
  for (int idx = t; idx < 1280; idx += 256)
    *((float4*)xf + idx) = *((const float4*)src + idx);
  __syncthreads();

  // M2[i][c] = sum_m At[i][m] * xf[m][c]; tile 4i x 5c, m in float4 steps
  {
    const int c0 = (t & 7) * 5, i0 = (t >> 3) * 4;
    const float* At = At_g + (size_t)b * 16384;
    float acc[4][5];
    #pragma unroll
    for (int di = 0; di < 4; ++di)
      #pragma unroll
      for (int dc = 0; dc < 5; ++dc) acc[di][dc] = 0.f;
    for (int m = 0; m < 128; m += 4){
      float4 a4[4];
      #pragma unroll
      for (int di = 0; di < 4; ++di) a4[di] = *(const float4*)&At[(i0 + di) * 128 + m];
      #pragma unroll
      for (int dm = 0; dm < 4; ++dm){
        float xv[5];
        #pragma unroll
        for (int dc = 0; dc < 5; ++dc) xv[dc] = xf[(m + dm) * 40 + c0 + dc];
        #pragma unroll
        for (int di = 0; di < 4; ++di){
          float av = (&a4[di].x)[dm];
          #pragma unroll
          for (int dc = 0; dc < 5; ++dc)
            acc[di][dc] = fmaf(av, xv[dc], acc[di][dc]);
        }
      }
    }
    #pragma unroll
    for (int di = 0; di < 4; ++di)
      #pragma unroll
      for (int dc = 0; dc < 5; ++dc)
        M2[(i0 + di) * 40 + c0 + dc] = acc[di][dc];
  }
  __syncthreads();

  // H_t[i][j] = leaky(bias[j] + sum_c M2[i][c]*w[c][j]); tile 16i x 4j
  {
    const int j0 = (t & 31) * 4, i0 = (t >> 5) * 16;
    float4 bv = *(const float4*)&bias[j0];
    float acc[16][4];
    #pragma unroll
    for (int di = 0; di < 16; ++di){ acc[di][0]=bv.x; acc[di][1]=bv.y; acc[di][2]=bv.z; acc[di][3]=bv.w; }
    for (int c = 0; c < 40; ++c){
      float4 wv = *(const float4*)&w[c * 128 + j0];
      #pragma unroll
      for (int di = 0; di < 16; ++di){
        float mv = M2[(i0 + di) * 40 + c];
        acc[di][0] = fmaf(mv, wv.x, acc[di][0]);
        acc[di][1] = fmaf(mv, wv.y, acc[di][1]);
        acc[di][2] = fmaf(mv, wv.z, acc[di][2]);
        acc[di][3] = fmaf(mv, wv.w, acc[di][3]);
      }
    }
    float* dst = H + (size_t)b * (N * HG) + 40 * 128;
    #pragma unroll
    for (int di = 0; di < 16; ++di){
      float4 o;
      o.x = (acc[di][0] >= 0.f) ? acc[di][0] : 0.01f * acc[di][0];
      o.y = (acc[di][1] >= 0.f) ? acc[di][1] : 0.01f * acc[di][1];
      o.z = (acc[di][2] >= 0.f) ? acc[di][2] : 0.01f * acc[di][2];
      o.w = (acc[di][3] >= 0.f) ? acc[di][3] : 0.01f * acc[di][3];
      *(float4*)&dst[(i0 + di) * 128 + j0] = o;
    }
  }
}

// out[b] = fc_b + sum_h c4[h]  (c4 = vb-term collapsed: rows of P sum to 1)
__global__ void initout_kernel(float* __restrict__ out, const float* __restrict__ fcb,
                               const float* __restrict__ c4){
  int i = blockIdx.x * 256 + threadIdx.x;
  float base = fcb[0] + c4[0] + c4[1] + c4[2] + c4[3];
  if (i < BSZ) out[i] = base;
}

// ---------- prep: per-head M^T, R = fcw·Wv^T, c1/c2/c3/c4; grid (NH, 11) ----------
__global__ __launch_bounds__(256) void prep_kernel(
    const float* __restrict__ qw, const float* __restrict__ qb,
    const float* __restrict__ kw, const float* __restrict__ kb,
    const float* __restrict__ vw, const float* __restrict__ vb,
    const float* __restrict__ fcw,
    short* __restrict__ MT, short* __restrict__ Rbf,
    float* __restrict__ c1, float* __restrict__ c2,
    float* __restrict__ c3, float* __restrict__ c4){
  const int h = blockIdx.x, sl = blockIdx.y, t = threadIdx.x;
  const float* Q = qw + h * 16384;
  const float* K = kw + h * 16384;
  const float* V = vw + h * 16384;
  if (sl < 8){
    for (int idx = t; idx < 2048; idx += 256){
      int j = sl * 16 + (idx >> 7), d = idx & 127;
      float acc = 0.f;
      for (int e = 0; e < 128; ++e) acc = fmaf(Q[d * 128 + e], K[j * 128 + e], acc);
      MT[h * 16384 + j * 128 + d] = (short)f2bf(acc);     // MT[j][d] = M[d][j]
    }
    if (t < 16){
      int r = sl * 16 + t;
      float a = 0.f, bsum = 0.f;
      for (int e = 0; e < 128; ++e){
        a    = fmaf(Q[r * 128 + e], kb[h * 128 + e], a);
        bsum = fmaf(K[r * 128 + e], qb[h * 128 + e], bsum);
      }
      c1[h * 128 + r] = a;
      c2[h * 128 + r] = bsum;
    }
  }
  // R rows n in [sl*16, sl*16+16); zero-pad n >= 168
  for (int idx = t; idx < 2048; idx += 256){
    int n = sl * 16 + (idx >> 7), d = idx & 127;
    float acc = 0.f;
    if (n < N){
      const float* fr = fcw + n * 512 + h * 128;
      const float* vr = V + d * 128;
      for (int e = 0; e < 128; ++e) acc = fmaf(fr[e], vr[e], acc);
    }
    Rbf[h * 22528 + n * 128 + d] = (short)f2bf(acc);
  }
  if (sl == 0){
    if (t == 0){
      float a = 0.f;
      for (int e = 0; e < 128; ++e) a = fmaf(qb[h * 128 + e], kb[h * 128 + e], a);
      c3[h] = a;
    }
    if (t >= 64 && t < 128){                  // wave 1: c4 reduction
      int l = t - 64;
      float part = 0.f;
      for (int i = l; i < N * 128; i += 64){
        int n = i >> 7, e = i & 127;
        part = fmaf(fcw[n * 512 + h * 128 + e], vb[h * 128 + e], part);
      }
      part = wsum(part);
      if (l == 0) c4[h] = part;
    }
  }
}

// ---------- cast H -> bf16 with zero-padded rows 168..175 ----------
__global__ __launch_bounds__(256) void cast_kernel(const float* __restrict__ H,
                                                   short* __restrict__ Hbf){
  const int b = blockIdx.x;
  for (int idx = threadIdx.x; idx < NPAD * 128; idx += 256){
    int n = idx >> 7, d = idx & 127;
    float v = (n < N) ? H[((size_t)b * N + n) * 128 + d] : 0.f;
    Hbf[(size_t)b * NPAD * 128 + idx] = (short)f2bf(v);
  }
}

// ---------- u1/u2 precompute: u1[n]=H[n]·c1, u2[n]=H[n]·c2 per (b,h) ----------
__global__ __launch_bounds__(256) void uprep_kernel(const short* __restrict__ Hbf,
    const float* __restrict__ c1, const float* __restrict__ c2,
    float* __restrict__ u1g, float* __restrict__ u2g){
  const int b = blockIdx.x, t = threadIdx.x;
  for (int idx = t; idx < 176 * 4; idx += 256){
    int n = idx >> 2, h = idx & 3;
    const bf16x8* rp = (const bf16x8*)(Hbf + (size_t)b * NPAD * 128 + (size_t)n * 128);
    const float* C1 = c1 + h * 128;
    const float* C2 = c2 + h * 128;
    float a1 = 0.f, a2 = 0.f;
    for (int kk = 0; kk < 16; ++kk){
      bf16x8 v = rp[kk];
      #pragma unroll
      for (int j = 0; j < 8; ++j){
        float hv = bf2f((unsigned short)v[j]);
        a1 = fmaf(hv, C1[kk * 8 + j], a1);
        a2 = fmaf(hv, C2[kk * 8 + j], a2);
      }
    }
    u1g[(size_t)(b * 4 + h) * 176 + n] = a1;
    u2g[(size_t)(b * 4 + h) * 176 + n] = a2;
  }
}

// ---------- attention, flash-style, 8-wave block: grid (b) ----------
// Hsh 45KB + Tsh 32KB = 78KB -> 2 blocks/CU. ti task loop is #pragma unroll 1:
// r9's full unroll let the scheduler interleave 6 tasks' operand loads ->
// register blowup -> 432MB scratch spill (WRITE_SIZE canary). One body copy
// keeps per-iteration pressure at r6's proven ~64 VGPR.
__global__ __launch_bounds__(512, 4) void attn_flash(
    const short* __restrict__ Hbf, const short* __restrict__ MT,
    const short* __restrict__ Rbf,
    const float* __restrict__ u1g, const float* __restrict__ u2g,
    const float* __restrict__ c3g, float* __restrict__ out){
  const int b = blockIdx.x;
  const int t = threadIdx.x;
  const int wv = t >> 6, l = t & 63, quad = l >> 4, l15 = l & 15;
  const int h = wv & 3;

  __shared__ __align__(16) short Hsh[NPAD * 128];     // 45KB, swizzled
  __shared__ __align__(16) short Tsh[8 * 2048];       // 32KB, 4KB/wave private
  __shared__ float red8[8];

  const short* Hb = Hbf + (size_t)b * NPAD * 128;

  // ---- cooperative stage: 2816 x 16B units, coalesced global, swizzled LDS ----
  #pragma unroll
  for (int i = 0; i < 6; ++i){
    int idx = t + i * 512;
    if (idx < 2816){
      int row = idx >> 4, g = idx & 15;
      bf16x8 v = *(const bf16x8*)(Hb + row * 128 + g * 8);
      *(bf16x8*)(Hsh + row * 128 + ((g ^ (row & 15)) * 8)) = v;
    }
  }
  __syncthreads();

  const short* MTh = MT + h * 16384;
  const short* Rh  = Rbf + h * 22528;
  const float c3v = c3g[h];
  const float inv = 0.08838834764831845f;   // 1/sqrt(128)
  const float* u1p = u1g + (size_t)(b * 4 + h) * 176;
  const float* u2p = u2g + (size_t)(b * 4 + h) * 176;
  short* Tw = Tsh + wv * 2048;

  float tp = 0.f;
  #pragma unroll 1
  for (int ti = 0; ti < 6; ++ti){
    const int zt = (wv >> 2) + ti * 2;
    if (zt < 11){                                  // wave-uniform guard
      const int rowbase = zt * 16;

      // A-frags (H rows, from LDS) and R-frags (global, L2-hot)
      bf16x8 HA[4], RA[4];
      #pragma unroll
      for (int kk = 0; kk < 4; ++kk){
        HA[kk] = *(const bf16x8*)(Hsh + (rowbase + l15) * 128 + (((kk * 4 + quad) ^ l15) * 8));
        RA[kk] = *(const bf16x8*)(Rh + (rowbase + l15) * 128 + kk * 32 + quad * 8);
      }
      float u1v[4];
      #pragma unroll
      for (int r = 0; r < 4; ++r) u1v[r] = u1p[rowbase + quad * 4 + r];

      // ---- Phase A: T = H_chunk @ M -> private LDS slice (XOR-swizzled) ----
      #pragma unroll
      for (int jt = 0; jt < 8; ++jt){
        const int j0 = jt * 16;
        f32x4 acc = {0.f, 0.f, 0.f, 0.f};
        #pragma unroll
        for (int kk = 0; kk < 4; ++kk){
          bf16x8 Bv = *(const bf16x8*)(MTh + (j0 + l15) * 128 + kk * 32 + quad * 8);
          acc = __builtin_amdgcn_mfma_f32_16x16x32_bf16(HA[kk], Bv, acc, 0, 0, 0);
        }
        const int jcol = j0 + l15, ch = jcol >> 3;
        #pragma unroll
        for (int r = 0; r < 4; ++r){
          int row = quad * 4 + r;
          Tw[row * 128 + ((ch ^ row) << 3) + (jcol & 7)] = (short)f2bf(acc[r]);
        }
      }
      // no barrier: same-wave DS ops are ordered

      // ---- Phase BG + per-lane online softmax over 11 m-tiles ----
      float Mx[4], Av[4], Dv[4];
      #pragma unroll
      for (int r = 0; r < 4; ++r){ Mx[r] = -1e30f; Av[r] = 0.f; Dv[r] = 0.f; }

      #pragma unroll
      for (int mt = 0; mt < 11; ++mt){
        const int m0 = mt * 16;
        bf16x8 Bv[4];
        #pragma unroll
        for (int kk = 0; kk < 4; ++kk)
          Bv[kk] = *(const bf16x8*)(Hsh + (m0 + l15) * 128 + (((kk * 4 + quad) ^ l15) * 8));
        const float u2v = u2p[m0 + l15];
        f32x4 acc = {0.f, 0.f, 0.f, 0.f};
        f32x4 g   = {0.f, 0.f, 0.f, 0.f};
        #pragma unroll
        for (int kk = 0; kk < 4; ++kk){
          bf16x8 A = *(const bf16x8*)(Tw + l15 * 128 + (((kk * 4 + quad) ^ l15) << 3));
          acc = __builtin_amdgcn_mfma_f32_16x16x32_bf16(A, Bv[kk], acc, 0, 0, 0);
          g   = __builtin_amdgcn_mfma_f32_16x16x32_bf16(RA[kk], Bv[kk], g, 0, 0, 0);
        }
        const bool padcol = (mt == 10) && (l15 >= 8);     // cols 168..175 masked
        #pragma unroll
        for (int r = 0; r < 4; ++r){
          float s = padcol ? -1e30f : (acc[r] + u1v[r] + u2v + c3v) * inv;
          float Mn = fmaxf(Mx[r], s);
          float ea = __expf(Mx[r] - Mn);
          float eb = __expf(s - Mn);
          Av[r] = fmaf(Av[r], ea, eb * g[r]);
          Dv[r] = fmaf(Dv[r], ea, eb);
          Mx[r] = Mn;
        }
      }

      // ---- merge (M,A,D) across the 16 l15 lanes (stays within quad) ----
      #pragma unroll
      for (int r = 0; r < 4; ++r){
        #pragma unroll
        for (int o = 1; o < 16; o <<= 1){
          float M2 = __shfl_xor(Mx[r], o, 64);
          float A2 = __shfl_xor(Av[r], o, 64);
          float D2 = __shfl_xor(Dv[r], o, 64);
          float Mn = fmaxf(Mx[r], M2);
          float ea = __expf(Mx[r] - Mn);
          float eb = __expf(M2 - Mn);
          Av[r] = fmaf(Av[r], ea, A2 * eb);
          Dv[r] = fmaf(Dv[r], ea, D2 * eb);
          Mx[r] = Mn;
        }
      }

      // ---- per-row A/D, replicated over 16 lanes -> scale by 1/16 ----
      #pragma unroll
      for (int r = 0; r < 4; ++r){
        int n = rowbase + quad * 4 + r;
        if (n < N) tp += Av[r] / Dv[r];
      }
    }
  }
  tp *= (1.0f / 16.0f);

  // ---- block reduction over 8 waves ----
  #pragma unroll
  for (int o = 32; o > 0; o >>= 1) tp += __shfl_down(tp, o, 64);
  if (l == 0) red8[wv] = tp;
  __syncthreads();
  if (t == 0){
    float s = 0.f;
    #pragma unroll
    for (int i = 0; i < 8; ++i) s += red8[i];
    atomicAdd(out + b, s);
  }
}

} // anonymous namespace

extern "C" void kernel_launch(void* const* d_in, const int* in_sizes, int n_in,
                              void* d_out, int out_size, void* d_ws, size_t ws_size,
                              hipStream_t stream) {
  (void)in_sizes; (void)n_in; (void)out_size;
  const float* X      = (const float*)d_in[0];
  const float* spa_w1 = (const float*)d_in[1];
  const float* spa_b1 = (const float*)d_in[2];
  const float* spa_w2 = (const float*)d_in[3];
  const float* spa_b2 = (const float*)d_in[4];
  const float* tem_w1 = (const float*)d_in[5];
  const float* tem_b1 = (const float*)d_in[6];
  const float* tem_w2 = (const float*)d_in[7];
  const float* tem_b2 = (const float*)d_in[8];
  const float* sgnn_w = (const float*)d_in[9];
  const float* sgnn_b = (const float*)d_in[10];
  const float* tgnn_w = (const float*)d_in[11];
  const float* tgnn_b = (const float*)d_in[12];
  const float* q_w    = (const float*)d_in[13];
  const float* q_b    = (const float*)d_in[14];
  const float* k_w    = (const float*)d_in[15];
  const float* k_b    = (const float*)d_in[16];
  const float* v_w    = (const float*)d_in[17];
  const float* v_b    = (const float*)d_in[18];
  const float* fc_w   = (const float*)d_in[19];
  const float* fc_b   = (const float*)d_in[20];
  float* out = (float*)d_out;

  if (ws_size < (size_t)182714368) return;

  char* wsb = (char*)d_ws;
  float* H   = (float*)wsb;                      // fp32 H [0, 88MB)
  float* u1g = (float*)(wsb + 50331648);         // overlays dead-H region (H dead after cast)
  float* u2g = (float*)(wsb + 53215232);
  char*  Rb  = wsb + 88080384;
  float* Xf  = (float*)Rb;
  float* As  = (float*)(Rb + 20971520);
  float* At  = (float*)(Rb + 27525120);
  short* Hbf = (short*)Rb;                       // overlays dead Xf/As/At after ht
  char*  Pb  = Rb + 46137344;
  short* MT  = (short*)Pb;                       // 131072 B
  short* Rbf = (short*)(Pb + 131072);            // 180224 B (4 heads x 176 x 128 bf16)
  float* c1  = (float*)(Pb + 311296);
  float* c2  = (float*)(Pb + 313344);
  float* c3  = (float*)(Pb + 315392);
  float* c4  = (float*)(Pb + 315408);
  float* twg = (float*)(Pb + 327680);            // 32KB twiddle table

  twiddle_kernel<<<16, 256, 0, stream>>>(twg);
  feat_kernel<<<BSZ * P / 4, 256, 0, stream>>>(X, twg, Xf);
  cumnorm_kernel<<<BSZ, 256, 0, stream>>>(Xf);
  adjt_kernel<<<BSZ, 256, 0, stream>>>(Xf, tem_w1, tem_b1, tem_w2, tem_b2, At);
  adjs_kernel<<<BSZ, 256, 0, stream>>>(Xf, spa_w1, spa_b1, spa_w2, spa_b2, As);
  hs_kernel<<<BSZ, 256, 0, stream>>>(Xf, As, sgnn_w, sgnn_b, H);
  ht_kernel<<<BSZ, 256, 0, stream>>>(Xf, At, tgnn_w, tgnn_b, H);
  prep_kernel<<<dim3(NH, 11), 256, 0, stream>>>(q_w, q_b, k_w, k_b, v_w, v_b, fc_w,
                                                MT, Rbf, c1, c2, c3, c4);
  cast_kernel<<<BSZ, 256, 0, stream>>>(H, Hbf);          // H fp32 dead after this
  uprep_kernel<<<BSZ, 256, 0, stream>>>(Hbf, c1, c2, u1g, u2g);
  initout_kernel<<<4, 256, 0, stream>>>(out, fc_b, c4);
  attn_flash<<<dim3(BSZ), 512, 0, stream>>>(Hbf, MT, Rbf, u1g, u2g, c3, out);
}

// Round 11
// 1037.373 us; speedup vs baseline: 1.3475x; 1.1580x over previous
//
#include <hip/hip_runtime.h>
#include <math.h>

namespace {

constexpr int BSZ  = 1024;
constexpr int P    = 128;
constexpr int HG   = 128;
constexpr int NH   = 4;
constexpr int N    = 168;     // P + IND
constexpr int NPAD = 176;     // padded token count (11 tiles of 16)

typedef short bf16x8 __attribute__((ext_vector_type(8)));
typedef float f32x4  __attribute__((ext_vector_type(4)));
typedef short short4v __attribute__((ext_vector_type(4)));

__device__ __forceinline__ unsigned short f2bf(float x){
  union { float f; unsigned u; } v; v.f = x;
  unsigned r = (v.u + 0x7FFF + ((v.u >> 16) & 1)) >> 16;
  return (unsigned short)r;
}
__device__ __forceinline__ float bf2f(unsigned short b){
  union { unsigned u; float f; } v; v.u = ((unsigned)b) << 16;
  return v.f;
}

// ---------- wave (64-lane) butterfly reductions: result in ALL lanes ----------
__device__ __forceinline__ float wsum(float v){
  #pragma unroll
  for (int o = 1; o < 64; o <<= 1) v += __shfl_xor(v, o, 64);
  return v;
}
__device__ __forceinline__ float wmax(float v){
  #pragma unroll
  for (int o = 1; o < 64; o <<= 1) v = fmaxf(v, __shfl_xor(v, o, 64));
  return v;
}
__device__ __forceinline__ float wmin(float v){
  #pragma unroll
  for (int o = 1; o < 64; o <<= 1) v = fminf(v, __shfl_xor(v, o, 64));
  return v;
}
__device__ __forceinline__ float rsum256(float v, volatile float* red4){
  #pragma unroll
  for (int o = 32; o > 0; o >>= 1) v += __shfl_down(v, o, 64);
  __syncthreads();
  if ((threadIdx.x & 63) == 0) red4[threadIdx.x >> 6] = v;
  __syncthreads();
  return red4[0] + red4[1] + red4[2] + red4[3];
}

// ---------- twiddle table: tw[tt*64+l] = cos(2pi*(l*tt mod 128)/128),
//            tw[4096+...] = -sin(...)  (matches old recurrence convention) ----------
__global__ void twiddle_kernel(float* __restrict__ tw){
  int i = blockIdx.x * 256 + threadIdx.x;
  if (i < 4096){
    int tt = i >> 6, l = i & 63;
    int k = (l * tt) & 127;
    float ang = (float)k * (-0.049087385212340517f);   // -2*pi/128
    tw[i]        = cosf(ang);
    tw[4096 + i] = sinf(ang);                          // = -sin(+ang')
  }
}

// ---------- K1: per-patch features, one WAVE per patch ----------
// DFT via LDS twiddle table; median via 31-step radix-select on float bits.
__global__ __launch_bounds__(256) void feat_kernel(const float* __restrict__ X,
                                                   const float* __restrict__ twg,
                                                   float* __restrict__ Xf){
  const int wave = threadIdx.x >> 6, l = threadIdx.x & 63;
  const int pp = blockIdx.x * 4 + wave;          // patch id
  const float* xp = X + (size_t)pp * 128;
  const float x0 = xp[l];
  const float x1 = xp[l + 64];

  __shared__ float tws[8192];                    // 32KB: cos[4096], -sin[4096]
  for (int idx = threadIdx.x; idx < 2048; idx += 256)
    *((float4*)tws + idx) = *((const float4*)twg + idx);
  __syncthreads();

  // ---- temporal ----
  float sum   = wsum(x0 + x1);
  float mean  = sum * (1.0f / 128.0f);
  float mx    = wmax(fmaxf(x0, x1));
  float mn    = wmin(fminf(x0, x1));
  float sumsq = wsum(fmaf(x0, x0, x1 * x1));
  float c0 = x0 - mean, c1_ = x1 - mean;
  float c0q = c0 * c0, c1q = c1_ * c1_;
  float m2 = wsum(c0q + c1q);
  float m3 = wsum(c0q * c0 + c1q * c1_);
  float m4 = wsum(c0q * c0q + c1q * c1q);
  float var = m2 * (1.0f / 127.0f);
  float sd  = sqrtf(var);
  float rms = sqrtf(sumsq * (1.0f / 128.0f));
  float ex0 = expf(x0 - mx), ex1 = expf(x1 - mx);
  float Z   = wsum(ex0 + ex1);
  float SxE = wsum(fmaf(ex0, x0, ex1 * x1));
  float ent = (mx + logf(Z)) - SxE / Z;
  const float lo = (float)(-1.0 + 1e-7), hi = (float)(1.0 - 1e-7);
  float a0 = asinf(fminf(fmaxf(x0, lo), hi));
  float a1 = asinf(fminf(fmaxf(x1, lo), hi));
  float amean = wsum(a0 + a1) * (1.0f / 128.0f);
  float ad0 = a0 - amean, ad1 = a1 - amean;
  float std_asin = sqrtf(wsum(fmaf(ad0, ad0, ad1 * ad1)) * (1.0f / 127.0f));
  float b0 = atanf(x0), b1v = atanf(x1);
  float bmean = wsum(b0 + b1v) * (1.0f / 128.0f);
  float bd0 = b0 - bmean, bd1 = b1v - bmean;
  float std_atan = sqrtf(wsum(fmaf(bd0, bd0, bd1 * bd1)) * (1.0f / 127.0f));
  float kurt = (m4 * (1.0f / 128.0f)) / (sd * sd * sd * sd) - 3.0f;
  float skew = (m3 * (1.0f / 128.0f)) / (sd * sd * sd);

  // ---- DFT: lane l computes bin l; twiddles from LDS table ----
  const float sign = (l & 1) ? -1.0f : 1.0f;
  const int x0i = __float_as_int(x0), x1i = __float_as_int(x1);
  float re = 0.f, im = 0.f;
  #pragma unroll
  for (int tt = 0; tt < 64; ++tt){
    float s0v = __int_as_float(__builtin_amdgcn_readlane(x0i, tt));
    float s1v = __int_as_float(__builtin_amdgcn_readlane(x1i, tt));
    float se = fmaf(sign, s1v, s0v);
    float wc  = tws[tt * 64 + l];
    float wsv = tws[4096 + tt * 64 + l];
    re = fmaf(se, wc, re);
    im = fmaf(se, wsv, im);
  }
  float psd = fmaf(re, re, im * im) * 0.0078125f;          // bins 0..63 (lane l)
  float re64 = wsum(sign * (x0 + x1));                     // bin 64
  float psd64 = re64 * re64 * 0.0078125f;

  const float mult = (l == 0) ? 1.f : 2.f;
  float psum = wsum(psd * mult) + psd64;
  float p2   = wsum(psd * psd * mult) + psd64 * psd64;
  float vm   = wmax(psd);
  float maxp = fmaxf(vm, psd64);
  float meanfreq = (-0.5f * psd64) / psum;
  float pbw = sqrtf(p2 / psum);
  unsigned long long am = __ballot(psd == vm);             // first-index argmax
  int lmin = __builtin_ctzll(am);
  float fmaxv = (psd64 > vm) ? -0.5f : (float)lmin * (1.0f / 128.0f);
  float maxamp = sqrtf(maxp * 128.0f);

  // ---- median via radix-select on float bits (rank 64 of 128 weighted) ----
  const unsigned pu   = __float_as_uint(psd);
  const unsigned pu64 = __float_as_uint(psd64);
  unsigned Pv = 0u;
  #pragma unroll
  for (int bit = 30; bit >= 0; --bit){
    unsigned T = Pv | (1u << bit);
    unsigned long long m = __ballot(pu < T);
    int c = 2 * __popcll(m) - (int)(m & 1ull) + ((pu64 < T) ? 1 : 0);
    if (c <= 64) Pv = T;                 // rank-64 value >= T
  }
  float med;
  {
    unsigned long long em = __ballot(pu == Pv);
    unsigned long long m2b = __ballot(pu < Pv);
    int less = 2 * __popcll(m2b) - (int)(m2b & 1ull) + ((pu64 < Pv) ? 1 : 0);
    if (em){
      int kt = (int)__builtin_ctzll(em);
      med = (less == 64) ? (float)kt * (1.0f / 128.0f)
                         : -(float)kt * (1.0f / 128.0f);   // less==63: 2nd copy, neg freq
    } else {
      med = -0.5f;                        // rank-64 element is bin 64
    }
  }

  if (l == 0){
    float* o = Xf + (size_t)pp * 40;
    o[0]  = mx;  o[1]  = mn;  o[2]  = sd;   o[3]  = rms; o[4]  = mean;
    o[5]  = mx - mn;  o[6] = var;  o[7] = ent; o[8] = std_asin; o[9] = std_atan;
    o[10] = kurt; o[11] = skew;
    o[12] = meanfreq;
    o[13] = med;
    o[14] = psum;
    o[15] = 1.0f;
    o[16] = pbw;
    o[17] = maxp;
    o[18] = maxamp;
    o[19] = fmaxv;
  }
}

// ---------- K2: cumsum feature + per-sample normalization ----------
__global__ __launch_bounds__(256) void cumnorm_kernel(float* __restrict__ Xf){
  const int b = blockIdx.x, t = threadIdx.x;
  __shared__ float arr[128 * 40];
  __shared__ float red4[4];
  float* base = Xf + b * 5120;
  for (int idx = t; idx < 128 * 20; idx += 256){
    int p = idx / 20, c = idx - p * 20;
    arr[p * 40 + c] = base[p * 40 + c];
  }
  __syncthreads();
  if (t < 20){
    float acc = 0.f;
    for (int p = 0; p < 128; ++p){
      acc += arr[p * 40 + t];
      arr[p * 40 + 20 + t] = acc / sqrtf(fmaxf(fabsf(acc), 1e-12f));
    }
  }
  __syncthreads();
  float pa = 0.f;
  for (int idx = t; idx < 5120; idx += 256){ float v = arr[idx]; pa = fmaf(v, v, pa); }
  float nrm = sqrtf(rsum256(pa, red4));
  for (int idx = t; idx < 5120; idx += 256) base[idx] = arr[idx] / nrm;
}

// ---------- K3: A_t (register-tiled fp32) ----------
__global__ __launch_bounds__(256) void adjt_kernel(const float* __restrict__ Xf,
    const float* __restrict__ w1, const float* __restrict__ b1,
    const float* __restrict__ w2, const float* __restrict__ b2,
    float* __restrict__ At){
  const int b = blockIdx.x, t = threadIdx.x;
  __shared__ float xf[5120];          // stride 40
  __shared__ float T[128 * 64];
  const float* src = Xf + b * 5120;
  for (int idx = t; idx < 1280; idx += 256)
    *((float4*)xf + idx) = *((const float4*)src + idx);
  __syncthreads();

  // T1[i][k] = tanh(b1[k] + sum_c xf[i][c]*w1[c][k]); tile 8i x 4k per thread
  {
    const int k0 = (t & 15) * 4, i0 = (t >> 4) * 8;
    float4 bv = *(const float4*)&b1[k0];
    float acc[8][4];
    #pragma unroll
    for (int di = 0; di < 8; ++di){ acc[di][0]=bv.x; acc[di][1]=bv.y; acc[di][2]=bv.z; acc[di][3]=bv.w; }
    for (int c = 0; c < 40; ++c){
      float4 wv = *(const float4*)&w1[c * 64 + k0];
      #pragma unroll
      for (int di = 0; di < 8; ++di){
        float xv = xf[(i0 + di) * 40 + c];
        acc[di][0] = fmaf(xv, wv.x, acc[di][0]);
        acc[di][1] = fmaf(xv, wv.y, acc[di][1]);
        acc[di][2] = fmaf(xv, wv.z, acc[di][2]);
        acc[di][3] = fmaf(xv, wv.w, acc[di][3]);
      }
    }
    #pragma unroll
    for (int di = 0; di < 8; ++di){
      float4 o;
      o.x = tanhf(acc[di][0]); o.y = tanhf(acc[di][1]);
      o.z = tanhf(acc[di][2]); o.w = tanhf(acc[di][3]);
      *(float4*)&T[(i0 + di) * 64 + k0] = o;
    }
  }
  __syncthreads();

  // A_t[i][j] = b2[j] + sum_k T[i][k]*w2[k][j]; tile 16i x 4j per thread
  {
    const int j0 = (t & 31) * 4, i0 = (t >> 5) * 16;
    float4 bv = *(const float4*)&b2[j0];
    float acc[16][4];
    #pragma unroll
    for (int di = 0; di < 16; ++di){ acc[di][0]=bv.x; acc[di][1]=bv.y; acc[di][2]=bv.z; acc[di][3]=bv.w; }
    for (int k = 0; k < 64; ++k){
      float4 wv = *(const float4*)&w2[k * 128 + j0];
      #pragma unroll
      for (int di = 0; di < 16; ++di){
        float tv = T[(i0 + di) * 64 + k];
        acc[di][0] = fmaf(tv, wv.x, acc[di][0]);
        acc[di][1] = fmaf(tv, wv.y, acc[di][1]);
        acc[di][2] = fmaf(tv, wv.z, acc[di][2]);
        acc[di][3] = fmaf(tv, wv.w, acc[di][3]);
      }
    }
    float* dst = At + (size_t)b * 16384;
    #pragma unroll
    for (int di = 0; di < 16; ++di)
      *(float4*)&dst[(i0 + di) * 128 + j0] = *(float4*)acc[di];
  }
}

// ---------- K4: A_s ----------
__global__ __launch_bounds__(256) void adjs_kernel(const float* __restrict__ Xf,
    const float* __restrict__ w1, const float* __restrict__ b1,
    const float* __restrict__ w2, const float* __restrict__ b2,
    float* __restrict__ As){
  const int b = blockIdx.x, t = threadIdx.x;
  __shared__ float xf[5120];
  __shared__ float T2[40 * 64];
  const float* src = Xf + b * 5120;
  for (int idx = t; idx < 1280; idx += 256)
    *((float4*)xf + idx) = *((const float4*)src + idx);
  __syncthreads();
  for (int idx = t; idx < 40 * 64; idx += 256){
    int i = idx >> 6, k = idx & 63;
    float acc = b1[k];
    for (int p = 0; p < 128; ++p) acc = fmaf(xf[p * 40 + i], w1[p * 64 + k], acc);
    T2[idx] = tanhf(acc);
  }
  __syncthreads();
  float* dst = As + b * 1600;
  for (int idx = t; idx < 1600; idx += 256){
    int i = idx / 40, j = idx - i * 40;
    float acc = b2[j];
    #pragma unroll 8
    for (int k = 0; k < 64; ++k) acc = fmaf(T2[i * 64 + k], w2[k * 40 + j], acc);
    dst[idx] = acc;
  }
}

// ---------- K5: H_s (register-tiled) -> writes bf16 Hbf rows 0..39 directly ----------
__global__ __launch_bounds__(256) void hs_kernel(const float* __restrict__ Xf,
    const float* __restrict__ As_g, const float* __restrict__ w, const float* __restrict__ bias,
    short* __restrict__ Hbf){
  const int b = blockIdx.x, t = threadIdx.x;
  __shared__ float xf[5120];          // stride 40
  __shared__ float As[1600];
  __shared__ float M[40 * 128];
  const float* src = Xf + b * 5120;
  for (int idx = t; idx < 1280; idx += 256)
    *((float4*)xf + idx) = *((const float4*)src + idx);
  for (int idx = t; idx < 400; idx += 256)
    *((float4*)As + idx) = *((const float4*)(As_g + b * 1600) + idx);
  __syncthreads();

  // M[i][p] = sum_m As[i][m] * xf[p][m]; tile 5i x 4p, m in float4 steps
  {
    const int p0 = (t & 31) * 4, i0 = (t >> 5) * 5;
    float acc[5][4];
    #pragma unroll
    for (int di = 0; di < 5; ++di)
      #pragma unroll
      for (int dp = 0; dp < 4; ++dp) acc[di][dp] = 0.f;
    for (int m = 0; m < 40; m += 4){
      float4 a4[5], x4[4];
      #pragma unroll
      for (int di = 0; di < 5; ++di) a4[di] = *(const float4*)&As[(i0 + di) * 40 + m];
      #pragma unroll
      for (int dp = 0; dp < 4; ++dp) x4[dp] = *(const float4*)&xf[(p0 + dp) * 40 + m];
      #pragma unroll
      for (int dm = 0; dm < 4; ++dm)
        #pragma unroll
        for (int di = 0; di < 5; ++di){
          float av = (&a4[di].x)[dm];
          #pragma unroll
          for (int dp = 0; dp < 4; ++dp)
            acc[di][dp] = fmaf(av, (&x4[dp].x)[dm], acc[di][dp]);
        }
    }
    #pragma unroll
    for (int di = 0; di < 5; ++di)
      *(float4*)&M[(i0 + di) * 128 + p0] = *(float4*)acc[di];
  }
  __syncthreads();

  // H_s[i][j] = leaky(bias[j] + sum_p M[i][p]*w[p][j]); tile 5i x 4j; bf16 out
  {
    const int j0 = (t & 31) * 4, i0 = (t >> 5) * 5;
    float4 bv = *(const float4*)&bias[j0];
    float acc[5][4];
    #pragma unroll
    for (int di = 0; di < 5; ++di){ acc[di][0]=bv.x; acc[di][1]=bv.y; acc[di][2]=bv.z; acc[di][3]=bv.w; }
    for (int p = 0; p < 128; ++p){
      float4 wv = *(const float4*)&w[p * 128 + j0];
      #pragma unroll
      for (int di = 0; di < 5; ++di){
        float mv = M[(i0 + di) * 128 + p];
        acc[di][0] = fmaf(mv, wv.x, acc[di][0]);
        acc[di][1] = fmaf(mv, wv.y, acc[di][1]);
        acc[di][2] = fmaf(mv, wv.z, acc[di][2]);
        acc[di][3] = fmaf(mv, wv.w, acc[di][3]);
      }
    }
    short* dst = Hbf + (size_t)b * NPAD * 128;
    #pragma unroll
    for (int di = 0; di < 5; ++di){
      short4v o;
      #pragma unroll
      for (int q = 0; q < 4; ++q){
        float v = acc[di][q];
        v = (v >= 0.f) ? v : 0.01f * v;
        o[q] = (short)f2bf(v);
      }
      *(short4v*)&dst[(i0 + di) * 128 + j0] = o;
    }
  }
}

// ---------- K6: H_t (register-tiled) -> bf16 Hbf rows 40..167 + zero pad 168..175 ----------
__global__ __launch_bounds__(256) void ht_kernel(const float* __restrict__ Xf,
    const float* __restrict__ At_g, const float* __restrict__ w, const float* __restrict__ bias,
    short* __restrict__ Hbf){
  const int b = blockIdx.x, t = threadIdx.x;
  __shared__ float xf[5120];          // stride 40
  __shared__ float M2[128 * 40];
  const float* src = Xf + b * 5120;
  for (int idx = t; idx < 1280; idx += 256)
    *((float4*)xf + idx) = *((const float4*)src + idx);
  // zero-pad rows 168..175 (independent region, no barrier needed vs xf load)
  {
    short* padp = Hbf + (size_t)b * NPAD * 128 + 168 * 128;
    for (int idx = t; idx < 256; idx += 256)
      *(float2*)&padp[idx * 4] = (float2){0.f, 0.f};
  }
  __syncthreads();

  // M2[i][c] = sum_m At[i][m] * xf[m][c]; tile 4i x 5c, m in float4 steps
  {
    const int c0 = (t & 7) * 5, i0 = (t >> 3) * 4;
    const float* At = At_g + (size_t)b * 16384;
    float acc[4][5];
    #pragma unroll
    for (int di = 0; di < 4; ++di)
      #pragma unroll
      for (int dc = 0; dc < 5; ++dc) acc[di][dc] = 0.f;
    for (int m = 0; m < 128; m += 4){
      float4 a4[4];
      #pragma unroll
      for (int di = 0; di < 4; ++di) a4[di] = *(const float4*)&At[(i0 + di) * 128 + m];
      #pragma unroll
      for (int dm = 0; dm < 4; ++dm){
        float xv[5];
        #pragma unroll
        for (int dc = 0; dc < 5; ++dc) xv[dc] = xf[(m + dm) * 40 + c0 + dc];
        #pragma unroll
        for (int di = 0; di < 4; ++di){
          float av = (&a4[di].x)[dm];
          #pragma unroll
          for (int dc = 0; dc < 5; ++dc)
            acc[di][dc] = fmaf(av, xv[dc], acc[di][dc]);
        }
      }
    }
    #pragma unroll
    for (int di = 0; di < 4; ++di)
      #pragma unroll
      for (int dc = 0; dc < 5; ++dc)
        M2[(i0 + di) * 40 + c0 + dc] = acc[di][dc];
  }
  __syncthreads();

  // H_t[i][j] = leaky(bias[j] + sum_c M2[i][c]*w[c][j]); tile 16i x 4j; bf16 out
  {
    const int j0 = (t & 31) * 4, i0 = (t >> 5) * 16;
    float4 bv = *(const float4*)&bias[j0];
    float acc[16][4];
    #pragma unroll
    for (int di = 0; di < 16; ++di){ acc[di][0]=bv.x; acc[di][1]=bv.y; acc[di][2]=bv.z; acc[di][3]=bv.w; }
    for (int c = 0; c < 40; ++c){
      float4 wv = *(const float4*)&w[c * 128 + j0];
      #pragma unroll
      for (int di = 0; di < 16; ++di){
        float mv = M2[(i0 + di) * 40 + c];
        acc[di][0] = fmaf(mv, wv.x, acc[di][0]);
        acc[di][1] = fmaf(mv, wv.y, acc[di][1]);
        acc[di][2] = fmaf(mv, wv.z, acc[di][2]);
        acc[di][3] = fmaf(mv, wv.w, acc[di][3]);
      }
    }
    short* dst = Hbf + (size_t)b * NPAD * 128 + 40 * 128;
    #pragma unroll
    for (int di = 0; di < 16; ++di){
      short4v o;
      #pragma unroll
      for (int q = 0; q < 4; ++q){
        float v = acc[di][q];
        v = (v >= 0.f) ? v : 0.01f * v;
        o[q] = (short)f2bf(v);
      }
      *(short4v*)&dst[(i0 + di) * 128 + j0] = o;
    }
  }
}

// out[b] = fc_b + sum_h c4[h]  (c4 = vb-term collapsed: rows of P sum to 1)
__global__ void initout_kernel(float* __restrict__ out, const float* __restrict__ fcb,
                               const float* __restrict__ c4){
  int i = blockIdx.x * 256 + threadIdx.x;
  float base = fcb[0] + c4[0] + c4[1] + c4[2] + c4[3];
  if (i < BSZ) out[i] = base;
}

// ---------- prep: per-head M^T, R = fcw·Wv^T, c1/c2/c3/c4; grid (NH, 11) ----------
__global__ __launch_bounds__(256) void prep_kernel(
    const float* __restrict__ qw, const float* __restrict__ qb,
    const float* __restrict__ kw, const float* __restrict__ kb,
    const float* __restrict__ vw, const float* __restrict__ vb,
    const float* __restrict__ fcw,
    short* __restrict__ MT, short* __restrict__ Rbf,
    float* __restrict__ c1, float* __restrict__ c2,
    float* __restrict__ c3, float* __restrict__ c4){
  const int h = blockIdx.x, sl = blockIdx.y, t = threadIdx.x;
  const float* Q = qw + h * 16384;
  const float* K = kw + h * 16384;
  const float* V = vw + h * 16384;
  if (sl < 8){
    for (int idx = t; idx < 2048; idx += 256){
      int j = sl * 16 + (idx >> 7), d = idx & 127;
      float acc = 0.f;
      for (int e = 0; e < 128; ++e) acc = fmaf(Q[d * 128 + e], K[j * 128 + e], acc);
      MT[h * 16384 + j * 128 + d] = (short)f2bf(acc);     // MT[j][d] = M[d][j]
    }
    if (t < 16){
      int r = sl * 16 + t;
      float a = 0.f, bsum = 0.f;
      for (int e = 0; e < 128; ++e){
        a    = fmaf(Q[r * 128 + e], kb[h * 128 + e], a);
        bsum = fmaf(K[r * 128 + e], qb[h * 128 + e], bsum);
      }
      c1[h * 128 + r] = a;
      c2[h * 128 + r] = bsum;
    }
  }
  // R rows n in [sl*16, sl*16+16); zero-pad n >= 168
  for (int idx = t; idx < 2048; idx += 256){
    int n = sl * 16 + (idx >> 7), d = idx & 127;
    float acc = 0.f;
    if (n < N){
      const float* fr = fcw + n * 512 + h * 128;
      const float* vr = V + d * 128;
      for (int e = 0; e < 128; ++e) acc = fmaf(fr[e], vr[e], acc);
    }
    Rbf[h * 22528 + n * 128 + d] = (short)f2bf(acc);
  }
  if (sl == 0){
    if (t == 0){
      float a = 0.f;
      for (int e = 0; e < 128; ++e) a = fmaf(qb[h * 128 + e], kb[h * 128 + e], a);
      c3[h] = a;
    }
    if (t >= 64 && t < 128){                  // wave 1: c4 reduction
      int l = t - 64;
      float part = 0.f;
      for (int i = l; i < N * 128; i += 64){
        int n = i >> 7, e = i & 127;
        part = fmaf(fcw[n * 512 + h * 128 + e], vb[h * 128 + e], part);
      }
      part = wsum(part);
      if (l == 0) c4[h] = part;
    }
  }
}

// ---------- u1/u2 precompute: u1[n]=H[n]·c1, u2[n]=H[n]·c2 per (b,h) ----------
__global__ __launch_bounds__(256) void uprep_kernel(const short* __restrict__ Hbf,
    const float* __restrict__ c1, const float* __restrict__ c2,
    float* __restrict__ u1g, float* __restrict__ u2g){
  const int b = blockIdx.x, t = threadIdx.x;
  for (int idx = t; idx < 176 * 4; idx += 256){
    int n = idx >> 2, h = idx & 3;
    const bf16x8* rp = (const bf16x8*)(Hbf + (size_t)b * NPAD * 128 + (size_t)n * 128);
    const float* C1 = c1 + h * 128;
    const float* C2 = c2 + h * 128;
    float a1 = 0.f, a2 = 0.f;
    for (int kk = 0; kk < 16; ++kk){
      bf16x8 v = rp[kk];
      #pragma unroll
      for (int j = 0; j < 8; ++j){
        float hv = bf2f((unsigned short)v[j]);
        a1 = fmaf(hv, C1[kk * 8 + j], a1);
        a2 = fmaf(hv, C2[kk * 8 + j], a2);
      }
    }
    u1g[(size_t)(b * 4 + h) * 176 + n] = a1;
    u2g[(size_t)(b * 4 + h) * 176 + n] = a2;
  }
}

// ---------- attention, flash-style, 8-wave block: grid (b) ----------
// Hsh 45KB + Tsh 32KB = 78KB -> 2 blocks/CU (LDS-limited). launch_bounds(512,2):
// r10's (512,4) made the allocator cap at 64 VGPR -> 124MB residual spill;
// (512,2) allows ~128 VGPR (still 2 blocks/CU via LDS) -> no spill.
// ti task loop stays #pragma unroll 1 (r9 lesson: full unroll -> 432MB spill).
__global__ __launch_bounds__(512, 2) void attn_flash(
    const short* __restrict__ Hbf, const short* __restrict__ MT,
    const short* __restrict__ Rbf,
    const float* __restrict__ u1g, const float* __restrict__ u2g,
    const float* __restrict__ c3g, float* __restrict__ out){
  const int b = blockIdx.x;
  const int t = threadIdx.x;
  const int wv = t >> 6, l = t & 63, quad = l >> 4, l15 = l & 15;
  const int h = wv & 3;

  __shared__ __align__(16) short Hsh[NPAD * 128];     // 45KB, swizzled
  __shared__ __align__(16) short Tsh[8 * 2048];       // 32KB, 4KB/wave private
  __shared__ float red8[8];

  const short* Hb = Hbf + (size_t)b * NPAD * 128;

  // ---- cooperative stage: 2816 x 16B units, coalesced global, swizzled LDS ----
  #pragma unroll
  for (int i = 0; i < 6; ++i){
    int idx = t + i * 512;
    if (idx < 2816){
      int row = idx >> 4, g = idx & 15;
      bf16x8 v = *(const bf16x8*)(Hb + row * 128 + g * 8);
      *(bf16x8*)(Hsh + row * 128 + ((g ^ (row & 15)) * 8)) = v;
    }
  }
  __syncthreads();

  const short* MTh = MT + h * 16384;
  const short* Rh  = Rbf + h * 22528;
  const float c3v = c3g[h];
  const float inv = 0.08838834764831845f;   // 1/sqrt(128)
  const float* u1p = u1g + (size_t)(b * 4 + h) * 176;
  const float* u2p = u2g + (size_t)(b * 4 + h) * 176;
  short* Tw = Tsh + wv * 2048;

  float tp = 0.f;
  #pragma unroll 1
  for (int ti = 0; ti < 6; ++ti){
    const int zt = (wv >> 2) + ti * 2;
    if (zt < 11){                                  // wave-uniform guard
      const int rowbase = zt * 16;

      // A-frags (H rows, from LDS) and R-frags (global, L2-hot)
      bf16x8 HA[4], RA[4];
      #pragma unroll
      for (int kk = 0; kk < 4; ++kk){
        HA[kk] = *(const bf16x8*)(Hsh + (rowbase + l15) * 128 + (((kk * 4 + quad) ^ l15) * 8));
        RA[kk] = *(const bf16x8*)(Rh + (rowbase + l15) * 128 + kk * 32 + quad * 8);
      }
      float u1v[4];
      #pragma unroll
      for (int r = 0; r < 4; ++r) u1v[r] = u1p[rowbase + quad * 4 + r];

      // ---- Phase A: T = H_chunk @ M -> private LDS slice (XOR-swizzled) ----
      #pragma unroll
      for (int jt = 0; jt < 8; ++jt){
        const int j0 = jt * 16;
        f32x4 acc = {0.f, 0.f, 0.f, 0.f};
        #pragma unroll
        for (int kk = 0; kk < 4; ++kk){
          bf16x8 Bv = *(const bf16x8*)(MTh + (j0 + l15) * 128 + kk * 32 + quad * 8);
          acc = __builtin_amdgcn_mfma_f32_16x16x32_bf16(HA[kk], Bv, acc, 0, 0, 0);
        }
        const int jcol = j0 + l15, ch = jcol >> 3;
        #pragma unroll
        for (int r = 0; r < 4; ++r){
          int row = quad * 4 + r;
          Tw[row * 128 + ((ch ^ row) << 3) + (jcol & 7)] = (short)f2bf(acc[r]);
        }
      }
      // no barrier: same-wave DS ops are ordered

      // ---- Phase BG + per-lane online softmax over 11 m-tiles ----
      float Mx[4], Av[4], Dv[4];
      #pragma unroll
      for (int r = 0; r < 4; ++r){ Mx[r] = -1e30f; Av[r] = 0.f; Dv[r] = 0.f; }

      #pragma unroll
      for (int mt = 0; mt < 11; ++mt){
        const int m0 = mt * 16;
        bf16x8 Bv[4];
        #pragma unroll
        for (int kk = 0; kk < 4; ++kk)
          Bv[kk] = *(const bf16x8*)(Hsh + (m0 + l15) * 128 + (((kk * 4 + quad) ^ l15) * 8));
        const float u2v = u2p[m0 + l15];
        f32x4 acc = {0.f, 0.f, 0.f, 0.f};
        f32x4 g   = {0.f, 0.f, 0.f, 0.f};
        #pragma unroll
        for (int kk = 0; kk < 4; ++kk){
          bf16x8 A = *(const bf16x8*)(Tw + l15 * 128 + (((kk * 4 + quad) ^ l15) << 3));
          acc = __builtin_amdgcn_mfma_f32_16x16x32_bf16(A, Bv[kk], acc, 0, 0, 0);
          g   = __builtin_amdgcn_mfma_f32_16x16x32_bf16(RA[kk], Bv[kk], g, 0, 0, 0);
        }
        const bool padcol = (mt == 10) && (l15 >= 8);     // cols 168..175 masked
        #pragma unroll
        for (int r = 0; r < 4; ++r){
          float s = padcol ? -1e30f : (acc[r] + u1v[r] + u2v + c3v) * inv;
          float Mn = fmaxf(Mx[r], s);
          float ea = __expf(Mx[r] - Mn);
          float eb = __expf(s - Mn);
          Av[r] = fmaf(Av[r], ea, eb * g[r]);
          Dv[r] = fmaf(Dv[r], ea, eb);
          Mx[r] = Mn;
        }
      }

      // ---- merge (M,A,D) across the 16 l15 lanes (stays within quad) ----
      #pragma unroll
      for (int r = 0; r < 4; ++r){
        #pragma unroll
        for (int o = 1; o < 16; o <<= 1){
          float M2 = __shfl_xor(Mx[r], o, 64);
          float A2 = __shfl_xor(Av[r], o, 64);
          float D2 = __shfl_xor(Dv[r], o, 64);
          float Mn = fmaxf(Mx[r], M2);
          float ea = __expf(Mx[r] - Mn);
          float eb = __expf(M2 - Mn);
          Av[r] = fmaf(Av[r], ea, A2 * eb);
          Dv[r] = fmaf(Dv[r], ea, D2 * eb);
          Mx[r] = Mn;
        }
      }

      // ---- per-row A/D, replicated over 16 lanes -> scale by 1/16 ----
      #pragma unroll
      for (int r = 0; r < 4; ++r){
        int n = rowbase + quad * 4 + r;
        if (n < N) tp += Av[r] / Dv[r];
      }
    }
  }
  tp *= (1.0f / 16.0f);

  // ---- block reduction over 8 waves ----
  #pragma unroll
  for (int o = 32; o > 0; o >>= 1) tp += __shfl_down(tp, o, 64);
  if (l == 0) red8[wv] = tp;
  __syncthreads();
  if (t == 0){
    float s = 0.f;
    #pragma unroll
    for (int i = 0; i < 8; ++i) s += red8[i];
    atomicAdd(out + b, s);
  }
}

} // anonymous namespace

extern "C" void kernel_launch(void* const* d_in, const int* in_sizes, int n_in,
                              void* d_out, int out_size, void* d_ws, size_t ws_size,
                              hipStream_t stream) {
  (void)in_sizes; (void)n_in; (void)out_size;
  const float* X      = (const float*)d_in[0];
  const float* spa_w1 = (const float*)d_in[1];
  const float* spa_b1 = (const float*)d_in[2];
  const float* spa_w2 = (const float*)d_in[3];
  const float* spa_b2 = (const float*)d_in[4];
  const float* tem_w1 = (const float*)d_in[5];
  const float* tem_b1 = (const float*)d_in[6];
  const float* tem_w2 = (const float*)d_in[7];
  const float* tem_b2 = (const float*)d_in[8];
  const float* sgnn_w = (const float*)d_in[9];
  const float* sgnn_b = (const float*)d_in[10];
  const float* tgnn_w = (const float*)d_in[11];
  const float* tgnn_b = (const float*)d_in[12];
  const float* q_w    = (const float*)d_in[13];
  const float* q_b    = (const float*)d_in[14];
  const float* k_w    = (const float*)d_in[15];
  const float* k_b    = (const float*)d_in[16];
  const float* v_w    = (const float*)d_in[17];
  const float* v_b    = (const float*)d_in[18];
  const float* fc_w   = (const float*)d_in[19];
  const float* fc_b   = (const float*)d_in[20];
  float* out = (float*)d_out;

  if (ws_size < (size_t)182714368) return;

  char* wsb = (char*)d_ws;
  short* Hbf = (short*)wsb;                      // bf16 H [0, 46.1MB) (old fp32-H region;
                                                 // moved here: hs/ht write it while other
                                                 // blocks still read Xf/As/At in Rb region)
  float* u1g = (float*)(wsb + 50331648);
  float* u2g = (float*)(wsb + 53215232);
  char*  Rb  = wsb + 88080384;
  float* Xf  = (float*)Rb;
  float* As  = (float*)(Rb + 20971520);
  float* At  = (float*)(Rb + 27525120);
  char*  Pb  = Rb + 46137344;
  short* MT  = (short*)Pb;                       // 131072 B
  short* Rbf = (short*)(Pb + 131072);            // 180224 B (4 heads x 176 x 128 bf16)
  float* c1  = (float*)(Pb + 311296);
  float* c2  = (float*)(Pb + 313344);
  float* c3  = (float*)(Pb + 315392);
  float* c4  = (float*)(Pb + 315408);
  float* twg = (float*)(Pb + 327680);            // 32KB twiddle table

  twiddle_kernel<<<16, 256, 0, stream>>>(twg);
  feat_kernel<<<BSZ * P / 4, 256, 0, stream>>>(X, twg, Xf);
  cumnorm_kernel<<<BSZ, 256, 0, stream>>>(Xf);
  adjt_kernel<<<BSZ, 256, 0, stream>>>(Xf, tem_w1, tem_b1, tem_w2, tem_b2, At);
  adjs_kernel<<<BSZ, 256, 0, stream>>>(Xf, spa_w1, spa_b1, spa_w2, spa_b2, As);
  hs_kernel<<<BSZ, 256, 0, stream>>>(Xf, As, sgnn_w, sgnn_b, Hbf);
  ht_kernel<<<BSZ, 256, 0, stream>>>(Xf, At, tgnn_w, tgnn_b, Hbf);
  prep_kernel<<<dim3(NH, 11), 256, 0, stream>>>(q_w, q_b, k_w, k_b, v_w, v_b, fc_w,
                                                MT, Rbf, c1, c2, c3, c4);
  uprep_kernel<<<BSZ, 256, 0, stream>>>(Hbf, c1, c2, u1g, u2g);
  initout_kernel<<<4, 256, 0, stream>>>(out, fc_b, c4);
  attn_flash<<<dim3(BSZ), 512, 0, stream>>>(Hbf, MT, Rbf, u1g, u2g, c3, out);
}

// Round 12
// 1035.253 us; speedup vs baseline: 1.3503x; 1.0020x over previous
//
#include <hip/hip_runtime.h>
#include <math.h>

namespace {

constexpr int BSZ  = 1024;
constexpr int P    = 128;
constexpr int HG   = 128;
constexpr int NH   = 4;
constexpr int N    = 168;     // P + IND
constexpr int NPAD = 176;     // padded token count (11 tiles of 16)

typedef short bf16x8 __attribute__((ext_vector_type(8)));
typedef float f32x4  __attribute__((ext_vector_type(4)));
typedef short short4v __attribute__((ext_vector_type(4)));

__device__ __forceinline__ unsigned short f2bf(float x){
  union { float f; unsigned u; } v; v.f = x;
  unsigned r = (v.u + 0x7FFF + ((v.u >> 16) & 1)) >> 16;
  return (unsigned short)r;
}
__device__ __forceinline__ float bf2f(unsigned short b){
  union { unsigned u; float f; } v; v.u = ((unsigned)b) << 16;
  return v.f;
}

// ---------- wave (64-lane) butterfly reductions: result in ALL lanes ----------
__device__ __forceinline__ float wsum(float v){
  #pragma unroll
  for (int o = 1; o < 64; o <<= 1) v += __shfl_xor(v, o, 64);
  return v;
}
__device__ __forceinline__ float wmax(float v){
  #pragma unroll
  for (int o = 1; o < 64; o <<= 1) v = fmaxf(v, __shfl_xor(v, o, 64));
  return v;
}
__device__ __forceinline__ float wmin(float v){
  #pragma unroll
  for (int o = 1; o < 64; o <<= 1) v = fminf(v, __shfl_xor(v, o, 64));
  return v;
}
// inclusive 64-lane scan
__device__ __forceinline__ float wscan(float v){
  #pragma unroll
  for (int o = 1; o < 64; o <<= 1){
    float u = __shfl_up(v, o, 64);
    if ((threadIdx.x & 63) >= o) v += u;
  }
  return v;
}
__device__ __forceinline__ float rsum256(float v, volatile float* red4){
  #pragma unroll
  for (int o = 32; o > 0; o >>= 1) v += __shfl_down(v, o, 64);
  __syncthreads();
  if ((threadIdx.x & 63) == 0) red4[threadIdx.x >> 6] = v;
  __syncthreads();
  return red4[0] + red4[1] + red4[2] + red4[3];
}

// ---------- twiddle table: tw[tt*64+l] = cos(2pi*(l*tt mod 128)/128),
//            tw[4096+...] = -sin(...)  ----------
__global__ void twiddle_kernel(float* __restrict__ tw){
  int i = blockIdx.x * 256 + threadIdx.x;
  if (i < 4096){
    int tt = i >> 6, l = i & 63;
    int k = (l * tt) & 127;
    float ang = (float)k * (-0.049087385212340517f);   // -2*pi/128
    tw[i]        = cosf(ang);
    tw[4096 + i] = sinf(ang);
  }
}

// ---------- K1: per-patch features, one WAVE per patch ----------
// DFT: se precomputed per wave in LDS (even/odd bin variants) -> loop body is
// 3 conflict-free ds_read + 2 fma (no readlanes, no fold-fma). Median via
// 31-step radix-select on float bits.
__global__ __launch_bounds__(256) void feat_kernel(const float* __restrict__ X,
                                                   const float* __restrict__ twg,
                                                   float* __restrict__ Xf){
  const int wave = threadIdx.x >> 6, l = threadIdx.x & 63;
  const int pp = blockIdx.x * 4 + wave;          // patch id
  const float* xp = X + (size_t)pp * 128;
  const float x0 = xp[l];
  const float x1 = xp[l + 64];

  __shared__ float tws[8192];                    // 32KB: cos[4096], -sin[4096]
  __shared__ float sesh[4 * 128];                // per-wave: [0..63]=x0+x1, [64..127]=x0-x1
  sesh[wave * 128 + l]      = x0 + x1;
  sesh[wave * 128 + 64 + l] = x0 - x1;
  for (int idx = threadIdx.x; idx < 2048; idx += 256)
    *((float4*)tws + idx) = *((const float4*)twg + idx);
  __syncthreads();

  // ---- temporal ----
  float sum   = wsum(x0 + x1);
  float mean  = sum * (1.0f / 128.0f);
  float mx    = wmax(fmaxf(x0, x1));
  float mn    = wmin(fminf(x0, x1));
  float sumsq = wsum(fmaf(x0, x0, x1 * x1));
  float c0 = x0 - mean, c1_ = x1 - mean;
  float c0q = c0 * c0, c1q = c1_ * c1_;
  float m2 = wsum(c0q + c1q);
  float m3 = wsum(c0q * c0 + c1q * c1_);
  float m4 = wsum(c0q * c0q + c1q * c1q);
  float var = m2 * (1.0f / 127.0f);
  float sd  = sqrtf(var);
  float rms = sqrtf(sumsq * (1.0f / 128.0f));
  float ex0 = __expf(x0 - mx), ex1 = __expf(x1 - mx);
  float Z   = wsum(ex0 + ex1);
  float SxE = wsum(fmaf(ex0, x0, ex1 * x1));
  float ent = (mx + __logf(Z)) - SxE / Z;
  const float lo = (float)(-1.0 + 1e-7), hi = (float)(1.0 - 1e-7);
  float a0 = asinf(fminf(fmaxf(x0, lo), hi));
  float a1 = asinf(fminf(fmaxf(x1, lo), hi));
  float amean = wsum(a0 + a1) * (1.0f / 128.0f);
  float ad0 = a0 - amean, ad1 = a1 - amean;
  float std_asin = sqrtf(wsum(fmaf(ad0, ad0, ad1 * ad1)) * (1.0f / 127.0f));
  float b0 = atanf(x0), b1v = atanf(x1);
  float bmean = wsum(b0 + b1v) * (1.0f / 128.0f);
  float bd0 = b0 - bmean, bd1 = b1v - bmean;
  float std_atan = sqrtf(wsum(fmaf(bd0, bd0, bd1 * bd1)) * (1.0f / 127.0f));
  float kurt = (m4 * (1.0f / 128.0f)) / (sd * sd * sd * sd) - 3.0f;
  float skew = (m3 * (1.0f / 128.0f)) / (sd * sd * sd);

  // ---- DFT: lane l computes bin l; se + twiddles from LDS ----
  const float sign = (l & 1) ? -1.0f : 1.0f;
  const float* sep = &sesh[wave * 128 + (l & 1) * 64];
  float re = 0.f, im = 0.f;
  #pragma unroll
  for (int tt = 0; tt < 64; ++tt){
    float se  = sep[tt];
    re = fmaf(se, tws[tt * 64 + l], re);
    im = fmaf(se, tws[4096 + tt * 64 + l], im);
  }
  float psd = fmaf(re, re, im * im) * 0.0078125f;          // bins 0..63 (lane l)
  float re64 = wsum(sign * (x0 + x1));                     // bin 64
  float psd64 = re64 * re64 * 0.0078125f;

  const float mult = (l == 0) ? 1.f : 2.f;
  float psum = wsum(psd * mult) + psd64;
  float p2   = wsum(psd * psd * mult) + psd64 * psd64;
  float vm   = wmax(psd);
  float maxp = fmaxf(vm, psd64);
  float meanfreq = (-0.5f * psd64) / psum;
  float pbw = sqrtf(p2 / psum);
  unsigned long long am = __ballot(psd == vm);             // first-index argmax
  int lmin = __builtin_ctzll(am);
  float fmaxv = (psd64 > vm) ? -0.5f : (float)lmin * (1.0f / 128.0f);
  float maxamp = sqrtf(maxp * 128.0f);

  // ---- median via radix-select on float bits (rank 64 of 128 weighted) ----
  const unsigned pu   = __float_as_uint(psd);
  const unsigned pu64 = __float_as_uint(psd64);
  unsigned Pv = 0u;
  #pragma unroll
  for (int bit = 30; bit >= 0; --bit){
    unsigned T = Pv | (1u << bit);
    unsigned long long m = __ballot(pu < T);
    int c = 2 * __popcll(m) - (int)(m & 1ull) + ((pu64 < T) ? 1 : 0);
    if (c <= 64) Pv = T;                 // rank-64 value >= T
  }
  float med;
  {
    unsigned long long em = __ballot(pu == Pv);
    unsigned long long m2b = __ballot(pu < Pv);
    int less = 2 * __popcll(m2b) - (int)(m2b & 1ull) + ((pu64 < Pv) ? 1 : 0);
    if (em){
      int kt = (int)__builtin_ctzll(em);
      med = (less == 64) ? (float)kt * (1.0f / 128.0f)
                         : -(float)kt * (1.0f / 128.0f);
    } else {
      med = -0.5f;                        // rank-64 element is bin 64
    }
  }

  if (l == 0){
    float* o = Xf + (size_t)pp * 40;
    o[0]  = mx;  o[1]  = mn;  o[2]  = sd;   o[3]  = rms; o[4]  = mean;
    o[5]  = mx - mn;  o[6] = var;  o[7] = ent; o[8] = std_asin; o[9] = std_atan;
    o[10] = kurt; o[11] = skew;
    o[12] = meanfreq;
    o[13] = med;
    o[14] = psum;
    o[15] = 1.0f;
    o[16] = pbw;
    o[17] = maxp;
    o[18] = maxamp;
    o[19] = fmaxv;
  }
}

// ---------- K2: cumsum feature (wave-parallel scan) + per-sample norm ----------
__global__ __launch_bounds__(256) void cumnorm_kernel(float* __restrict__ Xf){
  const int b = blockIdx.x, t = threadIdx.x;
  const int wv = t >> 6, l = t & 63;
  __shared__ float arr[128 * 40];
  __shared__ float red4[4];
  float* base = Xf + b * 5120;
  for (int idx = t; idx < 128 * 20; idx += 256){
    int p = idx / 20, c = idx - p * 20;
    arr[p * 40 + c] = base[p * 40 + c];
  }
  __syncthreads();
  // channel c handled by wave c%4: 128-prefix = two 64-lane scans + carry
  #pragma unroll
  for (int k = 0; k < 5; ++k){
    int c = wv + k * 4;                                    // 0..19
    float v0 = arr[l * 40 + c];
    float v1 = arr[(l + 64) * 40 + c];
    float s0 = wscan(v0);
    float tot0 = __shfl(s0, 63, 64);
    float s1 = wscan(v1) + tot0;
    arr[l * 40 + 20 + c]        = s0 / sqrtf(fmaxf(fabsf(s0), 1e-12f));
    arr[(l + 64) * 40 + 20 + c] = s1 / sqrtf(fmaxf(fabsf(s1), 1e-12f));
  }
  __syncthreads();
  float pa = 0.f;
  for (int idx = t; idx < 5120; idx += 256){ float v = arr[idx]; pa = fmaf(v, v, pa); }
  float nrm = sqrtf(rsum256(pa, red4));
  for (int idx = t; idx < 5120; idx += 256) base[idx] = arr[idx] / nrm;
}

// ---------- K3+K4 fused: A_t then A_s (xf loaded once; T reused for T2) ----------
__global__ __launch_bounds__(256) void adj_kernel(const float* __restrict__ Xf,
    const float* __restrict__ tw1, const float* __restrict__ tb1,
    const float* __restrict__ tw2, const float* __restrict__ tb2,
    const float* __restrict__ sw1, const float* __restrict__ sb1,
    const float* __restrict__ sw2, const float* __restrict__ sb2,
    float* __restrict__ At, float* __restrict__ As){
  const int b = blockIdx.x, t = threadIdx.x;
  __shared__ float xf[5120];          // stride 40
  __shared__ float T[128 * 64];       // adjt T1; reused for adjs T2 (40*64)
  const float* src = Xf + b * 5120;
  for (int idx = t; idx < 1280; idx += 256)
    *((float4*)xf + idx) = *((const float4*)src + idx);
  __syncthreads();

  // ---- adjt phase 1: T1[i][k] = tanh(b1[k] + sum_c xf[i][c]*w1[c][k]) ----
  {
    const int k0 = (t & 15) * 4, i0 = (t >> 4) * 8;
    float4 bv = *(const float4*)&tb1[k0];
    float acc[8][4];
    #pragma unroll
    for (int di = 0; di < 8; ++di){ acc[di][0]=bv.x; acc[di][1]=bv.y; acc[di][2]=bv.z; acc[di][3]=bv.w; }
    for (int c = 0; c < 40; ++c){
      float4 wv = *(const float4*)&tw1[c * 64 + k0];
      #pragma unroll
      for (int di = 0; di < 8; ++di){
        float xv = xf[(i0 + di) * 40 + c];
        acc[di][0] = fmaf(xv, wv.x, acc[di][0]);
        acc[di][1] = fmaf(xv, wv.y, acc[di][1]);
        acc[di][2] = fmaf(xv, wv.z, acc[di][2]);
        acc[di][3] = fmaf(xv, wv.w, acc[di][3]);
      }
    }
    #pragma unroll
    for (int di = 0; di < 8; ++di){
      float4 o;
      o.x = tanhf(acc[di][0]); o.y = tanhf(acc[di][1]);
      o.z = tanhf(acc[di][2]); o.w = tanhf(acc[di][3]);
      *(float4*)&T[(i0 + di) * 64 + k0] = o;
    }
  }
  __syncthreads();

  // ---- adjt phase 2: A_t[i][j] = b2[j] + sum_k T1[i][k]*w2[k][j] ----
  {
    const int j0 = (t & 31) * 4, i0 = (t >> 5) * 16;
    float4 bv = *(const float4*)&tb2[j0];
    float acc[16][4];
    #pragma unroll
    for (int di = 0; di < 16; ++di){ acc[di][0]=bv.x; acc[di][1]=bv.y; acc[di][2]=bv.z; acc[di][3]=bv.w; }
    for (int k = 0; k < 64; ++k){
      float4 wv = *(const float4*)&tw2[k * 128 + j0];
      #pragma unroll
      for (int di = 0; di < 16; ++di){
        float tv = T[(i0 + di) * 64 + k];
        acc[di][0] = fmaf(tv, wv.x, acc[di][0]);
        acc[di][1] = fmaf(tv, wv.y, acc[di][1]);
        acc[di][2] = fmaf(tv, wv.z, acc[di][2]);
        acc[di][3] = fmaf(tv, wv.w, acc[di][3]);
      }
    }
    float* dst = At + (size_t)b * 16384;
    #pragma unroll
    for (int di = 0; di < 16; ++di)
      *(float4*)&dst[(i0 + di) * 128 + j0] = *(float4*)acc[di];
  }
  __syncthreads();                      // T dead; reuse as T2

  // ---- adjs phase 1: T2[i][k] = tanh(b1[k] + sum_p xf[p][i]*w1[p][k]) ----
  for (int idx = t; idx < 40 * 64; idx += 256){
    int i = idx >> 6, k = idx & 63;
    float acc = sb1[k];
    for (int p = 0; p < 128; ++p) acc = fmaf(xf[p * 40 + i], sw1[p * 64 + k], acc);
    T[idx] = tanhf(acc);
  }
  __syncthreads();

  // ---- adjs phase 2: A_s[i][j] = b2[j] + sum_k T2[i][k]*w2[k][j] ----
  float* dst = As + b * 1600;
  for (int idx = t; idx < 1600; idx += 256){
    int i = idx / 40, j = idx - i * 40;
    float acc = sb2[j];
    #pragma unroll 8
    for (int k = 0; k < 64; ++k) acc = fmaf(T[i * 64 + k], sw2[k * 40 + j], acc);
    dst[idx] = acc;
  }
}

// ---------- K5+K6 fused: H_s then H_t -> bf16 Hbf (xf loaded once; M reused) ----------
__global__ __launch_bounds__(256) void hsht_kernel(const float* __restrict__ Xf,
    const float* __restrict__ As_g, const float* __restrict__ At_g,
    const float* __restrict__ sw, const float* __restrict__ sb,
    const float* __restrict__ tw, const float* __restrict__ tb,
    short* __restrict__ Hbf){
  const int b = blockIdx.x, t = threadIdx.x;
  __shared__ float xf[5120];          // stride 40
  __shared__ float As[1600];
  __shared__ float M[5120];           // hs M (40x128); reused as ht M2 (128x40)
  const float* src = Xf + b * 5120;
  for (int idx = t; idx < 1280; idx += 256)
    *((float4*)xf + idx) = *((const float4*)src + idx);
  for (int idx = t; idx < 400; idx += 256)
    *((float4*)As + idx) = *((const float4*)(As_g + b * 1600) + idx);
  // zero-pad Hbf rows 168..175
  {
    short* padp = Hbf + (size_t)b * NPAD * 128 + 168 * 128;
    for (int idx = t; idx < 256; idx += 256)
      *(float2*)&padp[idx * 4] = (float2){0.f, 0.f};
  }
  __syncthreads();

  // ---- hs phase 1: M[i][p] = sum_m As[i][m] * xf[p][m]; tile 5i x 4p ----
  {
    const int p0 = (t & 31) * 4, i0 = (t >> 5) * 5;
    float acc[5][4];
    #pragma unroll
    for (int di = 0; di < 5; ++di)
      #pragma unroll
      for (int dp = 0; dp < 4; ++dp) acc[di][dp] = 0.f;
    for (int m = 0; m < 40; m += 4){
      float4 a4[5], x4[4];
      #pragma unroll
      for (int di = 0; di < 5; ++di) a4[di] = *(const float4*)&As[(i0 + di) * 40 + m];
      #pragma unroll
      for (int dp = 0; dp < 4; ++dp) x4[dp] = *(const float4*)&xf[(p0 + dp) * 40 + m];
      #pragma unroll
      for (int dm = 0; dm < 4; ++dm)
        #pragma unroll
        for (int di = 0; di < 5; ++di){
          float av = (&a4[di].x)[dm];
          #pragma unroll
          for (int dp = 0; dp < 4; ++dp)
            acc[di][dp] = fmaf(av, (&x4[dp].x)[dm], acc[di][dp]);
        }
    }
    #pragma unroll
    for (int di = 0; di < 5; ++di)
      *(float4*)&M[(i0 + di) * 128 + p0] = *(float4*)acc[di];
  }
  __syncthreads();

  // ---- hs phase 2: H_s[i][j] -> bf16 Hbf rows 0..39 ----
  {
    const int j0 = (t & 31) * 4, i0 = (t >> 5) * 5;
    float4 bv = *(const float4*)&sb[j0];
    float acc[5][4];
    #pragma unroll
    for (int di = 0; di < 5; ++di){ acc[di][0]=bv.x; acc[di][1]=bv.y; acc[di][2]=bv.z; acc[di][3]=bv.w; }
    for (int p = 0; p < 128; ++p){
      float4 wv = *(const float4*)&sw[p * 128 + j0];
      #pragma unroll
      for (int di = 0; di < 5; ++di){
        float mv = M[(i0 + di) * 128 + p];
        acc[di][0] = fmaf(mv, wv.x, acc[di][0]);
        acc[di][1] = fmaf(mv, wv.y, acc[di][1]);
        acc[di][2] = fmaf(mv, wv.z, acc[di][2]);
        acc[di][3] = fmaf(mv, wv.w, acc[di][3]);
      }
    }
    short* dst = Hbf + (size_t)b * NPAD * 128;
    #pragma unroll
    for (int di = 0; di < 5; ++di){
      short4v o;
      #pragma unroll
      for (int q = 0; q < 4; ++q){
        float v = acc[di][q];
        v = (v >= 0.f) ? v : 0.01f * v;
        o[q] = (short)f2bf(v);
      }
      *(short4v*)&dst[(i0 + di) * 128 + j0] = o;
    }
  }
  __syncthreads();                      // M dead; reuse as M2

  // ---- ht phase 1: M2[i][c] = sum_m At[i][m] * xf[m][c]; tile 4i x 5c ----
  {
    const int c0 = (t & 7) * 5, i0 = (t >> 3) * 4;
    const float* At = At_g + (size_t)b * 16384;
    float acc[4][5];
    #pragma unroll
    for (int di = 0; di < 4; ++di)
      #pragma unroll
      for (int dc = 0; dc < 5; ++dc) acc[di][dc] = 0.f;
    for (int m = 0; m < 128; m += 4){
      float4 a4[4];
      #pragma unroll
      for (int di = 0; di < 4; ++di) a4[di] = *(const float4*)&At[(i0 + di) * 128 + m];
      #pragma unroll
      for (int dm = 0; dm < 4; ++dm){
        float xv[5];
        #pragma unroll
        for (int dc = 0; dc < 5; ++dc) xv[dc] = xf[(m + dm) * 40 + c0 + dc];
        #pragma unroll
        for (int di = 0; di < 4; ++di){
          float av = (&a4[di].x)[dm];
          #pragma unroll
          for (int dc = 0; dc < 5; ++dc)
            acc[di][dc] = fmaf(av, xv[dc], acc[di][dc]);
        }
      }
    }
    #pragma unroll
    for (int di = 0; di < 4; ++di)
      #pragma unroll
      for (int dc = 0; dc < 5; ++dc)
        M[(i0 + di) * 40 + c0 + dc] = acc[di][dc];
  }
  __syncthreads();

  // ---- ht phase 2: H_t[i][j] -> bf16 Hbf rows 40..167 ----
  {
    const int j0 = (t & 31) * 4, i0 = (t >> 5) * 16;
    float4 bv = *(const float4*)&tb[j0];
    float acc[16][4];
    #pragma unroll
    for (int di = 0; di < 16; ++di){ acc[di][0]=bv.x; acc[di][1]=bv.y; acc[di][2]=bv.z; acc[di][3]=bv.w; }
    for (int c = 0; c < 40; ++c){
      float4 wv = *(const float4*)&tw[c * 128 + j0];
      #pragma unroll
      for (int di = 0; di < 16; ++di){
        float mv = M[(i0 + di) * 40 + c];
        acc[di][0] = fmaf(mv, wv.x, acc[di][0]);
        acc[di][1] = fmaf(mv, wv.y, acc[di][1]);
        acc[di][2] = fmaf(mv, wv.z, acc[di][2]);
        acc[di][3] = fmaf(mv, wv.w, acc[di][3]);
      }
    }
    short* dst = Hbf + (size_t)b * NPAD * 128 + 40 * 128;
    #pragma unroll
    for (int di = 0; di < 16; ++di){
      short4v o;
      #pragma unroll
      for (int q = 0; q < 4; ++q){
        float v = acc[di][q];
        v = (v >= 0.f) ? v : 0.01f * v;
        o[q] = (short)f2bf(v);
      }
      *(short4v*)&dst[(i0 + di) * 128 + j0] = o;
    }
  }
}

// out[b] = fc_b + sum_h c4[h]
__global__ void initout_kernel(float* __restrict__ out, const float* __restrict__ fcb,
                               const float* __restrict__ c4){
  int i = blockIdx.x * 256 + threadIdx.x;
  float base = fcb[0] + c4[0] + c4[1] + c4[2] + c4[3];
  if (i < BSZ) out[i] = base;
}

// ---------- prep: per-head M^T, R = fcw·Wv^T, c1/c2/c3/c4; grid (NH, 11) ----------
__global__ __launch_bounds__(256) void prep_kernel(
    const float* __restrict__ qw, const float* __restrict__ qb,
    const float* __restrict__ kw, const float* __restrict__ kb,
    const float* __restrict__ vw, const float* __restrict__ vb,
    const float* __restrict__ fcw,
    short* __restrict__ MT, short* __restrict__ Rbf,
    float* __restrict__ c1, float* __restrict__ c2,
    float* __restrict__ c3, float* __restrict__ c4){
  const int h = blockIdx.x, sl = blockIdx.y, t = threadIdx.x;
  const float* Q = qw + h * 16384;
  const float* K = kw + h * 16384;
  const float* V = vw + h * 16384;
  if (sl < 8){
    for (int idx = t; idx < 2048; idx += 256){
      int j = sl * 16 + (idx >> 7), d = idx & 127;
      float acc = 0.f;
      for (int e = 0; e < 128; ++e) acc = fmaf(Q[d * 128 + e], K[j * 128 + e], acc);
      MT[h * 16384 + j * 128 + d] = (short)f2bf(acc);     // MT[j][d] = M[d][j]
    }
    if (t < 16){
      int r = sl * 16 + t;
      float a = 0.f, bsum = 0.f;
      for (int e = 0; e < 128; ++e){
        a    = fmaf(Q[r * 128 + e], kb[h * 128 + e], a);
        bsum = fmaf(K[r * 128 + e], qb[h * 128 + e], bsum);
      }
      c1[h * 128 + r] = a;
      c2[h * 128 + r] = bsum;
    }
  }
  // R rows n in [sl*16, sl*16+16); zero-pad n >= 168
  for (int idx = t; idx < 2048; idx += 256){
    int n = sl * 16 + (idx >> 7), d = idx & 127;
    float acc = 0.f;
    if (n < N){
      const float* fr = fcw + n * 512 + h * 128;
      const float* vr = V + d * 128;
      for (int e = 0; e < 128; ++e) acc = fmaf(fr[e], vr[e], acc);
    }
    Rbf[h * 22528 + n * 128 + d] = (short)f2bf(acc);
  }
  if (sl == 0){
    if (t == 0){
      float a = 0.f;
      for (int e = 0; e < 128; ++e) a = fmaf(qb[h * 128 + e], kb[h * 128 + e], a);
      c3[h] = a;
    }
    if (t >= 64 && t < 128){                  // wave 1: c4 reduction
      int l = t - 64;
      float part = 0.f;
      for (int i = l; i < N * 128; i += 64){
        int n = i >> 7, e = i & 127;
        part = fmaf(fcw[n * 512 + h * 128 + e], vb[h * 128 + e], part);
      }
      part = wsum(part);
      if (l == 0) c4[h] = part;
    }
  }
}

// ---------- u1/u2 precompute: u1[n]=H[n]·c1, u2[n]=H[n]·c2 per (b,h) ----------
__global__ __launch_bounds__(256) void uprep_kernel(const short* __restrict__ Hbf,
    const float* __restrict__ c1, const float* __restrict__ c2,
    float* __restrict__ u1g, float* __restrict__ u2g){
  const int b = blockIdx.x, t = threadIdx.x;
  for (int idx = t; idx < 176 * 4; idx += 256){
    int n = idx >> 2, h = idx & 3;
    const bf16x8* rp = (const bf16x8*)(Hbf + (size_t)b * NPAD * 128 + (size_t)n * 128);
    const float* C1 = c1 + h * 128;
    const float* C2 = c2 + h * 128;
    float a1 = 0.f, a2 = 0.f;
    for (int kk = 0; kk < 16; ++kk){
      bf16x8 v = rp[kk];
      #pragma unroll
      for (int j = 0; j < 8; ++j){
        float hv = bf2f((unsigned short)v[j]);
        a1 = fmaf(hv, C1[kk * 8 + j], a1);
        a2 = fmaf(hv, C2[kk * 8 + j], a2);
      }
    }
    u1g[(size_t)(b * 4 + h) * 176 + n] = a1;
    u2g[(size_t)(b * 4 + h) * 176 + n] = a2;
  }
}

// ---------- attention, flash-style, 8-wave block: grid (b) ----------
// (512,2): LDS 78KB -> 2 blocks/CU; VGPR free to ~128, no spill.
// ti task loop #pragma unroll 1 (r9 lesson: full unroll -> spill).
__global__ __launch_bounds__(512, 2) void attn_flash(
    const short* __restrict__ Hbf, const short* __restrict__ MT,
    const short* __restrict__ Rbf,
    const float* __restrict__ u1g, const float* __restrict__ u2g,
    const float* __restrict__ c3g, float* __restrict__ out){
  const int b = blockIdx.x;
  const int t = threadIdx.x;
  const int wv = t >> 6, l = t & 63, quad = l >> 4, l15 = l & 15;
  const int h = wv & 3;

  __shared__ __align__(16) short Hsh[NPAD * 128];     // 45KB, swizzled
  __shared__ __align__(16) short Tsh[8 * 2048];       // 32KB, 4KB/wave private
  __shared__ float red8[8];

  const short* Hb = Hbf + (size_t)b * NPAD * 128;

  // ---- cooperative stage: 2816 x 16B units, coalesced global, swizzled LDS ----
  #pragma unroll
  for (int i = 0; i < 6; ++i){
    int idx = t + i * 512;
    if (idx < 2816){
      int row = idx >> 4, g = idx & 15;
      bf16x8 v = *(const bf16x8*)(Hb + row * 128 + g * 8);
      *(bf16x8*)(Hsh + row * 128 + ((g ^ (row & 15)) * 8)) = v;
    }
  }
  __syncthreads();

  const short* MTh = MT + h * 16384;
  const short* Rh  = Rbf + h * 22528;
  const float c3v = c3g[h];
  const float inv = 0.08838834764831845f;   // 1/sqrt(128)
  const float* u1p = u1g + (size_t)(b * 4 + h) * 176;
  const float* u2p = u2g + (size_t)(b * 4 + h) * 176;
  short* Tw = Tsh + wv * 2048;

  float tp = 0.f;
  #pragma unroll 1
  for (int ti = 0; ti < 6; ++ti){
    const int zt = (wv >> 2) + ti * 2;
    if (zt < 11){                                  // wave-uniform guard
      const int rowbase = zt * 16;

      // A-frags (H rows, from LDS) and R-frags (global, L2-hot)
      bf16x8 HA[4], RA[4];
      #pragma unroll
      for (int kk = 0; kk < 4; ++kk){
        HA[kk] = *(const bf16x8*)(Hsh + (rowbase + l15) * 128 + (((kk * 4 + quad) ^ l15) * 8));
        RA[kk] = *(const bf16x8*)(Rh + (rowbase + l15) * 128 + kk * 32 + quad * 8);
      }
      float u1v[4];
      #pragma unroll
      for (int r = 0; r < 4; ++r) u1v[r] = u1p[rowbase + quad * 4 + r];

      // ---- Phase A: T = H_chunk @ M -> private LDS slice (XOR-swizzled) ----
      #pragma unroll
      for (int jt = 0; jt < 8; ++jt){
        const int j0 = jt * 16;
        f32x4 acc = {0.f, 0.f, 0.f, 0.f};
        #pragma unroll
        for (int kk = 0; kk < 4; ++kk){
          bf16x8 Bv = *(const bf16x8*)(MTh + (j0 + l15) * 128 + kk * 32 + quad * 8);
          acc = __builtin_amdgcn_mfma_f32_16x16x32_bf16(HA[kk], Bv, acc, 0, 0, 0);
        }
        const int jcol = j0 + l15, ch = jcol >> 3;
        #pragma unroll
        for (int r = 0; r < 4; ++r){
          int row = quad * 4 + r;
          Tw[row * 128 + ((ch ^ row) << 3) + (jcol & 7)] = (short)f2bf(acc[r]);
        }
      }
      // no barrier: same-wave DS ops are ordered

      // ---- Phase BG + per-lane online softmax over 11 m-tiles ----
      float Mx[4], Av[4], Dv[4];
      #pragma unroll
      for (int r = 0; r < 4; ++r){ Mx[r] = -1e30f; Av[r] = 0.f; Dv[r] = 0.f; }

      #pragma unroll
      for (int mt = 0; mt < 11; ++mt){
        const int m0 = mt * 16;
        bf16x8 Bv[4];
        #pragma unroll
        for (int kk = 0; kk < 4; ++kk)
          Bv[kk] = *(const bf16x8*)(Hsh + (m0 + l15) * 128 + (((kk * 4 + quad) ^ l15) * 8));
        const float u2v = u2p[m0 + l15];
        f32x4 acc = {0.f, 0.f, 0.f, 0.f};
        f32x4 g   = {0.f, 0.f, 0.f, 0.f};
        #pragma unroll
        for (int kk = 0; kk < 4; ++kk){
          bf16x8 A = *(const bf16x8*)(Tw + l15 * 128 + (((kk * 4 + quad) ^ l15) << 3));
          acc = __builtin_amdgcn_mfma_f32_16x16x32_bf16(A, Bv[kk], acc, 0, 0, 0);
          g   = __builtin_amdgcn_mfma_f32_16x16x32_bf16(RA[kk], Bv[kk], g, 0, 0, 0);
        }
        const bool padcol = (mt == 10) && (l15 >= 8);     // cols 168..175 masked
        #pragma unroll
        for (int r = 0; r < 4; ++r){
          float s = padcol ? -1e30f : (acc[r] + u1v[r] + u2v + c3v) * inv;
          float Mn = fmaxf(Mx[r], s);
          float ea = __expf(Mx[r] - Mn);
          float eb = __expf(s - Mn);
          Av[r] = fmaf(Av[r], ea, eb * g[r]);
          Dv[r] = fmaf(Dv[r], ea, eb);
          Mx[r] = Mn;
        }
      }

      // ---- merge (M,A,D) across the 16 l15 lanes (stays within quad) ----
      #pragma unroll
      for (int r = 0; r < 4; ++r){
        #pragma unroll
        for (int o = 1; o < 16; o <<= 1){
          float M2 = __shfl_xor(Mx[r], o, 64);
          float A2 = __shfl_xor(Av[r], o, 64);
          float D2 = __shfl_xor(Dv[r], o, 64);
          float Mn = fmaxf(Mx[r], M2);
          float ea = __expf(Mx[r] - Mn);
          float eb = __expf(M2 - Mn);
          Av[r] = fmaf(Av[r], ea, A2 * eb);
          Dv[r] = fmaf(Dv[r], ea, D2 * eb);
          Mx[r] = Mn;
        }
      }

      // ---- per-row A/D, replicated over 16 lanes -> scale by 1/16 ----
      #pragma unroll
      for (int r = 0; r < 4; ++r){
        int n = rowbase + quad * 4 + r;
        if (n < N) tp += Av[r] / Dv[r];
      }
    }
  }
  tp *= (1.0f / 16.0f);

  // ---- block reduction over 8 waves ----
  #pragma unroll
  for (int o = 32; o > 0; o >>= 1) tp += __shfl_down(tp, o, 64);
  if (l == 0) red8[wv] = tp;
  __syncthreads();
  if (t == 0){
    float s = 0.f;
    #pragma unroll
    for (int i = 0; i < 8; ++i) s += red8[i];
    atomicAdd(out + b, s);
  }
}

} // anonymous namespace

extern "C" void kernel_launch(void* const* d_in, const int* in_sizes, int n_in,
                              void* d_out, int out_size, void* d_ws, size_t ws_size,
                              hipStream_t stream) {
  (void)in_sizes; (void)n_in; (void)out_size;
  const float* X      = (const float*)d_in[0];
  const float* spa_w1 = (const float*)d_in[1];
  const float* spa_b1 = (const float*)d_in[2];
  const float* spa_w2 = (const float*)d_in[3];
  const float* spa_b2 = (const float*)d_in[4];
  const float* tem_w1 = (const float*)d_in[5];
  const float* tem_b1 = (const float*)d_in[6];
  const float* tem_w2 = (const float*)d_in[7];
  const float* tem_b2 = (const float*)d_in[8];
  const float* sgnn_w = (const float*)d_in[9];
  const float* sgnn_b = (const float*)d_in[10];
  const float* tgnn_w = (const float*)d_in[11];
  const float* tgnn_b = (const float*)d_in[12];
  const float* q_w    = (const float*)d_in[13];
  const float* q_b    = (const float*)d_in[14];
  const float* k_w    = (const float*)d_in[15];
  const float* k_b    = (const float*)d_in[16];
  const float* v_w    = (const float*)d_in[17];
  const float* v_b    = (const float*)d_in[18];
  const float* fc_w   = (const float*)d_in[19];
  const float* fc_b   = (const float*)d_in[20];
  float* out = (float*)d_out;

  if (ws_size < (size_t)182714368) return;

  char* wsb = (char*)d_ws;
  short* Hbf = (short*)wsb;                      // bf16 H [0, 46.1MB)
  float* u1g = (float*)(wsb + 50331648);
  float* u2g = (float*)(wsb + 53215232);
  char*  Rb  = wsb + 88080384;
  float* Xf  = (float*)Rb;
  float* As  = (float*)(Rb + 20971520);
  float* At  = (float*)(Rb + 27525120);
  char*  Pb  = Rb + 46137344;
  short* MT  = (short*)Pb;                       // 131072 B
  short* Rbf = (short*)(Pb + 131072);            // 180224 B
  float* c1  = (float*)(Pb + 311296);
  float* c2  = (float*)(Pb + 313344);
  float* c3  = (float*)(Pb + 315392);
  float* c4  = (float*)(Pb + 315408);
  float* twg = (float*)(Pb + 327680);            // 32KB twiddle table

  twiddle_kernel<<<16, 256, 0, stream>>>(twg);
  feat_kernel<<<BSZ * P / 4, 256, 0, stream>>>(X, twg, Xf);
  cumnorm_kernel<<<BSZ, 256, 0, stream>>>(Xf);
  adj_kernel<<<BSZ, 256, 0, stream>>>(Xf, tem_w1, tem_b1, tem_w2, tem_b2,
                                      spa_w1, spa_b1, spa_w2, spa_b2, At, As);
  hsht_kernel<<<BSZ, 256, 0, stream>>>(Xf, As, At, sgnn_w, sgnn_b, tgnn_w, tgnn_b, Hbf);
  prep_kernel<<<dim3(NH, 11), 256, 0, stream>>>(q_w, q_b, k_w, k_b, v_w, v_b, fc_w,
                                                MT, Rbf, c1, c2, c3, c4);
  uprep_kernel<<<BSZ, 256, 0, stream>>>(Hbf, c1, c2, u1g, u2g);
  initout_kernel<<<4, 256, 0, stream>>>(out, fc_b, c4);
  attn_flash<<<dim3(BSZ), 512, 0, stream>>>(Hbf, MT, Rbf, u1g, u2g, c3, out);
}

// Round 13
// 1032.442 us; speedup vs baseline: 1.3540x; 1.0027x over previous
//
#include <hip/hip_runtime.h>
#include <math.h>

namespace {

constexpr int BSZ  = 1024;
constexpr int P    = 128;
constexpr int HG   = 128;
constexpr int NH   = 4;
constexpr int N    = 168;     // P + IND
constexpr int NPAD = 176;     // padded token count (11 tiles of 16)

typedef short bf16x8 __attribute__((ext_vector_type(8)));
typedef float f32x4  __attribute__((ext_vector_type(4)));
typedef short short4v __attribute__((ext_vector_type(4)));

__device__ __forceinline__ unsigned short f2bf(float x){
  union { float f; unsigned u; } v; v.f = x;
  unsigned r = (v.u + 0x7FFF + ((v.u >> 16) & 1)) >> 16;
  return (unsigned short)r;
}
__device__ __forceinline__ float bf2f(unsigned short b){
  union { unsigned u; float f; } v; v.u = ((unsigned)b) << 16;
  return v.f;
}

// ---------- wave (64-lane) butterfly reductions: result in ALL lanes ----------
__device__ __forceinline__ float wsum(float v){
  #pragma unroll
  for (int o = 1; o < 64; o <<= 1) v += __shfl_xor(v, o, 64);
  return v;
}
__device__ __forceinline__ float wmax(float v){
  #pragma unroll
  for (int o = 1; o < 64; o <<= 1) v = fmaxf(v, __shfl_xor(v, o, 64));
  return v;
}
__device__ __forceinline__ float wmin(float v){
  #pragma unroll
  for (int o = 1; o < 64; o <<= 1) v = fminf(v, __shfl_xor(v, o, 64));
  return v;
}
// inclusive 64-lane scan
__device__ __forceinline__ float wscan(float v){
  #pragma unroll
  for (int o = 1; o < 64; o <<= 1){
    float u = __shfl_up(v, o, 64);
    if ((threadIdx.x & 63) >= o) v += u;
  }
  return v;
}
__device__ __forceinline__ float rsum256(float v, volatile float* red4){
  #pragma unroll
  for (int o = 32; o > 0; o >>= 1) v += __shfl_down(v, o, 64);
  __syncthreads();
  if ((threadIdx.x & 63) == 0) red4[threadIdx.x >> 6] = v;
  __syncthreads();
  return red4[0] + red4[1] + red4[2] + red4[3];
}

// ---------- twiddle table: tw[tt*64+l] = cos(2pi*(l*tt mod 128)/128),
//            tw[4096+...] = -sin(...)  ----------
__global__ void twiddle_kernel(float* __restrict__ tw){
  int i = blockIdx.x * 256 + threadIdx.x;
  if (i < 4096){
    int tt = i >> 6, l = i & 63;
    int k = (l * tt) & 127;
    float ang = (float)k * (-0.049087385212340517f);   // -2*pi/128
    tw[i]        = cosf(ang);
    tw[4096 + i] = sinf(ang);
  }
}

// ---------- K1: per-patch features, one WAVE per patch ----------
// DFT: se in LDS with stride-65 odd-half (even lanes read bank tt%32, odd lanes
// bank (tt+1)%32 -> two broadcasts, conflict-free; r12's stride-64 layout was
// same-bank -> 8.4M conflict cycles). re/im split into 2 partials each to break
// the 64-long dependent fma chains.
__global__ __launch_bounds__(256) void feat_kernel(const float* __restrict__ X,
                                                   const float* __restrict__ twg,
                                                   float* __restrict__ Xf){
  const int wave = threadIdx.x >> 6, l = threadIdx.x & 63;
  const int pp = blockIdx.x * 4 + wave;          // patch id
  const float* xp = X + (size_t)pp * 128;
  const float x0 = xp[l];
  const float x1 = xp[l + 64];

  __shared__ float tws[8192];                    // 32KB: cos[4096], -sin[4096]
  __shared__ float sesh[4 * 130];                // per-wave: [0..63]=x0+x1, [65..128]=x0-x1
  sesh[wave * 130 + l]      = x0 + x1;
  sesh[wave * 130 + 65 + l] = x0 - x1;
  for (int idx = threadIdx.x; idx < 2048; idx += 256)
    *((float4*)tws + idx) = *((const float4*)twg + idx);
  __syncthreads();

  // ---- temporal ----
  float sum   = wsum(x0 + x1);
  float mean  = sum * (1.0f / 128.0f);
  float mx    = wmax(fmaxf(x0, x1));
  float mn    = wmin(fminf(x0, x1));
  float sumsq = wsum(fmaf(x0, x0, x1 * x1));
  float c0 = x0 - mean, c1_ = x1 - mean;
  float c0q = c0 * c0, c1q = c1_ * c1_;
  float m2 = wsum(c0q + c1q);
  float m3 = wsum(c0q * c0 + c1q * c1_);
  float m4 = wsum(c0q * c0q + c1q * c1q);
  float var = m2 * (1.0f / 127.0f);
  float sd  = sqrtf(var);
  float rms = sqrtf(sumsq * (1.0f / 128.0f));
  float ex0 = __expf(x0 - mx), ex1 = __expf(x1 - mx);
  float Z   = wsum(ex0 + ex1);
  float SxE = wsum(fmaf(ex0, x0, ex1 * x1));
  float ent = (mx + __logf(Z)) - SxE / Z;
  const float lo = (float)(-1.0 + 1e-7), hi = (float)(1.0 - 1e-7);
  float a0 = asinf(fminf(fmaxf(x0, lo), hi));
  float a1 = asinf(fminf(fmaxf(x1, lo), hi));
  float amean = wsum(a0 + a1) * (1.0f / 128.0f);
  float ad0 = a0 - amean, ad1 = a1 - amean;
  float std_asin = sqrtf(wsum(fmaf(ad0, ad0, ad1 * ad1)) * (1.0f / 127.0f));
  float b0 = atanf(x0), b1v = atanf(x1);
  float bmean = wsum(b0 + b1v) * (1.0f / 128.0f);
  float bd0 = b0 - bmean, bd1 = b1v - bmean;
  float std_atan = sqrtf(wsum(fmaf(bd0, bd0, bd1 * bd1)) * (1.0f / 127.0f));
  float kurt = (m4 * (1.0f / 128.0f)) / (sd * sd * sd * sd) - 3.0f;
  float skew = (m3 * (1.0f / 128.0f)) / (sd * sd * sd);

  // ---- DFT: lane l computes bin l; se + twiddles from LDS; 4 indep chains ----
  const float sign = (l & 1) ? -1.0f : 1.0f;
  const float* sep = &sesh[wave * 130 + (l & 1) * 65];
  float re0 = 0.f, re1 = 0.f, im0 = 0.f, im1 = 0.f;
  #pragma unroll
  for (int tt = 0; tt < 64; tt += 2){
    float seA = sep[tt];
    float seB = sep[tt + 1];
    re0 = fmaf(seA, tws[tt * 64 + l], re0);
    im0 = fmaf(seA, tws[4096 + tt * 64 + l], im0);
    re1 = fmaf(seB, tws[(tt + 1) * 64 + l], re1);
    im1 = fmaf(seB, tws[4096 + (tt + 1) * 64 + l], im1);
  }
  float re = re0 + re1, im = im0 + im1;
  float psd = fmaf(re, re, im * im) * 0.0078125f;          // bins 0..63 (lane l)
  float re64 = wsum(sign * (x0 + x1));                     // bin 64
  float psd64 = re64 * re64 * 0.0078125f;

  const float mult = (l == 0) ? 1.f : 2.f;
  float psum = wsum(psd * mult) + psd64;
  float p2   = wsum(psd * psd * mult) + psd64 * psd64;
  float vm   = wmax(psd);
  float maxp = fmaxf(vm, psd64);
  float meanfreq = (-0.5f * psd64) / psum;
  float pbw = sqrtf(p2 / psum);
  unsigned long long am = __ballot(psd == vm);             // first-index argmax
  int lmin = __builtin_ctzll(am);
  float fmaxv = (psd64 > vm) ? -0.5f : (float)lmin * (1.0f / 128.0f);
  float maxamp = sqrtf(maxp * 128.0f);

  // ---- median via radix-select on float bits (rank 64 of 128 weighted) ----
  const unsigned pu   = __float_as_uint(psd);
  const unsigned pu64 = __float_as_uint(psd64);
  unsigned Pv = 0u;
  #pragma unroll
  for (int bit = 30; bit >= 0; --bit){
    unsigned T = Pv | (1u << bit);
    unsigned long long m = __ballot(pu < T);
    int c = 2 * __popcll(m) - (int)(m & 1ull) + ((pu64 < T) ? 1 : 0);
    if (c <= 64) Pv = T;                 // rank-64 value >= T
  }
  float med;
  {
    unsigned long long em = __ballot(pu == Pv);
    unsigned long long m2b = __ballot(pu < Pv);
    int less = 2 * __popcll(m2b) - (int)(m2b & 1ull) + ((pu64 < Pv) ? 1 : 0);
    if (em){
      int kt = (int)__builtin_ctzll(em);
      med = (less == 64) ? (float)kt * (1.0f / 128.0f)
                         : -(float)kt * (1.0f / 128.0f);
    } else {
      med = -0.5f;                        // rank-64 element is bin 64
    }
  }

  if (l == 0){
    float* o = Xf + (size_t)pp * 40;
    o[0]  = mx;  o[1]  = mn;  o[2]  = sd;   o[3]  = rms; o[4]  = mean;
    o[5]  = mx - mn;  o[6] = var;  o[7] = ent; o[8] = std_asin; o[9] = std_atan;
    o[10] = kurt; o[11] = skew;
    o[12] = meanfreq;
    o[13] = med;
    o[14] = psum;
    o[15] = 1.0f;
    o[16] = pbw;
    o[17] = maxp;
    o[18] = maxamp;
    o[19] = fmaxv;
  }
}

// ---------- K2: cumsum feature (wave-parallel scan) + per-sample norm ----------
__global__ __launch_bounds__(256) void cumnorm_kernel(float* __restrict__ Xf){
  const int b = blockIdx.x, t = threadIdx.x;
  const int wv = t >> 6, l = t & 63;
  __shared__ float arr[128 * 40];
  __shared__ float red4[4];
  float* base = Xf + b * 5120;
  for (int idx = t; idx < 128 * 20; idx += 256){
    int p = idx / 20, c = idx - p * 20;
    arr[p * 40 + c] = base[p * 40 + c];
  }
  __syncthreads();
  // channel c handled by wave c%4: 128-prefix = two 64-lane scans + carry
  #pragma unroll
  for (int k = 0; k < 5; ++k){
    int c = wv + k * 4;                                    // 0..19
    float v0 = arr[l * 40 + c];
    float v1 = arr[(l + 64) * 40 + c];
    float s0 = wscan(v0);
    float tot0 = __shfl(s0, 63, 64);
    float s1 = wscan(v1) + tot0;
    arr[l * 40 + 20 + c]        = s0 / sqrtf(fmaxf(fabsf(s0), 1e-12f));
    arr[(l + 64) * 40 + 20 + c] = s1 / sqrtf(fmaxf(fabsf(s1), 1e-12f));
  }
  __syncthreads();
  float pa = 0.f;
  for (int idx = t; idx < 5120; idx += 256){ float v = arr[idx]; pa = fmaf(v, v, pa); }
  float nrm = sqrtf(rsum256(pa, red4));
  for (int idx = t; idx < 5120; idx += 256) base[idx] = arr[idx] / nrm;
}

// ---------- K3+K4 fused: A_t then A_s (xf loaded once; T reused for T2) ----------
__global__ __launch_bounds__(256) void adj_kernel(const float* __restrict__ Xf,
    const float* __restrict__ tw1, const float* __restrict__ tb1,
    const float* __restrict__ tw2, const float* __restrict__ tb2,
    const float* __restrict__ sw1, const float* __restrict__ sb1,
    const float* __restrict__ sw2, const float* __restrict__ sb2,
    float* __restrict__ At, float* __restrict__ As){
  const int b = blockIdx.x, t = threadIdx.x;
  __shared__ float xf[5120];          // stride 40
  __shared__ float T[128 * 64];       // adjt T1; reused for adjs T2 (40*64)
  const float* src = Xf + b * 5120;
  for (int idx = t; idx < 1280; idx += 256)
    *((float4*)xf + idx) = *((const float4*)src + idx);
  __syncthreads();

  // ---- adjt phase 1: T1[i][k] = tanh(b1[k] + sum_c xf[i][c]*w1[c][k]) ----
  {
    const int k0 = (t & 15) * 4, i0 = (t >> 4) * 8;
    float4 bv = *(const float4*)&tb1[k0];
    float acc[8][4];
    #pragma unroll
    for (int di = 0; di < 8; ++di){ acc[di][0]=bv.x; acc[di][1]=bv.y; acc[di][2]=bv.z; acc[di][3]=bv.w; }
    for (int c = 0; c < 40; ++c){
      float4 wv = *(const float4*)&tw1[c * 64 + k0];
      #pragma unroll
      for (int di = 0; di < 8; ++di){
        float xv = xf[(i0 + di) * 40 + c];
        acc[di][0] = fmaf(xv, wv.x, acc[di][0]);
        acc[di][1] = fmaf(xv, wv.y, acc[di][1]);
        acc[di][2] = fmaf(xv, wv.z, acc[di][2]);
        acc[di][3] = fmaf(xv, wv.w, acc[di][3]);
      }
    }
    #pragma unroll
    for (int di = 0; di < 8; ++di){
      float4 o;
      o.x = tanhf(acc[di][0]); o.y = tanhf(acc[di][1]);
      o.z = tanhf(acc[di][2]); o.w = tanhf(acc[di][3]);
      *(float4*)&T[(i0 + di) * 64 + k0] = o;
    }
  }
  __syncthreads();

  // ---- adjt phase 2: A_t[i][j] = b2[j] + sum_k T1[i][k]*w2[k][j] ----
  {
    const int j0 = (t & 31) * 4, i0 = (t >> 5) * 16;
    float4 bv = *(const float4*)&tb2[j0];
    float acc[16][4];
    #pragma unroll
    for (int di = 0; di < 16; ++di){ acc[di][0]=bv.x; acc[di][1]=bv.y; acc[di][2]=bv.z; acc[di][3]=bv.w; }
    for (int k = 0; k < 64; ++k){
      float4 wv = *(const float4*)&tw2[k * 128 + j0];
      #pragma unroll
      for (int di = 0; di < 16; ++di){
        float tv = T[(i0 + di) * 64 + k];
        acc[di][0] = fmaf(tv, wv.x, acc[di][0]);
        acc[di][1] = fmaf(tv, wv.y, acc[di][1]);
        acc[di][2] = fmaf(tv, wv.z, acc[di][2]);
        acc[di][3] = fmaf(tv, wv.w, acc[di][3]);
      }
    }
    float* dst = At + (size_t)b * 16384;
    #pragma unroll
    for (int di = 0; di < 16; ++di)
      *(float4*)&dst[(i0 + di) * 128 + j0] = *(float4*)acc[di];
  }
  __syncthreads();                      // T dead; reuse as T2

  // ---- adjs phase 1: T2[i][k] = tanh(b1[k] + sum_p xf[p][i]*w1[p][k]) ----
  for (int idx = t; idx < 40 * 64; idx += 256){
    int i = idx >> 6, k = idx & 63;
    float acc = sb1[k];
    for (int p = 0; p < 128; ++p) acc = fmaf(xf[p * 40 + i], sw1[p * 64 + k], acc);
    T[idx] = tanhf(acc);
  }
  __syncthreads();

  // ---- adjs phase 2: A_s[i][j] = b2[j] + sum_k T2[i][k]*w2[k][j] ----
  float* dst = As + b * 1600;
  for (int idx = t; idx < 1600; idx += 256){
    int i = idx / 40, j = idx - i * 40;
    float acc = sb2[j];
    #pragma unroll 8
    for (int k = 0; k < 64; ++k) acc = fmaf(T[i * 64 + k], sw2[k * 40 + j], acc);
    dst[idx] = acc;
  }
}

// ---------- K5+K6 fused: H_s then H_t -> bf16 Hbf (xf loaded once; M reused) ----------
__global__ __launch_bounds__(256) void hsht_kernel(const float* __restrict__ Xf,
    const float* __restrict__ As_g, const float* __restrict__ At_g,
    const float* __restrict__ sw, const float* __restrict__ sb,
    const float* __restrict__ tw, const float* __restrict__ tb,
    short* __restrict__ Hbf){
  const int b = blockIdx.x, t = threadIdx.x;
  __shared__ float xf[5120];          // stride 40
  __shared__ float As[1600];
  __shared__ float M[5120];           // hs M (40x128); reused as ht M2 (128x40)
  const float* src = Xf + b * 5120;
  for (int idx = t; idx < 1280; idx += 256)
    *((float4*)xf + idx) = *((const float4*)src + idx);
  for (int idx = t; idx < 400; idx += 256)
    *((float4*)As + idx) = *((const float4*)(As_g + b * 1600) + idx);
  // zero-pad Hbf rows 168..175
  {
    short* padp = Hbf + (size_t)b * NPAD * 128 + 168 * 128;
    for (int idx = t; idx < 256; idx += 256)
      *(float2*)&padp[idx * 4] = (float2){0.f, 0.f};
  }
  __syncthreads();

  // ---- hs phase 1: M[i][p] = sum_m As[i][m] * xf[p][m]; tile 5i x 4p ----
  {
    const int p0 = (t & 31) * 4, i0 = (t >> 5) * 5;
    float acc[5][4];
    #pragma unroll
    for (int di = 0; di < 5; ++di)
      #pragma unroll
      for (int dp = 0; dp < 4; ++dp) acc[di][dp] = 0.f;
    for (int m = 0; m < 40; m += 4){
      float4 a4[5], x4[4];
      #pragma unroll
      for (int di = 0; di < 5; ++di) a4[di] = *(const float4*)&As[(i0 + di) * 40 + m];
      #pragma unroll
      for (int dp = 0; dp < 4; ++dp) x4[dp] = *(const float4*)&xf[(p0 + dp) * 40 + m];
      #pragma unroll
      for (int dm = 0; dm < 4; ++dm)
        #pragma unroll
        for (int di = 0; di < 5; ++di){
          float av = (&a4[di].x)[dm];
          #pragma unroll
          for (int dp = 0; dp < 4; ++dp)
            acc[di][dp] = fmaf(av, (&x4[dp].x)[dm], acc[di][dp]);
        }
    }
    #pragma unroll
    for (int di = 0; di < 5; ++di)
      *(float4*)&M[(i0 + di) * 128 + p0] = *(float4*)acc[di];
  }
  __syncthreads();

  // ---- hs phase 2: H_s[i][j] -> bf16 Hbf rows 0..39 ----
  {
    const int j0 = (t & 31) * 4, i0 = (t >> 5) * 5;
    float4 bv = *(const float4*)&sb[j0];
    float acc[5][4];
    #pragma unroll
    for (int di = 0; di < 5; ++di){ acc[di][0]=bv.x; acc[di][1]=bv.y; acc[di][2]=bv.z; acc[di][3]=bv.w; }
    for (int p = 0; p < 128; ++p){
      float4 wv = *(const float4*)&sw[p * 128 + j0];
      #pragma unroll
      for (int di = 0; di < 5; ++di){
        float mv = M[(i0 + di) * 128 + p];
        acc[di][0] = fmaf(mv, wv.x, acc[di][0]);
        acc[di][1] = fmaf(mv, wv.y, acc[di][1]);
        acc[di][2] = fmaf(mv, wv.z, acc[di][2]);
        acc[di][3] = fmaf(mv, wv.w, acc[di][3]);
      }
    }
    short* dst = Hbf + (size_t)b * NPAD * 128;
    #pragma unroll
    for (int di = 0; di < 5; ++di){
      short4v o;
      #pragma unroll
      for (int q = 0; q < 4; ++q){
        float v = acc[di][q];
        v = (v >= 0.f) ? v : 0.01f * v;
        o[q] = (short)f2bf(v);
      }
      *(short4v*)&dst[(i0 + di) * 128 + j0] = o;
    }
  }
  __syncthreads();                      // M dead; reuse as M2

  // ---- ht phase 1: M2[i][c] = sum_m At[i][m] * xf[m][c]; tile 4i x 5c ----
  {
    const int c0 = (t & 7) * 5, i0 = (t >> 3) * 4;
    const float* At = At_g + (size_t)b * 16384;
    float acc[4][5];
    #pragma unroll
    for (int di = 0; di < 4; ++di)
      #pragma unroll
      for (int dc = 0; dc < 5; ++dc) acc[di][dc] = 0.f;
    for (int m = 0; m < 128; m += 4){
      float4 a4[4];
      #pragma unroll
      for (int di = 0; di < 4; ++di) a4[di] = *(const float4*)&At[(i0 + di) * 128 + m];
      #pragma unroll
      for (int dm = 0; dm < 4; ++dm){
        float xv[5];
        #pragma unroll
        for (int dc = 0; dc < 5; ++dc) xv[dc] = xf[(m + dm) * 40 + c0 + dc];
        #pragma unroll
        for (int di = 0; di < 4; ++di){
          float av = (&a4[di].x)[dm];
          #pragma unroll
          for (int dc = 0; dc < 5; ++dc)
            acc[di][dc] = fmaf(av, xv[dc], acc[di][dc]);
        }
      }
    }
    #pragma unroll
    for (int di = 0; di < 4; ++di)
      #pragma unroll
      for (int dc = 0; dc < 5; ++dc)
        M[(i0 + di) * 40 + c0 + dc] = acc[di][dc];
  }
  __syncthreads();

  // ---- ht phase 2: H_t[i][j] -> bf16 Hbf rows 40..167 ----
  {
    const int j0 = (t & 31) * 4, i0 = (t >> 5) * 16;
    float4 bv = *(const float4*)&tb[j0];
    float acc[16][4];
    #pragma unroll
    for (int di = 0; di < 16; ++di){ acc[di][0]=bv.x; acc[di][1]=bv.y; acc[di][2]=bv.z; acc[di][3]=bv.w; }
    for (int c = 0; c < 40; ++c){
      float4 wv = *(const float4*)&tw[c * 128 + j0];
      #pragma unroll
      for (int di = 0; di < 16; ++di){
        float mv = M[(i0 + di) * 40 + c];
        acc[di][0] = fmaf(mv, wv.x, acc[di][0]);
        acc[di][1] = fmaf(mv, wv.y, acc[di][1]);
        acc[di][2] = fmaf(mv, wv.z, acc[di][2]);
        acc[di][3] = fmaf(mv, wv.w, acc[di][3]);
      }
    }
    short* dst = Hbf + (size_t)b * NPAD * 128 + 40 * 128;
    #pragma unroll
    for (int di = 0; di < 16; ++di){
      short4v o;
      #pragma unroll
      for (int q = 0; q < 4; ++q){
        float v = acc[di][q];
        v = (v >= 0.f) ? v : 0.01f * v;
        o[q] = (short)f2bf(v);
      }
      *(short4v*)&dst[(i0 + di) * 128 + j0] = o;
    }
  }
}

// out[b] = fc_b + sum_h c4[h]
__global__ void initout_kernel(float* __restrict__ out, const float* __restrict__ fcb,
                               const float* __restrict__ c4){
  int i = blockIdx.x * 256 + threadIdx.x;
  float base = fcb[0] + c4[0] + c4[1] + c4[2] + c4[3];
  if (i < BSZ) out[i] = base;
}

// ---------- prep: per-head M^T, R = fcw·Wv^T, c1/c2/c3/c4; grid (NH, 11) ----------
__global__ __launch_bounds__(256) void prep_kernel(
    const float* __restrict__ qw, const float* __restrict__ qb,
    const float* __restrict__ kw, const float* __restrict__ kb,
    const float* __restrict__ vw, const float* __restrict__ vb,
    const float* __restrict__ fcw,
    short* __restrict__ MT, short* __restrict__ Rbf,
    float* __restrict__ c1, float* __restrict__ c2,
    float* __restrict__ c3, float* __restrict__ c4){
  const int h = blockIdx.x, sl = blockIdx.y, t = threadIdx.x;
  const float* Q = qw + h * 16384;
  const float* K = kw + h * 16384;
  const float* V = vw + h * 16384;
  if (sl < 8){
    for (int idx = t; idx < 2048; idx += 256){
      int j = sl * 16 + (idx >> 7), d = idx & 127;
      float acc = 0.f;
      for (int e = 0; e < 128; ++e) acc = fmaf(Q[d * 128 + e], K[j * 128 + e], acc);
      MT[h * 16384 + j * 128 + d] = (short)f2bf(acc);     // MT[j][d] = M[d][j]
    }
    if (t < 16){
      int r = sl * 16 + t;
      float a = 0.f, bsum = 0.f;
      for (int e = 0; e < 128; ++e){
        a    = fmaf(Q[r * 128 + e], kb[h * 128 + e], a);
        bsum = fmaf(K[r * 128 + e], qb[h * 128 + e], bsum);
      }
      c1[h * 128 + r] = a;
      c2[h * 128 + r] = bsum;
    }
  }
  // R rows n in [sl*16, sl*16+16); zero-pad n >= 168
  for (int idx = t; idx < 2048; idx += 256){
    int n = sl * 16 + (idx >> 7), d = idx & 127;
    float acc = 0.f;
    if (n < N){
      const float* fr = fcw + n * 512 + h * 128;
      const float* vr = V + d * 128;
      for (int e = 0; e < 128; ++e) acc = fmaf(fr[e], vr[e], acc);
    }
    Rbf[h * 22528 + n * 128 + d] = (short)f2bf(acc);
  }
  if (sl == 0){
    if (t == 0){
      float a = 0.f;
      for (int e = 0; e < 128; ++e) a = fmaf(qb[h * 128 + e], kb[h * 128 + e], a);
      c3[h] = a;
    }
    if (t >= 64 && t < 128){                  // wave 1: c4 reduction
      int l = t - 64;
      float part = 0.f;
      for (int i = l; i < N * 128; i += 64){
        int n = i >> 7, e = i & 127;
        part = fmaf(fcw[n * 512 + h * 128 + e], vb[h * 128 + e], part);
      }
      part = wsum(part);
      if (l == 0) c4[h] = part;
    }
  }
}

// ---------- u1/u2 precompute: u1[n]=H[n]·c1, u2[n]=H[n]·c2 per (b,h) ----------
__global__ __launch_bounds__(256) void uprep_kernel(const short* __restrict__ Hbf,
    const float* __restrict__ c1, const float* __restrict__ c2,
    float* __restrict__ u1g, float* __restrict__ u2g){
  const int b = blockIdx.x, t = threadIdx.x;
  for (int idx = t; idx < 176 * 4; idx += 256){
    int n = idx >> 2, h = idx & 3;
    const bf16x8* rp = (const bf16x8*)(Hbf + (size_t)b * NPAD * 128 + (size_t)n * 128);
    const float* C1 = c1 + h * 128;
    const float* C2 = c2 + h * 128;
    float a1 = 0.f, a2 = 0.f;
    for (int kk = 0; kk < 16; ++kk){
      bf16x8 v = rp[kk];
      #pragma unroll
      for (int j = 0; j < 8; ++j){
        float hv = bf2f((unsigned short)v[j]);
        a1 = fmaf(hv, C1[kk * 8 + j], a1);
        a2 = fmaf(hv, C2[kk * 8 + j], a2);
      }
    }
    u1g[(size_t)(b * 4 + h) * 176 + n] = a1;
    u2g[(size_t)(b * 4 + h) * 176 + n] = a2;
  }
}

// ---------- attention, flash-style, 8-wave block: grid (b) ----------
// (512,2): LDS 78KB -> 2 blocks/CU; VGPR free to ~128, no spill.
// ti task loop #pragma unroll 1 (r9 lesson: full unroll -> spill).
__global__ __launch_bounds__(512, 2) void attn_flash(
    const short* __restrict__ Hbf, const short* __restrict__ MT,
    const short* __restrict__ Rbf,
    const float* __restrict__ u1g, const float* __restrict__ u2g,
    const float* __restrict__ c3g, float* __restrict__ out){
  const int b = blockIdx.x;
  const int t = threadIdx.x;
  const int wv = t >> 6, l = t & 63, quad = l >> 4, l15 = l & 15;
  const int h = wv & 3;

  __shared__ __align__(16) short Hsh[NPAD * 128];     // 45KB, swizzled
  __shared__ __align__(16) short Tsh[8 * 2048];       // 32KB, 4KB/wave private
  __shared__ float red8[8];

  const short* Hb = Hbf + (size_t)b * NPAD * 128;

  // ---- cooperative stage: 2816 x 16B units, coalesced global, swizzled LDS ----
  #pragma unroll
  for (int i = 0; i < 6; ++i){
    int idx = t + i * 512;
    if (idx < 2816){
      int row = idx >> 4, g = idx & 15;
      bf16x8 v = *(const bf16x8*)(Hb + row * 128 + g * 8);
      *(bf16x8*)(Hsh + row * 128 + ((g ^ (row & 15)) * 8)) = v;
    }
  }
  __syncthreads();

  const short* MTh = MT + h * 16384;
  const short* Rh  = Rbf + h * 22528;
  const float c3v = c3g[h];
  const float inv = 0.08838834764831845f;   // 1/sqrt(128)
  const float* u1p = u1g + (size_t)(b * 4 + h) * 176;
  const float* u2p = u2g + (size_t)(b * 4 + h) * 176;
  short* Tw = Tsh + wv * 2048;

  float tp = 0.f;
  #pragma unroll 1
  for (int ti = 0; ti < 6; ++ti){
    const int zt = (wv >> 2) + ti * 2;
    if (zt < 11){                                  // wave-uniform guard
      const int rowbase = zt * 16;

      // A-frags (H rows, from LDS) and R-frags (global, L2-hot)
      bf16x8 HA[4], RA[4];
      #pragma unroll
      for (int kk = 0; kk < 4; ++kk){
        HA[kk] = *(const bf16x8*)(Hsh + (rowbase + l15) * 128 + (((kk * 4 + quad) ^ l15) * 8));
        RA[kk] = *(const bf16x8*)(Rh + (rowbase + l15) * 128 + kk * 32 + quad * 8);
      }
      float u1v[4];
      #pragma unroll
      for (int r = 0; r < 4; ++r) u1v[r] = u1p[rowbase + quad * 4 + r];

      // ---- Phase A: T = H_chunk @ M -> private LDS slice (XOR-swizzled) ----
      #pragma unroll
      for (int jt = 0; jt < 8; ++jt){
        const int j0 = jt * 16;
        f32x4 acc = {0.f, 0.f, 0.f, 0.f};
        #pragma unroll
        for (int kk = 0; kk < 4; ++kk){
          bf16x8 Bv = *(const bf16x8*)(MTh + (j0 + l15) * 128 + kk * 32 + quad * 8);
          acc = __builtin_amdgcn_mfma_f32_16x16x32_bf16(HA[kk], Bv, acc, 0, 0, 0);
        }
        const int jcol = j0 + l15, ch = jcol >> 3;
        #pragma unroll
        for (int r = 0; r < 4; ++r){
          int row = quad * 4 + r;
          Tw[row * 128 + ((ch ^ row) << 3) + (jcol & 7)] = (short)f2bf(acc[r]);
        }
      }
      // no barrier: same-wave DS ops are ordered

      // ---- Phase BG + per-lane online softmax over 11 m-tiles ----
      float Mx[4], Av[4], Dv[4];
      #pragma unroll
      for (int r = 0; r < 4; ++r){ Mx[r] = -1e30f; Av[r] = 0.f; Dv[r] = 0.f; }

      #pragma unroll
      for (int mt = 0; mt < 11; ++mt){
        const int m0 = mt * 16;
        bf16x8 Bv[4];
        #pragma unroll
        for (int kk = 0; kk < 4; ++kk)
          Bv[kk] = *(const bf16x8*)(Hsh + (m0 + l15) * 128 + (((kk * 4 + quad) ^ l15) * 8));
        const float u2v = u2p[m0 + l15];
        f32x4 acc = {0.f, 0.f, 0.f, 0.f};
        f32x4 g   = {0.f, 0.f, 0.f, 0.f};
        #pragma unroll
        for (int kk = 0; kk < 4; ++kk){
          bf16x8 A = *(const bf16x8*)(Tw + l15 * 128 + (((kk * 4 + quad) ^ l15) << 3));
          acc = __builtin_amdgcn_mfma_f32_16x16x32_bf16(A, Bv[kk], acc, 0, 0, 0);
          g   = __builtin_amdgcn_mfma_f32_16x16x32_bf16(RA[kk], Bv[kk], g, 0, 0, 0);
        }
        const bool padcol = (mt == 10) && (l15 >= 8);     // cols 168..175 masked
        #pragma unroll
        for (int r = 0; r < 4; ++r){
          float s = padcol ? -1e30f : (acc[r] + u1v[r] + u2v + c3v) * inv;
          float Mn = fmaxf(Mx[r], s);
          float ea = __expf(Mx[r] - Mn);
          float eb = __expf(s - Mn);
          Av[r] = fmaf(Av[r], ea, eb * g[r]);
          Dv[r] = fmaf(Dv[r], ea, eb);
          Mx[r] = Mn;
        }
      }

      // ---- merge (M,A,D) across the 16 l15 lanes (stays within quad) ----
      #pragma unroll
      for (int r = 0; r < 4; ++r){
        #pragma unroll
        for (int o = 1; o < 16; o <<= 1){
          float M2 = __shfl_xor(Mx[r], o, 64);
          float A2 = __shfl_xor(Av[r], o, 64);
          float D2 = __shfl_xor(Dv[r], o, 64);
          float Mn = fmaxf(Mx[r], M2);
          float ea = __expf(Mx[r] - Mn);
          float eb = __expf(M2 - Mn);
          Av[r] = fmaf(Av[r], ea, A2 * eb);
          Dv[r] = fmaf(Dv[r], ea, D2 * eb);
          Mx[r] = Mn;
        }
      }

      // ---- per-row A/D, replicated over 16 lanes -> scale by 1/16 ----
      #pragma unroll
      for (int r = 0; r < 4; ++r){
        int n = rowbase + quad * 4 + r;
        if (n < N) tp += Av[r] / Dv[r];
      }
    }
  }
  tp *= (1.0f / 16.0f);

  // ---- block reduction over 8 waves ----
  #pragma unroll
  for (int o = 32; o > 0; o >>= 1) tp += __shfl_down(tp, o, 64);
  if (l == 0) red8[wv] = tp;
  __syncthreads();
  if (t == 0){
    float s = 0.f;
    #pragma unroll
    for (int i = 0; i < 8; ++i) s += red8[i];
    atomicAdd(out + b, s);
  }
}

} // anonymous namespace

extern "C" void kernel_launch(void* const* d_in, const int* in_sizes, int n_in,
                              void* d_out, int out_size, void* d_ws, size_t ws_size,
                              hipStream_t stream) {
  (void)in_sizes; (void)n_in; (void)out_size;
  const float* X      = (const float*)d_in[0];
  const float* spa_w1 = (const float*)d_in[1];
  const float* spa_b1 = (const float*)d_in[2];
  const float* spa_w2 = (const float*)d_in[3];
  const float* spa_b2 = (const float*)d_in[4];
  const float* tem_w1 = (const float*)d_in[5];
  const float* tem_b1 = (const float*)d_in[6];
  const float* tem_w2 = (const float*)d_in[7];
  const float* tem_b2 = (const float*)d_in[8];
  const float* sgnn_w = (const float*)d_in[9];
  const float* sgnn_b = (const float*)d_in[10];
  const float* tgnn_w = (const float*)d_in[11];
  const float* tgnn_b = (const float*)d_in[12];
  const float* q_w    = (const float*)d_in[13];
  const float* q_b    = (const float*)d_in[14];
  const float* k_w    = (const float*)d_in[15];
  const float* k_b    = (const float*)d_in[16];
  const float* v_w    = (const float*)d_in[17];
  const float* v_b    = (const float*)d_in[18];
  const float* fc_w   = (const float*)d_in[19];
  const float* fc_b   = (const float*)d_in[20];
  float* out = (float*)d_out;

  if (ws_size < (size_t)182714368) return;

  char* wsb = (char*)d_ws;
  short* Hbf = (short*)wsb;                      // bf16 H [0, 46.1MB)
  float* u1g = (float*)(wsb + 50331648);
  float* u2g = (float*)(wsb + 53215232);
  char*  Rb  = wsb + 88080384;
  float* Xf  = (float*)Rb;
  float* As  = (float*)(Rb + 20971520);
  float* At  = (float*)(Rb + 27525120);
  char*  Pb  = Rb + 46137344;
  short* MT  = (short*)Pb;                       // 131072 B
  short* Rbf = (short*)(Pb + 131072);            // 180224 B
  float* c1  = (float*)(Pb + 311296);
  float* c2  = (float*)(Pb + 313344);
  float* c3  = (float*)(Pb + 315392);
  float* c4  = (float*)(Pb + 315408);
  float* twg = (float*)(Pb + 327680);            // 32KB twiddle table

  twiddle_kernel<<<16, 256, 0, stream>>>(twg);
  feat_kernel<<<BSZ * P / 4, 256, 0, stream>>>(X, twg, Xf);
  cumnorm_kernel<<<BSZ, 256, 0, stream>>>(Xf);
  adj_kernel<<<BSZ, 256, 0, stream>>>(Xf, tem_w1, tem_b1, tem_w2, tem_b2,
                                      spa_w1, spa_b1, spa_w2, spa_b2, At, As);
  hsht_kernel<<<BSZ, 256, 0, stream>>>(Xf, As, At, sgnn_w, sgnn_b, tgnn_w, tgnn_b, Hbf);
  prep_kernel<<<dim3(NH, 11), 256, 0, stream>>>(q_w, q_b, k_w, k_b, v_w, v_b, fc_w,
                                                MT, Rbf, c1, c2, c3, c4);
  uprep_kernel<<<BSZ, 256, 0, stream>>>(Hbf, c1, c2, u1g, u2g);
  initout_kernel<<<4, 256, 0, stream>>>(out, fc_b, c4);
  attn_flash<<<dim3(BSZ), 512, 0, stream>>>(Hbf, MT, Rbf, u1g, u2g, c3, out);
}

// Round 14
// 1015.356 us; speedup vs baseline: 1.3767x; 1.0168x over previous
//
#include <hip/hip_runtime.h>
#include <math.h>

namespace {

constexpr int BSZ  = 1024;
constexpr int P    = 128;
constexpr int HG   = 128;
constexpr int NH   = 4;
constexpr int N    = 168;     // P + IND
constexpr int NPAD = 176;     // padded token count (11 tiles of 16)

typedef short bf16x8 __attribute__((ext_vector_type(8)));
typedef float f32x4  __attribute__((ext_vector_type(4)));
typedef short short4v __attribute__((ext_vector_type(4)));

__device__ __forceinline__ unsigned short f2bf(float x){
  union { float f; unsigned u; } v; v.f = x;
  unsigned r = (v.u + 0x7FFF + ((v.u >> 16) & 1)) >> 16;
  return (unsigned short)r;
}
__device__ __forceinline__ float bf2f(unsigned short b){
  union { unsigned u; float f; } v; v.u = ((unsigned)b) << 16;
  return v.f;
}

// ---------- wave (64-lane) butterfly reductions: result in ALL lanes ----------
__device__ __forceinline__ float wsum(float v){
  #pragma unroll
  for (int o = 1; o < 64; o <<= 1) v += __shfl_xor(v, o, 64);
  return v;
}
__device__ __forceinline__ float wmax(float v){
  #pragma unroll
  for (int o = 1; o < 64; o <<= 1) v = fmaxf(v, __shfl_xor(v, o, 64));
  return v;
}
__device__ __forceinline__ float wmin(float v){
  #pragma unroll
  for (int o = 1; o < 64; o <<= 1) v = fminf(v, __shfl_xor(v, o, 64));
  return v;
}
// inclusive 64-lane scan
__device__ __forceinline__ float wscan(float v){
  #pragma unroll
  for (int o = 1; o < 64; o <<= 1){
    float u = __shfl_up(v, o, 64);
    if ((threadIdx.x & 63) >= o) v += u;
  }
  return v;
}
__device__ __forceinline__ float rsum256(float v, volatile float* red4){
  #pragma unroll
  for (int o = 32; o > 0; o >>= 1) v += __shfl_down(v, o, 64);
  __syncthreads();
  if ((threadIdx.x & 63) == 0) red4[threadIdx.x >> 6] = v;
  __syncthreads();
  return red4[0] + red4[1] + red4[2] + red4[3];
}

// ---------- twiddle table: tw[tt*64+l] = cos(2pi*(l*tt mod 128)/128),
//            tw[4096+...] = -sin(...)  ----------
__global__ void twiddle_kernel(float* __restrict__ tw){
  int i = blockIdx.x * 256 + threadIdx.x;
  if (i < 4096){
    int tt = i >> 6, l = i & 63;
    int k = (l * tt) & 127;
    float ang = (float)k * (-0.049087385212340517f);   // -2*pi/128
    tw[i]        = cosf(ang);
    tw[4096 + i] = sinf(ang);
  }
}

// ---------- K1: per-patch features, one WAVE per patch; 8 waves/block ----------
// 512-thread blocks amortize the 32KB twiddle table over 8 waves: LDS 36.9KB ->
// 4 blocks/CU -> 32 waves/CU (100% cap, was 16/50%). Kernel is latency-bound
// (r13: conflicts 0, VALUBusy 69%, Occ 44%) -> 2x TLP hides the reduction and
// transcendental chains. Per-wave code unchanged.
__global__ __launch_bounds__(512) void feat_kernel(const float* __restrict__ X,
                                                   const float* __restrict__ twg,
                                                   float* __restrict__ Xf){
  const int wave = threadIdx.x >> 6, l = threadIdx.x & 63;
  const int pp = blockIdx.x * 8 + wave;          // patch id
  const float* xp = X + (size_t)pp * 128;
  const float x0 = xp[l];
  const float x1 = xp[l + 64];

  __shared__ float tws[8192];                    // 32KB: cos[4096], -sin[4096]
  __shared__ float sesh[8 * 130];                // per-wave: [0..63]=x0+x1, [65..128]=x0-x1
  sesh[wave * 130 + l]      = x0 + x1;
  sesh[wave * 130 + 65 + l] = x0 - x1;
  for (int idx = threadIdx.x; idx < 2048; idx += 512)
    *((float4*)tws + idx) = *((const float4*)twg + idx);
  __syncthreads();

  // ---- temporal ----
  float sum   = wsum(x0 + x1);
  float mean  = sum * (1.0f / 128.0f);
  float mx    = wmax(fmaxf(x0, x1));
  float mn    = wmin(fminf(x0, x1));
  float sumsq = wsum(fmaf(x0, x0, x1 * x1));
  float c0 = x0 - mean, c1_ = x1 - mean;
  float c0q = c0 * c0, c1q = c1_ * c1_;
  float m2 = wsum(c0q + c1q);
  float m3 = wsum(c0q * c0 + c1q * c1_);
  float m4 = wsum(c0q * c0q + c1q * c1q);
  float var = m2 * (1.0f / 127.0f);
  float sd  = sqrtf(var);
  float rms = sqrtf(sumsq * (1.0f / 128.0f));
  float ex0 = __expf(x0 - mx), ex1 = __expf(x1 - mx);
  float Z   = wsum(ex0 + ex1);
  float SxE = wsum(fmaf(ex0, x0, ex1 * x1));
  float ent = (mx + __logf(Z)) - SxE / Z;
  const float lo = (float)(-1.0 + 1e-7), hi = (float)(1.0 - 1e-7);
  float a0 = asinf(fminf(fmaxf(x0, lo), hi));
  float a1 = asinf(fminf(fmaxf(x1, lo), hi));
  float amean = wsum(a0 + a1) * (1.0f / 128.0f);
  float ad0 = a0 - amean, ad1 = a1 - amean;
  float std_asin = sqrtf(wsum(fmaf(ad0, ad0, ad1 * ad1)) * (1.0f / 127.0f));
  float b0 = atanf(x0), b1v = atanf(x1);
  float bmean = wsum(b0 + b1v) * (1.0f / 128.0f);
  float bd0 = b0 - bmean, bd1 = b1v - bmean;
  float std_atan = sqrtf(wsum(fmaf(bd0, bd0, bd1 * bd1)) * (1.0f / 127.0f));
  float kurt = (m4 * (1.0f / 128.0f)) / (sd * sd * sd * sd) - 3.0f;
  float skew = (m3 * (1.0f / 128.0f)) / (sd * sd * sd);

  // ---- DFT: lane l computes bin l; se + twiddles from LDS; 4 indep chains ----
  const float sign = (l & 1) ? -1.0f : 1.0f;
  const float* sep = &sesh[wave * 130 + (l & 1) * 65];
  float re0 = 0.f, re1 = 0.f, im0 = 0.f, im1 = 0.f;
  #pragma unroll
  for (int tt = 0; tt < 64; tt += 2){
    float seA = sep[tt];
    float seB = sep[tt + 1];
    re0 = fmaf(seA, tws[tt * 64 + l], re0);
    im0 = fmaf(seA, tws[4096 + tt * 64 + l], im0);
    re1 = fmaf(seB, tws[(tt + 1) * 64 + l], re1);
    im1 = fmaf(seB, tws[4096 + (tt + 1) * 64 + l], im1);
  }
  float re = re0 + re1, im = im0 + im1;
  float psd = fmaf(re, re, im * im) * 0.0078125f;          // bins 0..63 (lane l)
  float re64 = wsum(sign * (x0 + x1));                     // bin 64
  float psd64 = re64 * re64 * 0.0078125f;

  const float mult = (l == 0) ? 1.f : 2.f;
  float psum = wsum(psd * mult) + psd64;
  float p2   = wsum(psd * psd * mult) + psd64 * psd64;
  float vm   = wmax(psd);
  float maxp = fmaxf(vm, psd64);
  float meanfreq = (-0.5f * psd64) / psum;
  float pbw = sqrtf(p2 / psum);
  unsigned long long am = __ballot(psd == vm);             // first-index argmax
  int lmin = __builtin_ctzll(am);
  float fmaxv = (psd64 > vm) ? -0.5f : (float)lmin * (1.0f / 128.0f);
  float maxamp = sqrtf(maxp * 128.0f);

  // ---- median via radix-select on float bits (rank 64 of 128 weighted) ----
  const unsigned pu   = __float_as_uint(psd);
  const unsigned pu64 = __float_as_uint(psd64);
  unsigned Pv = 0u;
  #pragma unroll
  for (int bit = 30; bit >= 0; --bit){
    unsigned T = Pv | (1u << bit);
    unsigned long long m = __ballot(pu < T);
    int c = 2 * __popcll(m) - (int)(m & 1ull) + ((pu64 < T) ? 1 : 0);
    if (c <= 64) Pv = T;                 // rank-64 value >= T
  }
  float med;
  {
    unsigned long long em = __ballot(pu == Pv);
    unsigned long long m2b = __ballot(pu < Pv);
    int less = 2 * __popcll(m2b) - (int)(m2b & 1ull) + ((pu64 < Pv) ? 1 : 0);
    if (em){
      int kt = (int)__builtin_ctzll(em);
      med = (less == 64) ? (float)kt * (1.0f / 128.0f)
                         : -(float)kt * (1.0f / 128.0f);
    } else {
      med = -0.5f;                        // rank-64 element is bin 64
    }
  }

  if (l == 0){
    float* o = Xf + (size_t)pp * 40;
    o[0]  = mx;  o[1]  = mn;  o[2]  = sd;   o[3]  = rms; o[4]  = mean;
    o[5]  = mx - mn;  o[6] = var;  o[7] = ent; o[8] = std_asin; o[9] = std_atan;
    o[10] = kurt; o[11] = skew;
    o[12] = meanfreq;
    o[13] = med;
    o[14] = psum;
    o[15] = 1.0f;
    o[16] = pbw;
    o[17] = maxp;
    o[18] = maxamp;
    o[19] = fmaxv;
  }
}

// ---------- K2: cumsum feature (wave-parallel scan) + per-sample norm ----------
__global__ __launch_bounds__(256) void cumnorm_kernel(float* __restrict__ Xf){
  const int b = blockIdx.x, t = threadIdx.x;
  const int wv = t >> 6, l = t & 63;
  __shared__ float arr[128 * 40];
  __shared__ float red4[4];
  float* base = Xf + b * 5120;
  for (int idx = t; idx < 128 * 20; idx += 256){
    int p = idx / 20, c = idx - p * 20;
    arr[p * 40 + c] = base[p * 40 + c];
  }
  __syncthreads();
  // channel c handled by wave c%4: 128-prefix = two 64-lane scans + carry
  #pragma unroll
  for (int k = 0; k < 5; ++k){
    int c = wv + k * 4;                                    // 0..19
    float v0 = arr[l * 40 + c];
    float v1 = arr[(l + 64) * 40 + c];
    float s0 = wscan(v0);
    float tot0 = __shfl(s0, 63, 64);
    float s1 = wscan(v1) + tot0;
    arr[l * 40 + 20 + c]        = s0 / sqrtf(fmaxf(fabsf(s0), 1e-12f));
    arr[(l + 64) * 40 + 20 + c] = s1 / sqrtf(fmaxf(fabsf(s1), 1e-12f));
  }
  __syncthreads();
  float pa = 0.f;
  for (int idx = t; idx < 5120; idx += 256){ float v = arr[idx]; pa = fmaf(v, v, pa); }
  float nrm = sqrtf(rsum256(pa, red4));
  for (int idx = t; idx < 5120; idx += 256) base[idx] = arr[idx] / nrm;
}

// ---------- K3+K4 fused: A_t then A_s (xf loaded once; T reused for T2) ----------
__global__ __launch_bounds__(256) void adj_kernel(const float* __restrict__ Xf,
    const float* __restrict__ tw1, const float* __restrict__ tb1,
    const float* __restrict__ tw2, const float* __restrict__ tb2,
    const float* __restrict__ sw1, const float* __restrict__ sb1,
    const float* __restrict__ sw2, const float* __restrict__ sb2,
    float* __restrict__ At, float* __restrict__ As){
  const int b = blockIdx.x, t = threadIdx.x;
  __shared__ float xf[5120];          // stride 40
  __shared__ float T[128 * 64];       // adjt T1; reused for adjs T2 (40*64)
  const float* src = Xf + b * 5120;
  for (int idx = t; idx < 1280; idx += 256)
    *((float4*)xf + idx) = *((const float4*)src + idx);
  __syncthreads();

  // ---- adjt phase 1: T1[i][k] = tanh(b1[k] + sum_c xf[i][c]*w1[c][k]) ----
  {
    const int k0 = (t & 15) * 4, i0 = (t >> 4) * 8;
    float4 bv = *(const float4*)&tb1[k0];
    float acc[8][4];
    #pragma unroll
    for (int di = 0; di < 8; ++di){ acc[di][0]=bv.x; acc[di][1]=bv.y; acc[di][2]=bv.z; acc[di][3]=bv.w; }
    for (int c = 0; c < 40; ++c){
      float4 wv = *(const float4*)&tw1[c * 64 + k0];
      #pragma unroll
      for (int di = 0; di < 8; ++di){
        float xv = xf[(i0 + di) * 40 + c];
        acc[di][0] = fmaf(xv, wv.x, acc[di][0]);
        acc[di][1] = fmaf(xv, wv.y, acc[di][1]);
        acc[di][2] = fmaf(xv, wv.z, acc[di][2]);
        acc[di][3] = fmaf(xv, wv.w, acc[di][3]);
      }
    }
    #pragma unroll
    for (int di = 0; di < 8; ++di){
      float4 o;
      o.x = tanhf(acc[di][0]); o.y = tanhf(acc[di][1]);
      o.z = tanhf(acc[di][2]); o.w = tanhf(acc[di][3]);
      *(float4*)&T[(i0 + di) * 64 + k0] = o;
    }
  }
  __syncthreads();

  // ---- adjt phase 2: A_t[i][j] = b2[j] + sum_k T1[i][k]*w2[k][j] ----
  {
    const int j0 = (t & 31) * 4, i0 = (t >> 5) * 16;
    float4 bv = *(const float4*)&tb2[j0];
    float acc[16][4];
    #pragma unroll
    for (int di = 0; di < 16; ++di){ acc[di][0]=bv.x; acc[di][1]=bv.y; acc[di][2]=bv.z; acc[di][3]=bv.w; }
    for (int k = 0; k < 64; ++k){
      float4 wv = *(const float4*)&tw2[k * 128 + j0];
      #pragma unroll
      for (int di = 0; di < 16; ++di){
        float tv = T[(i0 + di) * 64 + k];
        acc[di][0] = fmaf(tv, wv.x, acc[di][0]);
        acc[di][1] = fmaf(tv, wv.y, acc[di][1]);
        acc[di][2] = fmaf(tv, wv.z, acc[di][2]);
        acc[di][3] = fmaf(tv, wv.w, acc[di][3]);
      }
    }
    float* dst = At + (size_t)b * 16384;
    #pragma unroll
    for (int di = 0; di < 16; ++di)
      *(float4*)&dst[(i0 + di) * 128 + j0] = *(float4*)acc[di];
  }
  __syncthreads();                      // T dead; reuse as T2

  // ---- adjs phase 1: T2[i][k] = tanh(b1[k] + sum_p xf[p][i]*w1[p][k]) ----
  for (int idx = t; idx < 40 * 64; idx += 256){
    int i = idx >> 6, k = idx & 63;
    float acc = sb1[k];
    for (int p = 0; p < 128; ++p) acc = fmaf(xf[p * 40 + i], sw1[p * 64 + k], acc);
    T[idx] = tanhf(acc);
  }
  __syncthreads();

  // ---- adjs phase 2: A_s[i][j] = b2[j] + sum_k T2[i][k]*w2[k][j] ----
  float* dst = As + b * 1600;
  for (int idx = t; idx < 1600; idx += 256){
    int i = idx / 40, j = idx - i * 40;
    float acc = sb2[j];
    #pragma unroll 8
    for (int k = 0; k < 64; ++k) acc = fmaf(T[i * 64 + k], sw2[k * 40 + j], acc);
    dst[idx] = acc;
  }
}

// ---------- K5+K6 fused: H_s then H_t -> bf16 Hbf (xf loaded once; M reused) ----------
__global__ __launch_bounds__(256) void hsht_kernel(const float* __restrict__ Xf,
    const float* __restrict__ As_g, const float* __restrict__ At_g,
    const float* __restrict__ sw, const float* __restrict__ sb,
    const float* __restrict__ tw, const float* __restrict__ tb,
    short* __restrict__ Hbf){
  const int b = blockIdx.x, t = threadIdx.x;
  __shared__ float xf[5120];          // stride 40
  __shared__ float As[1600];
  __shared__ float M[5120];           // hs M (40x128); reused as ht M2 (128x40)
  const float* src = Xf + b * 5120;
  for (int idx = t; idx < 1280; idx += 256)
    *((float4*)xf + idx) = *((const float4*)src + idx);
  for (int idx = t; idx < 400; idx += 256)
    *((float4*)As + idx) = *((const float4*)(As_g + b * 1600) + idx);
  // zero-pad Hbf rows 168..175
  {
    short* padp = Hbf + (size_t)b * NPAD * 128 + 168 * 128;
    for (int idx = t; idx < 256; idx += 256)
      *(float2*)&padp[idx * 4] = (float2){0.f, 0.f};
  }
  __syncthreads();

  // ---- hs phase 1: M[i][p] = sum_m As[i][m] * xf[p][m]; tile 5i x 4p ----
  {
    const int p0 = (t & 31) * 4, i0 = (t >> 5) * 5;
    float acc[5][4];
    #pragma unroll
    for (int di = 0; di < 5; ++di)
      #pragma unroll
      for (int dp = 0; dp < 4; ++dp) acc[di][dp] = 0.f;
    for (int m = 0; m < 40; m += 4){
      float4 a4[5], x4[4];
      #pragma unroll
      for (int di = 0; di < 5; ++di) a4[di] = *(const float4*)&As[(i0 + di) * 40 + m];
      #pragma unroll
      for (int dp = 0; dp < 4; ++dp) x4[dp] = *(const float4*)&xf[(p0 + dp) * 40 + m];
      #pragma unroll
      for (int dm = 0; dm < 4; ++dm)
        #pragma unroll
        for (int di = 0; di < 5; ++di){
          float av = (&a4[di].x)[dm];
          #pragma unroll
          for (int dp = 0; dp < 4; ++dp)
            acc[di][dp] = fmaf(av, (&x4[dp].x)[dm], acc[di][dp]);
        }
    }
    #pragma unroll
    for (int di = 0; di < 5; ++di)
      *(float4*)&M[(i0 + di) * 128 + p0] = *(float4*)acc[di];
  }
  __syncthreads();

  // ---- hs phase 2: H_s[i][j] -> bf16 Hbf rows 0..39 ----
  {
    const int j0 = (t & 31) * 4, i0 = (t >> 5) * 5;
    float4 bv = *(const float4*)&sb[j0];
    float acc[5][4];
    #pragma unroll
    for (int di = 0; di < 5; ++di){ acc[di][0]=bv.x; acc[di][1]=bv.y; acc[di][2]=bv.z; acc[di][3]=bv.w; }
    for (int p = 0; p < 128; ++p){
      float4 wv = *(const float4*)&sw[p * 128 + j0];
      #pragma unroll
      for (int di = 0; di < 5; ++di){
        float mv = M[(i0 + di) * 128 + p];
        acc[di][0] = fmaf(mv, wv.x, acc[di][0]);
        acc[di][1] = fmaf(mv, wv.y, acc[di][1]);
        acc[di][2] = fmaf(mv, wv.z, acc[di][2]);
        acc[di][3] = fmaf(mv, wv.w, acc[di][3]);
      }
    }
    short* dst = Hbf + (size_t)b * NPAD * 128;
    #pragma unroll
    for (int di = 0; di < 5; ++di){
      short4v o;
      #pragma unroll
      for (int q = 0; q < 4; ++q){
        float v = acc[di][q];
        v = (v >= 0.f) ? v : 0.01f * v;
        o[q] = (short)f2bf(v);
      }
      *(short4v*)&dst[(i0 + di) * 128 + j0] = o;
    }
  }
  __syncthreads();                      // M dead; reuse as M2

  // ---- ht phase 1: M2[i][c] = sum_m At[i][m] * xf[m][c]; tile 4i x 5c ----
  {
    const int c0 = (t & 7) * 5, i0 = (t >> 3) * 4;
    const float* At = At_g + (size_t)b * 16384;
    float acc[4][5];
    #pragma unroll
    for (int di = 0; di < 4; ++di)
      #pragma unroll
      for (int dc = 0; dc < 5; ++dc) acc[di][dc] = 0.f;
    for (int m = 0; m < 128; m += 4){
      float4 a4[4];
      #pragma unroll
      for (int di = 0; di < 4; ++di) a4[di] = *(const float4*)&At[(i0 + di) * 128 + m];
      #pragma unroll
      for (int dm = 0; dm < 4; ++dm){
        float xv[5];
        #pragma unroll
        for (int dc = 0; dc < 5; ++dc) xv[dc] = xf[(m + dm) * 40 + c0 + dc];
        #pragma unroll
        for (int di = 0; di < 4; ++di){
          float av = (&a4[di].x)[dm];
          #pragma unroll
          for (int dc = 0; dc < 5; ++dc)
            acc[di][dc] = fmaf(av, xv[dc], acc[di][dc]);
        }
      }
    }
    #pragma unroll
    for (int di = 0; di < 4; ++di)
      #pragma unroll
      for (int dc = 0; dc < 5; ++dc)
        M[(i0 + di) * 40 + c0 + dc] = acc[di][dc];
  }
  __syncthreads();

  // ---- ht phase 2: H_t[i][j] -> bf16 Hbf rows 40..167 ----
  {
    const int j0 = (t & 31) * 4, i0 = (t >> 5) * 16;
    float4 bv = *(const float4*)&tb[j0];
    float acc[16][4];
    #pragma unroll
    for (int di = 0; di < 16; ++di){ acc[di][0]=bv.x; acc[di][1]=bv.y; acc[di][2]=bv.z; acc[di][3]=bv.w; }
    for (int c = 0; c < 40; ++c){
      float4 wv = *(const float4*)&tw[c * 128 + j0];
      #pragma unroll
      for (int di = 0; di < 16; ++di){
        float mv = M[(i0 + di) * 40 + c];
        acc[di][0] = fmaf(mv, wv.x, acc[di][0]);
        acc[di][1] = fmaf(mv, wv.y, acc[di][1]);
        acc[di][2] = fmaf(mv, wv.z, acc[di][2]);
        acc[di][3] = fmaf(mv, wv.w, acc[di][3]);
      }
    }
    short* dst = Hbf + (size_t)b * NPAD * 128 + 40 * 128;
    #pragma unroll
    for (int di = 0; di < 16; ++di){
      short4v o;
      #pragma unroll
      for (int q = 0; q < 4; ++q){
        float v = acc[di][q];
        v = (v >= 0.f) ? v : 0.01f * v;
        o[q] = (short)f2bf(v);
      }
      *(short4v*)&dst[(i0 + di) * 128 + j0] = o;
    }
  }
}

// out[b] = fc_b + sum_h c4[h]
__global__ void initout_kernel(float* __restrict__ out, const float* __restrict__ fcb,
                               const float* __restrict__ c4){
  int i = blockIdx.x * 256 + threadIdx.x;
  float base = fcb[0] + c4[0] + c4[1] + c4[2] + c4[3];
  if (i < BSZ) out[i] = base;
}

// ---------- prep: per-head M^T, R = fcw·Wv^T, c1/c2/c3/c4; grid (NH, 11) ----------
__global__ __launch_bounds__(256) void prep_kernel(
    const float* __restrict__ qw, const float* __restrict__ qb,
    const float* __restrict__ kw, const float* __restrict__ kb,
    const float* __restrict__ vw, const float* __restrict__ vb,
    const float* __restrict__ fcw,
    short* __restrict__ MT, short* __restrict__ Rbf,
    float* __restrict__ c1, float* __restrict__ c2,
    float* __restrict__ c3, float* __restrict__ c4){
  const int h = blockIdx.x, sl = blockIdx.y, t = threadIdx.x;
  const float* Q = qw + h * 16384;
  const float* K = kw + h * 16384;
  const float* V = vw + h * 16384;
  if (sl < 8){
    for (int idx = t; idx < 2048; idx += 256){
      int j = sl * 16 + (idx >> 7), d = idx & 127;
      float acc = 0.f;
      for (int e = 0; e < 128; ++e) acc = fmaf(Q[d * 128 + e], K[j * 128 + e], acc);
      MT[h * 16384 + j * 128 + d] = (short)f2bf(acc);     // MT[j][d] = M[d][j]
    }
    if (t < 16){
      int r = sl * 16 + t;
      float a = 0.f, bsum = 0.f;
      for (int e = 0; e < 128; ++e){
        a    = fmaf(Q[r * 128 + e], kb[h * 128 + e], a);
        bsum = fmaf(K[r * 128 + e], qb[h * 128 + e], bsum);
      }
      c1[h * 128 + r] = a;
      c2[h * 128 + r] = bsum;
    }
  }
  // R rows n in [sl*16, sl*16+16); zero-pad n >= 168
  for (int idx = t; idx < 2048; idx += 256){
    int n = sl * 16 + (idx >> 7), d = idx & 127;
    float acc = 0.f;
    if (n < N){
      const float* fr = fcw + n * 512 + h * 128;
      const float* vr = V + d * 128;
      for (int e = 0; e < 128; ++e) acc = fmaf(fr[e], vr[e], acc);
    }
    Rbf[h * 22528 + n * 128 + d] = (short)f2bf(acc);
  }
  if (sl == 0){
    if (t == 0){
      float a = 0.f;
      for (int e = 0; e < 128; ++e) a = fmaf(qb[h * 128 + e], kb[h * 128 + e], a);
      c3[h] = a;
    }
    if (t >= 64 && t < 128){                  // wave 1: c4 reduction
      int l = t - 64;
      float part = 0.f;
      for (int i = l; i < N * 128; i += 64){
        int n = i >> 7, e = i & 127;
        part = fmaf(fcw[n * 512 + h * 128 + e], vb[h * 128 + e], part);
      }
      part = wsum(part);
      if (l == 0) c4[h] = part;
    }
  }
}

// ---------- u1/u2 precompute: u1[n]=H[n]·c1, u2[n]=H[n]·c2 per (b,h) ----------
__global__ __launch_bounds__(256) void uprep_kernel(const short* __restrict__ Hbf,
    const float* __restrict__ c1, const float* __restrict__ c2,
    float* __restrict__ u1g, float* __restrict__ u2g){
  const int b = blockIdx.x, t = threadIdx.x;
  for (int idx = t; idx < 176 * 4; idx += 256){
    int n = idx >> 2, h = idx & 3;
    const bf16x8* rp = (const bf16x8*)(Hbf + (size_t)b * NPAD * 128 + (size_t)n * 128);
    const float* C1 = c1 + h * 128;
    const float* C2 = c2 + h * 128;
    float a1 = 0.f, a2 = 0.f;
    for (int kk = 0; kk < 16; ++kk){
      bf16x8 v = rp[kk];
      #pragma unroll
      for (int j = 0; j < 8; ++j){
        float hv = bf2f((unsigned short)v[j]);
        a1 = fmaf(hv, C1[kk * 8 + j], a1);
        a2 = fmaf(hv, C2[kk * 8 + j], a2);
      }
    }
    u1g[(size_t)(b * 4 + h) * 176 + n] = a1;
    u2g[(size_t)(b * 4 + h) * 176 + n] = a2;
  }
}

// ---------- attention, flash-style, 8-wave block: grid (b) ----------
// (512,2): LDS 78KB -> 2 blocks/CU; VGPR free to ~128, no spill.
// ti task loop #pragma unroll 1 (r9 lesson: full unroll -> spill).
__global__ __launch_bounds__(512, 2) void attn_flash(
    const short* __restrict__ Hbf, const short* __restrict__ MT,
    const short* __restrict__ Rbf,
    const float* __restrict__ u1g, const float* __restrict__ u2g,
    const float* __restrict__ c3g, float* __restrict__ out){
  const int b = blockIdx.x;
  const int t = threadIdx.x;
  const int wv = t >> 6, l = t & 63, quad = l >> 4, l15 = l & 15;
  const int h = wv & 3;

  __shared__ __align__(16) short Hsh[NPAD * 128];     // 45KB, swizzled
  __shared__ __align__(16) short Tsh[8 * 2048];       // 32KB, 4KB/wave private
  __shared__ float red8[8];

  const short* Hb = Hbf + (size_t)b * NPAD * 128;

  // ---- cooperative stage: 2816 x 16B units, coalesced global, swizzled LDS ----
  #pragma unroll
  for (int i = 0; i < 6; ++i){
    int idx = t + i * 512;
    if (idx < 2816){
      int row = idx >> 4, g = idx & 15;
      bf16x8 v = *(const bf16x8*)(Hb + row * 128 + g * 8);
      *(bf16x8*)(Hsh + row * 128 + ((g ^ (row & 15)) * 8)) = v;
    }
  }
  __syncthreads();

  const short* MTh = MT + h * 16384;
  const short* Rh  = Rbf + h * 22528;
  const float c3v = c3g[h];
  const float inv = 0.08838834764831845f;   // 1/sqrt(128)
  const float* u1p = u1g + (size_t)(b * 4 + h) * 176;
  const float* u2p = u2g + (size_t)(b * 4 + h) * 176;
  short* Tw = Tsh + wv * 2048;

  float tp = 0.f;
  #pragma unroll 1
  for (int ti = 0; ti < 6; ++ti){
    const int zt = (wv >> 2) + ti * 2;
    if (zt < 11){                                  // wave-uniform guard
      const int rowbase = zt * 16;

      // A-frags (H rows, from LDS) and R-frags (global, L2-hot)
      bf16x8 HA[4], RA[4];
      #pragma unroll
      for (int kk = 0; kk < 4; ++kk){
        HA[kk] = *(const bf16x8*)(Hsh + (rowbase + l15) * 128 + (((kk * 4 + quad) ^ l15) * 8));
        RA[kk] = *(const bf16x8*)(Rh + (rowbase + l15) * 128 + kk * 32 + quad * 8);
      }
      float u1v[4];
      #pragma unroll
      for (int r = 0; r < 4; ++r) u1v[r] = u1p[rowbase + quad * 4 + r];

      // ---- Phase A: T = H_chunk @ M -> private LDS slice (XOR-swizzled) ----
      #pragma unroll
      for (int jt = 0; jt < 8; ++jt){
        const int j0 = jt * 16;
        f32x4 acc = {0.f, 0.f, 0.f, 0.f};
        #pragma unroll
        for (int kk = 0; kk < 4; ++kk){
          bf16x8 Bv = *(const bf16x8*)(MTh + (j0 + l15) * 128 + kk * 32 + quad * 8);
          acc = __builtin_amdgcn_mfma_f32_16x16x32_bf16(HA[kk], Bv, acc, 0, 0, 0);
        }
        const int jcol = j0 + l15, ch = jcol >> 3;
        #pragma unroll
        for (int r = 0; r < 4; ++r){
          int row = quad * 4 + r;
          Tw[row * 128 + ((ch ^ row) << 3) + (jcol & 7)] = (short)f2bf(acc[r]);
        }
      }
      // no barrier: same-wave DS ops are ordered

      // ---- Phase BG + per-lane online softmax over 11 m-tiles ----
      float Mx[4], Av[4], Dv[4];
      #pragma unroll
      for (int r = 0; r < 4; ++r){ Mx[r] = -1e30f; Av[r] = 0.f; Dv[r] = 0.f; }

      #pragma unroll
      for (int mt = 0; mt < 11; ++mt){
        const int m0 = mt * 16;
        bf16x8 Bv[4];
        #pragma unroll
        for (int kk = 0; kk < 4; ++kk)
          Bv[kk] = *(const bf16x8*)(Hsh + (m0 + l15) * 128 + (((kk * 4 + quad) ^ l15) * 8));
        const float u2v = u2p[m0 + l15];
        f32x4 acc = {0.f, 0.f, 0.f, 0.f};
        f32x4 g   = {0.f, 0.f, 0.f, 0.f};
        #pragma unroll
        for (int kk = 0; kk < 4; ++kk){
          bf16x8 A = *(const bf16x8*)(Tw + l15 * 128 + (((kk * 4 + quad) ^ l15) << 3));
          acc = __builtin_amdgcn_mfma_f32_16x16x32_bf16(A, Bv[kk], acc, 0, 0, 0);
          g   = __builtin_amdgcn_mfma_f32_16x16x32_bf16(RA[kk], Bv[kk], g, 0, 0, 0);
        }
        const bool padcol = (mt == 10) && (l15 >= 8);     // cols 168..175 masked
        #pragma unroll
        for (int r = 0; r < 4; ++r){
          float s = padcol ? -1e30f : (acc[r] + u1v[r] + u2v + c3v) * inv;
          float Mn = fmaxf(Mx[r], s);
          float ea = __expf(Mx[r] - Mn);
          float eb = __expf(s - Mn);
          Av[r] = fmaf(Av[r], ea, eb * g[r]);
          Dv[r] = fmaf(Dv[r], ea, eb);
          Mx[r] = Mn;
        }
      }

      // ---- merge (M,A,D) across the 16 l15 lanes (stays within quad) ----
      #pragma unroll
      for (int r = 0; r < 4; ++r){
        #pragma unroll
        for (int o = 1; o < 16; o <<= 1){
          float M2 = __shfl_xor(Mx[r], o, 64);
          float A2 = __shfl_xor(Av[r], o, 64);
          float D2 = __shfl_xor(Dv[r], o, 64);
          float Mn = fmaxf(Mx[r], M2);
          float ea = __expf(Mx[r] - Mn);
          float eb = __expf(M2 - Mn);
          Av[r] = fmaf(Av[r], ea, A2 * eb);
          Dv[r] = fmaf(Dv[r], ea, D2 * eb);
          Mx[r] = Mn;
        }
      }

      // ---- per-row A/D, replicated over 16 lanes -> scale by 1/16 ----
      #pragma unroll
      for (int r = 0; r < 4; ++r){
        int n = rowbase + quad * 4 + r;
        if (n < N) tp += Av[r] / Dv[r];
      }
    }
  }
  tp *= (1.0f / 16.0f);

  // ---- block reduction over 8 waves ----
  #pragma unroll
  for (int o = 32; o > 0; o >>= 1) tp += __shfl_down(tp, o, 64);
  if (l == 0) red8[wv] = tp;
  __syncthreads();
  if (t == 0){
    float s = 0.f;
    #pragma unroll
    for (int i = 0; i < 8; ++i) s += red8[i];
    atomicAdd(out + b, s);
  }
}

} // anonymous namespace

extern "C" void kernel_launch(void* const* d_in, const int* in_sizes, int n_in,
                              void* d_out, int out_size, void* d_ws, size_t ws_size,
                              hipStream_t stream) {
  (void)in_sizes; (void)n_in; (void)out_size;
  const float* X      = (const float*)d_in[0];
  const float* spa_w1 = (const float*)d_in[1];
  const float* spa_b1 = (const float*)d_in[2];
  const float* spa_w2 = (const float*)d_in[3];
  const float* spa_b2 = (const float*)d_in[4];
  const float* tem_w1 = (const float*)d_in[5];
  const float* tem_b1 = (const float*)d_in[6];
  const float* tem_w2 = (const float*)d_in[7];
  const float* tem_b2 = (const float*)d_in[8];
  const float* sgnn_w = (const float*)d_in[9];
  const float* sgnn_b = (const float*)d_in[10];
  const float* tgnn_w = (const float*)d_in[11];
  const float* tgnn_b = (const float*)d_in[12];
  const float* q_w    = (const float*)d_in[13];
  const float* q_b    = (const float*)d_in[14];
  const float* k_w    = (const float*)d_in[15];
  const float* k_b    = (const float*)d_in[16];
  const float* v_w    = (const float*)d_in[17];
  const float* v_b    = (const float*)d_in[18];
  const float* fc_w   = (const float*)d_in[19];
  const float* fc_b   = (const float*)d_in[20];
  float* out = (float*)d_out;

  if (ws_size < (size_t)182714368) return;

  char* wsb = (char*)d_ws;
  short* Hbf = (short*)wsb;                      // bf16 H [0, 46.1MB)
  float* u1g = (float*)(wsb + 50331648);
  float* u2g = (float*)(wsb + 53215232);
  char*  Rb  = wsb + 88080384;
  float* Xf  = (float*)Rb;
  float* As  = (float*)(Rb + 20971520);
  float* At  = (float*)(Rb + 27525120);
  char*  Pb  = Rb + 46137344;
  short* MT  = (short*)Pb;                       // 131072 B
  short* Rbf = (short*)(Pb + 131072);            // 180224 B
  float* c1  = (float*)(Pb + 311296);
  float* c2  = (float*)(Pb + 313344);
  float* c3  = (float*)(Pb + 315392);
  float* c4  = (float*)(Pb + 315408);
  float* twg = (float*)(Pb + 327680);            // 32KB twiddle table

  twiddle_kernel<<<16, 256, 0, stream>>>(twg);
  feat_kernel<<<BSZ * P / 8, 512, 0, stream>>>(X, twg, Xf);
  cumnorm_kernel<<<BSZ, 256, 0, stream>>>(Xf);
  adj_kernel<<<BSZ, 256, 0, stream>>>(Xf, tem_w1, tem_b1, tem_w2, tem_b2,
                                      spa_w1, spa_b1, spa_w2, spa_b2, At, As);
  hsht_kernel<<<BSZ, 256, 0, stream>>>(Xf, As, At, sgnn_w, sgnn_b, tgnn_w, tgnn_b, Hbf);
  prep_kernel<<<dim3(NH, 11), 256, 0, stream>>>(q_w, q_b, k_w, k_b, v_w, v_b, fc_w,
                                                MT, Rbf, c1, c2, c3, c4);
  uprep_kernel<<<BSZ, 256, 0, stream>>>(Hbf, c1, c2, u1g, u2g);
  initout_kernel<<<4, 256, 0, stream>>>(out, fc_b, c4);
  attn_flash<<<dim3(BSZ), 512, 0, stream>>>(Hbf, MT, Rbf, u1g, u2g, c3, out);
}